// Round 1
// baseline (4997.645 us; speedup 1.0000x reference)
//
#include <hip/hip_runtime.h>

#define BB 8
#define CC 64
#define HH 128
#define WW 320

// float offsets inside d_out
#define N_OUTF (BB*CC*HH*WW)           // 20,971,520
#define N_V    (BB*HH*WW)              // 327,680
#define N_M    (BB*HH*WW*WW)           // 104,857,600
#define OFF_V    (N_OUTF)
#define OFF_ML2R (N_OUTF + N_V)        // 21,299,200
#define OFF_MR2L (OFF_ML2R + N_M)      // 126,156,800
#define OUT_TOTAL (OFF_MR2L + N_M)     // 231,014,400
#define WT_FLOATS 81920                // 2*36864 + 2*4096

// ---------------------------------------------------------------------------
// Weight transpose: rb_w [co][ci][ky][kx] -> wT [ci][ky][kx][co]
//                   wl/wr [co][ci]        -> [ci][co]
__global__ __launch_bounds__(256) void k_wt(
    const float* __restrict__ w1, const float* __restrict__ w2,
    const float* __restrict__ wl, const float* __restrict__ wr,
    float* __restrict__ wt)
{
    int tid = blockIdx.x * 256 + threadIdx.x;
    int stride = gridDim.x * 256;
    for (int e = tid; e < 64*64*9; e += stride) {
        int co = e / 576;
        int r  = e - co * 576;          // ci*9 + ky*3 + kx
        wt[r*64 + co]          = w1[e];
        wt[36864 + r*64 + co]  = w2[e];
    }
    for (int e = tid; e < 4096; e += stride) {
        int co = e >> 6, ci = e & 63;
        wt[73728 + ci*64 + co] = wl[e];
        wt[77824 + ci*64 + co] = wr[e];
    }
}

// ---------------------------------------------------------------------------
// 3x3 conv, 64->64, pad 1. mode 0: LeakyReLU(0.1). mode 1: += residual.
// block: 256 thr = 64 x-lanes * 4 co-groups(16 co each). grid: (W/64, H, B)
__global__ __launch_bounds__(256) void k_conv3x3(
    const float* __restrict__ in, const float* __restrict__ wT,
    const float* __restrict__ res, float* __restrict__ out, int mode)
{
    __shared__ float tile[CC*3*66];      // [ci][ky][x], 50688 B
    const int tid = threadIdx.x;
    const int x0 = blockIdx.x * 64;
    const int y  = blockIdx.y;
    const int b  = blockIdx.z;

    for (int e = tid; e < CC*3*66; e += 256) {
        int ci = e / 198;
        int r  = e - ci*198;
        int ky = r / 66;
        int xx = r - ky*66;
        int gy = y + ky - 1;
        int gx = x0 + xx - 1;
        float v = 0.f;
        if ((unsigned)gy < (unsigned)HH && (unsigned)gx < (unsigned)WW)
            v = in[((size_t)(b*CC + ci)*HH + gy)*WW + gx];
        tile[e] = v;
    }
    __syncthreads();

    const int xl = tid & 63;
    const int cg = __builtin_amdgcn_readfirstlane(tid >> 6);   // wave-uniform
    float acc[16];
#pragma unroll
    for (int j = 0; j < 16; ++j) acc[j] = 0.f;

    for (int ci = 0; ci < CC; ++ci) {
        const float* lrow = &tile[ci*198];
#pragma unroll
        for (int ky = 0; ky < 3; ++ky) {
            const float* wp = &wT[(ci*9 + ky*3)*64 + cg*16];   // scalar loads
            float i0 = lrow[ky*66 + xl + 0];
            float i1 = lrow[ky*66 + xl + 1];
            float i2 = lrow[ky*66 + xl + 2];
#pragma unroll
            for (int j = 0; j < 16; ++j)
                acc[j] += i0*wp[j] + i1*wp[64+j] + i2*wp[128+j];
        }
    }

    const int gx = x0 + xl;
#pragma unroll
    for (int j = 0; j < 16; ++j) {
        int co = cg*16 + j;
        size_t oi = ((size_t)(b*CC + co)*HH + y)*WW + gx;
        float v = acc[j];
        if (mode == 0) v = (v > 0.f) ? v : 0.1f*v;
        else           v += res[oi];
        out[oi] = v;
    }
}

// ---------------------------------------------------------------------------
// 1x1 conv + bias, (B,C,H,W) -> F layout (b,h,w,c). thread = one position.
__global__ __launch_bounds__(256) void k_conv1x1(
    const float* __restrict__ buf, const float* __restrict__ wT,
    const float* __restrict__ bias, float* __restrict__ F)
{
    int p = blockIdx.x * 256 + threadIdx.x;          // 0..B*H*W-1
    int b = p / (HH*WW);
    int rem = p - b*(HH*WW);
    const float* ip = &buf[(size_t)b*CC*HH*WW + rem];
    float acc[64];
#pragma unroll
    for (int j = 0; j < 64; ++j) acc[j] = bias[j];
    for (int ci = 0; ci < CC; ++ci) {
        float v = ip[(size_t)ci*HH*WW];
        const float* wp = &wT[ci*64];
#pragma unroll
        for (int j = 0; j < 64; ++j) acc[j] += v * wp[j];
    }
    float4* op = (float4*)&F[(size_t)p*64];
#pragma unroll
    for (int j = 0; j < 16; ++j)
        op[j] = make_float4(acc[4*j], acc[4*j+1], acc[4*j+2], acc[4*j+3]);
}

// ---------------------------------------------------------------------------
// XOR swizzle for 64-wide f32 LDS tiles read as float4 from 16 distinct rows
__device__ __forceinline__ int swz(int r, int c) {
    return r*64 + (c ^ (((r >> 2) & 7) << 2));
}

// S[row] (320x320) = F0row (320x64) @ F1row^T. grid: (5 wt, 5 vt, 1024 rows)
__global__ __launch_bounds__(256) void k_sgemm(
    const float* __restrict__ F0, const float* __restrict__ F1,
    float* __restrict__ S)
{
    __shared__ __align__(16) float A[64*64];
    __shared__ __align__(16) float Bt[64*64];
    const int wt = blockIdx.x, vt = blockIdx.y, row = blockIdx.z;
    const int tid = threadIdx.x;
    const float* f0 = &F0[((size_t)row*WW + wt*64)*64];
    const float* f1 = &F1[((size_t)row*WW + vt*64)*64];
    for (int e = tid; e < 4096; e += 256) {
        int i = e >> 6, c = e & 63;
        A[swz(i, c)]  = f0[i*64 + c];
        Bt[swz(i, c)] = f1[i*64 + c];
    }
    __syncthreads();

    const int wq = tid >> 4, vq = tid & 15;
    float acc[4][4];
#pragma unroll
    for (int i = 0; i < 4; ++i)
#pragma unroll
        for (int j = 0; j < 4; ++j) acc[i][j] = 0.f;

#pragma unroll
    for (int k4 = 0; k4 < 16; ++k4) {
        float4 a[4], bb[4];
#pragma unroll
        for (int i = 0; i < 4; ++i) {
            int r = wq*4 + i;
            a[i] = *(const float4*)&A[r*64 + ((k4*4) ^ (((r>>2)&7)<<2))];
        }
#pragma unroll
        for (int j = 0; j < 4; ++j) {
            int r = vq*4 + j;
            bb[j] = *(const float4*)&Bt[r*64 + ((k4*4) ^ (((r>>2)&7)<<2))];
        }
#pragma unroll
        for (int i = 0; i < 4; ++i)
#pragma unroll
            for (int j = 0; j < 4; ++j)
                acc[i][j] += a[i].x*bb[j].x + a[i].y*bb[j].y
                           + a[i].z*bb[j].z + a[i].w*bb[j].w;
    }

    float* sp = &S[((size_t)row*WW + wt*64)*WW + vt*64];
#pragma unroll
    for (int i = 0; i < 4; ++i)
        *(float4*)&sp[(size_t)(wq*4 + i)*WW + vq*4] =
            make_float4(acc[i][0], acc[i][1], acc[i][2], acc[i][3]);
}

// ---------------------------------------------------------------------------
// Dual softmax per row: M_r2l = softmax_v(S) in place; M_l2r[v][w] =
// softmax_w(S)^T; V[w] = (sum_v M_l2r > 0.1). block per row, 320 threads.
__global__ __launch_bounds__(320) void k_softmax(
    float* __restrict__ S, float* __restrict__ Ml2r, float* __restrict__ Vout)
{
    __shared__ float pm[5*320], pl[5*320];
    __shared__ float rowmax[320], rowinv[320], colmax[320], colinv[320];
    __shared__ float T[64*65];
    __shared__ float Vp2[5*64];
    const int row = blockIdx.x;
    const int tid = threadIdx.x;
    const int wave = tid >> 6, lane = tid & 63;
    float* Srow = &S[(size_t)row * WW * WW];

    // ---- pass 1: stats. thread owns column v=tid (online); rows via shfl.
    float cm = -1e30f, cl = 0.f;
    for (int w = 0; w < WW; ++w) {
        float s = Srow[(size_t)w*WW + tid];
        if (s <= cm) {
            cl += __expf(s - cm);
        } else {
            cl = cl * __expf(cm - s) + 1.f;
            cm = s;
        }
        float m = s;
#pragma unroll
        for (int o = 32; o > 0; o >>= 1) m = fmaxf(m, __shfl_xor(m, o));
        float e = __expf(s - m);
#pragma unroll
        for (int o = 32; o > 0; o >>= 1) e += __shfl_xor(e, o);
        if (lane == 0) { pm[wave*320 + w] = m; pl[wave*320 + w] = e; }
    }
    __syncthreads();
    {
        int w = tid;
        float m = pm[w];
#pragma unroll
        for (int g = 1; g < 5; ++g) m = fmaxf(m, pm[g*320 + w]);
        float l = 0.f;
#pragma unroll
        for (int g = 0; g < 5; ++g) l += pl[g*320 + w] * __expf(pm[g*320 + w] - m);
        rowmax[w] = m; rowinv[w] = 1.f / l;
        colmax[w] = cm; colinv[w] = 1.f / cl;
    }
    __syncthreads();

    // ---- pass 2: normalize, transpose-write Ml2r, accumulate V
    const int myw = tid & 63;
    const int myg = tid / 64;          // 0..4
    for (int wt = 0; wt < 5; ++wt) {
        float vpart = 0.f;
        for (int vt = 0; vt < 5; ++vt) {
            for (int e = tid; e < 4096; e += 320) {
                int i = e >> 6, j = e & 63;
                int wgl = wt*64 + i, vgl = vt*64 + j;
                size_t si = (size_t)wgl*WW + vgl;
                float s = Srow[si];
                Srow[si] = __expf(s - rowmax[wgl]) * rowinv[wgl];
                T[j*65 + i] = __expf(s - colmax[vgl]) * colinv[vgl];
            }
            __syncthreads();
            for (int e = tid; e < 4096; e += 320) {
                int vr = e >> 6, wc = e & 63;
                Ml2r[((size_t)row*WW + vt*64 + vr)*WW + wt*64 + wc] = T[vr*65 + wc];
            }
            for (int j = myg; j < 64; j += 5) vpart += T[j*65 + myw];
            __syncthreads();
        }
        Vp2[myg*64 + myw] = vpart;
        __syncthreads();
        if (tid < 64) {
            float sv = 0.f;
#pragma unroll
            for (int g = 0; g < 5; ++g) sv += Vp2[g*64 + tid];
            Vout[(size_t)row*WW + wt*64 + tid] = (sv > 0.1f) ? 1.f : 0.f;
        }
        __syncthreads();
    }
}

// ---------------------------------------------------------------------------
// out_f[b,c,h,w] = sum_v M[row][w][v] * x_right[b,c,h,v]. grid: (5 wt, 1024)
__global__ __launch_bounds__(256) void k_outgemm(
    const float* __restrict__ M, const float* __restrict__ xr,
    float* __restrict__ outf)
{
    __shared__ __align__(16) float A[64*64];    // M tile  [w][v]
    __shared__ __align__(16) float Bt[64*64];   // xr tile [c][v]
    const int wt = blockIdx.x;
    const int row = blockIdx.y;
    const int b = row >> 7, h = row & 127;
    const int tid = threadIdx.x;
    const int wq = tid & 15, cq = tid >> 4;

    float acc[4][4];
#pragma unroll
    for (int i = 0; i < 4; ++i)
#pragma unroll
        for (int j = 0; j < 4; ++j) acc[i][j] = 0.f;

    for (int vt = 0; vt < 5; ++vt) {
        for (int e = tid; e < 4096; e += 256) {
            int i = e >> 6, k = e & 63;
            A[swz(i, k)]  = M[((size_t)row*WW + wt*64 + i)*WW + vt*64 + k];
            Bt[swz(i, k)] = xr[(((size_t)b*CC + i)*HH + h)*WW + vt*64 + k];
        }
        __syncthreads();
#pragma unroll
        for (int k4 = 0; k4 < 16; ++k4) {
            float4 a[4], bb[4];
#pragma unroll
            for (int i = 0; i < 4; ++i) {
                int r = wq + 16*i;
                a[i] = *(const float4*)&A[r*64 + ((k4*4) ^ (((r>>2)&7)<<2))];
            }
#pragma unroll
            for (int j = 0; j < 4; ++j) {
                int r = cq + 16*j;
                bb[j] = *(const float4*)&Bt[r*64 + ((k4*4) ^ (((r>>2)&7)<<2))];
            }
#pragma unroll
            for (int i = 0; i < 4; ++i)
#pragma unroll
                for (int j = 0; j < 4; ++j)
                    acc[i][j] += a[i].x*bb[j].x + a[i].y*bb[j].y
                               + a[i].z*bb[j].z + a[i].w*bb[j].w;
        }
        __syncthreads();
    }

#pragma unroll
    for (int j = 0; j < 4; ++j) {
        int c = cq + 16*j;
#pragma unroll
        for (int i = 0; i < 4; ++i) {
            int w = wt*64 + wq + 16*i;
            outf[(((size_t)b*CC + c)*HH + h)*WW + w] = acc[i][j];
        }
    }
}

// ---------------------------------------------------------------------------
extern "C" void kernel_launch(void* const* d_in, const int* in_sizes, int n_in,
                              void* d_out, int out_size, void* d_ws, size_t ws_size,
                              hipStream_t stream)
{
    const float* x_l = (const float*)d_in[0];
    const float* x_r = (const float*)d_in[1];
    const float* w1  = (const float*)d_in[2];
    const float* w2  = (const float*)d_in[3];
    const float* wl  = (const float*)d_in[4];
    const float* bl  = (const float*)d_in[5];
    const float* wr  = (const float*)d_in[6];
    const float* br  = (const float*)d_in[7];
    float* out = (float*)d_out;

    float* outf = out;
    float* Vp   = out + OFF_V;
    float* Ml2r = out + OFF_ML2R;
    float* Mr2l = out + OFF_MR2L;

    // scratch carved from output regions (everything rewritten later)
    float* r_l  = Ml2r;
    float* r_r  = Ml2r + (size_t)N_OUTF;
    float* bufl = Ml2r + 2*(size_t)N_OUTF;
    float* bufr = Ml2r + 3*(size_t)N_OUTF;
    float* F0   = Ml2r;                      // reuses r_l slot
    float* F1   = Ml2r + (size_t)N_OUTF;     // reuses r_r slot
    float* S    = Mr2l;
    float* WT   = out + ((size_t)OUT_TOTAL - WT_FLOATS);  // tail of Mr2l
    float* wT1 = WT, *wT2 = WT + 36864, *wlT = WT + 73728, *wrT = WT + 77824;

    k_wt<<<64, 256, 0, stream>>>(w1, w2, wl, wr, WT);

    dim3 cgrid(WW/64, HH, BB);
    k_conv3x3<<<cgrid, 256, 0, stream>>>(x_l, wT1, x_l, r_l, 0);
    k_conv3x3<<<cgrid, 256, 0, stream>>>(x_r, wT1, x_r, r_r, 0);
    k_conv3x3<<<cgrid, 256, 0, stream>>>(r_l, wT2, x_l, bufl, 1);
    k_conv3x3<<<cgrid, 256, 0, stream>>>(r_r, wT2, x_r, bufr, 1);

    int pblocks = (BB*HH*WW) / 256;          // 1280
    k_conv1x1<<<pblocks, 256, 0, stream>>>(bufl, wlT, bl, F0);
    k_conv1x1<<<pblocks, 256, 0, stream>>>(bufr, wrT, br, F1);

    dim3 sgrid(5, 5, BB*HH);
    k_sgemm<<<sgrid, 256, 0, stream>>>(F0, F1, S);

    k_softmax<<<BB*HH, 320, 0, stream>>>(S, Ml2r, Vp);

    dim3 ogrid(5, BB*HH);
    k_outgemm<<<ogrid, 256, 0, stream>>>(Mr2l, x_r, outf);
}

// Round 2
// 4485.132 us; speedup vs baseline: 1.1143x; 1.1143x over previous
//
#include <hip/hip_runtime.h>

#define BB 8
#define CC 64
#define HH 128
#define WW 320

// float offsets inside d_out
#define N_OUTF (BB*CC*HH*WW)           // 20,971,520
#define N_V    (BB*HH*WW)              // 327,680
#define N_M    (BB*HH*WW*WW)           // 104,857,600
#define OFF_V    (N_OUTF)
#define OFF_ML2R (N_OUTF + N_V)        // 21,299,200
#define OFF_MR2L (OFF_ML2R + N_M)      // 126,156,800
#define OUT_TOTAL (OFF_MR2L + N_M)     // 231,014,400
#define WT_FLOATS 81920                // 2*36864 + 2*4096

// ---------------------------------------------------------------------------
// Weight transpose: rb_w [co][ci][ky][kx] -> wT [ci][ky][kx][co]
//                   wl/wr [co][ci]        -> [ci][co]
__global__ __launch_bounds__(256) void k_wt(
    const float* __restrict__ w1, const float* __restrict__ w2,
    const float* __restrict__ wl, const float* __restrict__ wr,
    float* __restrict__ wt)
{
    int tid = blockIdx.x * 256 + threadIdx.x;
    int stride = gridDim.x * 256;
    for (int e = tid; e < 64*64*9; e += stride) {
        int co = e / 576;
        int r  = e - co * 576;          // ci*9 + ky*3 + kx
        wt[r*64 + co]          = w1[e];
        wt[36864 + r*64 + co]  = w2[e];
    }
    for (int e = tid; e < 4096; e += stride) {
        int co = e >> 6, ci = e & 63;
        wt[73728 + ci*64 + co] = wl[e];
        wt[77824 + ci*64 + co] = wr[e];
    }
}

// ---------------------------------------------------------------------------
// 3x3 conv, 64->64, pad 1. mode 0: LeakyReLU(0.1). mode 1: += residual.
// block: 256 thr = 64 x-lanes * 4 co-groups(16 co each). grid: (W/64, H, B)
__global__ __launch_bounds__(256) void k_conv3x3(
    const float* __restrict__ in, const float* __restrict__ wT,
    const float* __restrict__ res, float* __restrict__ out, int mode)
{
    __shared__ float tile[CC*3*66];      // [ci][ky][x], 50688 B
    const int tid = threadIdx.x;
    const int x0 = blockIdx.x * 64;
    const int y  = blockIdx.y;
    const int b  = blockIdx.z;

    {   // staging: 4 threads per ci, no integer divides
        int ci = tid >> 2, sub = tid & 3;
        const float* ibase = &in[(size_t)(b*CC + ci)*HH*WW];
        float* trow = &tile[ci*198];
#pragma unroll
        for (int ky = 0; ky < 3; ++ky) {
            int gy = y + ky - 1;
            bool yok = (unsigned)gy < (unsigned)HH;
            const float* irow = &ibase[(size_t)gy*WW];
            for (int xx = sub; xx < 66; xx += 4) {
                int gx = x0 + xx - 1;
                float v = 0.f;
                if (yok && (unsigned)gx < (unsigned)WW) v = irow[gx];
                trow[ky*66 + xx] = v;
            }
        }
    }
    __syncthreads();

    const int xl = tid & 63;
    const int cg = __builtin_amdgcn_readfirstlane(tid >> 6);   // wave-uniform
    float acc[16];
#pragma unroll
    for (int j = 0; j < 16; ++j) acc[j] = 0.f;

#pragma unroll 2
    for (int ci = 0; ci < CC; ++ci) {
        const float* lrow = &tile[ci*198];
#pragma unroll
        for (int ky = 0; ky < 3; ++ky) {
            const float* wp = &wT[(ci*9 + ky*3)*64 + cg*16];   // scalar loads
            float i0 = lrow[ky*66 + xl + 0];
            float i1 = lrow[ky*66 + xl + 1];
            float i2 = lrow[ky*66 + xl + 2];
#pragma unroll
            for (int j = 0; j < 16; ++j)
                acc[j] += i0*wp[j] + i1*wp[64+j] + i2*wp[128+j];
        }
    }

    const int gx = x0 + xl;
#pragma unroll
    for (int j = 0; j < 16; ++j) {
        int co = cg*16 + j;
        size_t oi = ((size_t)(b*CC + co)*HH + y)*WW + gx;
        float v = acc[j];
        if (mode == 0) v = (v > 0.f) ? v : 0.1f*v;
        else           v += res[oi];
        out[oi] = v;
    }
}

// ---------------------------------------------------------------------------
// 1x1 conv + bias, (B,C,H,W) -> F layout (b,h,w,c). thread = one position.
__global__ __launch_bounds__(256) void k_conv1x1(
    const float* __restrict__ buf, const float* __restrict__ wT,
    const float* __restrict__ bias, float* __restrict__ F)
{
    int p = blockIdx.x * 256 + threadIdx.x;          // 0..B*H*W-1
    int b = p / (HH*WW);
    int rem = p - b*(HH*WW);
    const float* ip = &buf[(size_t)b*CC*HH*WW + rem];
    float acc[64];
#pragma unroll
    for (int j = 0; j < 64; ++j) acc[j] = bias[j];
    for (int ci = 0; ci < CC; ++ci) {
        float v = ip[(size_t)ci*HH*WW];
        const float* wp = &wT[ci*64];
#pragma unroll
        for (int j = 0; j < 64; ++j) acc[j] += v * wp[j];
    }
    float4* op = (float4*)&F[(size_t)p*64];
#pragma unroll
    for (int j = 0; j < 16; ++j)
        op[j] = make_float4(acc[4*j], acc[4*j+1], acc[4*j+2], acc[4*j+3]);
}

// ---------------------------------------------------------------------------
// XOR swizzle for 64-wide f32 LDS tiles read as float4 from 16 distinct rows.
// XOR value is a multiple of 4 -> 4-aligned float groups stay contiguous.
__device__ __forceinline__ int swz(int r, int c) {
    return r*64 + (c ^ (((r >> 2) & 7) << 2));
}

// S[row] (320x320) = F0row (320x64) @ F1row^T. grid: (5 wt, 5 vt, 1024 rows)
__global__ __launch_bounds__(256) void k_sgemm(
    const float* __restrict__ F0, const float* __restrict__ F1,
    float* __restrict__ S)
{
    __shared__ __align__(16) float A[64*64];
    __shared__ __align__(16) float Bt[64*64];
    const int wt = blockIdx.x, vt = blockIdx.y, row = blockIdx.z;
    const int tid = threadIdx.x;
    const float4* f04 = (const float4*)&F0[((size_t)row*WW + wt*64)*64];
    const float4* f14 = (const float4*)&F1[((size_t)row*WW + vt*64)*64];
    for (int e = tid; e < 1024; e += 256) {
        int i = e >> 4, c4 = (e & 15) * 4;
        *(float4*)&A[swz(i, c4)]  = f04[e];
        *(float4*)&Bt[swz(i, c4)] = f14[e];
    }
    __syncthreads();

    const int wq = tid >> 4, vq = tid & 15;
    float acc[4][4];
#pragma unroll
    for (int i = 0; i < 4; ++i)
#pragma unroll
        for (int j = 0; j < 4; ++j) acc[i][j] = 0.f;

#pragma unroll
    for (int k4 = 0; k4 < 16; ++k4) {
        float4 a[4], bb[4];
#pragma unroll
        for (int i = 0; i < 4; ++i) {
            int r = wq*4 + i;
            a[i] = *(const float4*)&A[r*64 + ((k4*4) ^ (((r>>2)&7)<<2))];
        }
#pragma unroll
        for (int j = 0; j < 4; ++j) {
            int r = vq*4 + j;
            bb[j] = *(const float4*)&Bt[r*64 + ((k4*4) ^ (((r>>2)&7)<<2))];
        }
#pragma unroll
        for (int i = 0; i < 4; ++i)
#pragma unroll
            for (int j = 0; j < 4; ++j)
                acc[i][j] += a[i].x*bb[j].x + a[i].y*bb[j].y
                           + a[i].z*bb[j].z + a[i].w*bb[j].w;
    }

    float* sp = &S[((size_t)row*WW + wt*64)*WW + vt*64];
#pragma unroll
    for (int i = 0; i < 4; ++i)
        *(float4*)&sp[(size_t)(wq*4 + i)*WW + vq*4] =
            make_float4(acc[i][0], acc[i][1], acc[i][2], acc[i][3]);
}

// ---------------------------------------------------------------------------
// Dual softmax per row: M_r2l = softmax_v(S) in place; M_l2r[v][w] =
// softmax_w(S)^T; V[w] = (sum_v M_l2r > 0.1). block per row, 320 threads.
// Pass 1 is pure per-thread ownership: no cross-lane ops at all.
__global__ __launch_bounds__(320) void k_softmax(
    float* __restrict__ S, float* __restrict__ Ml2r, float* __restrict__ Vout)
{
    __shared__ float rowmax[320], rowinv[320], colmax[320], colinv[320];
    __shared__ float T[64*65];
    __shared__ float Vp2[5*64];
    const int row = blockIdx.x;
    const int tid = threadIdx.x;
    float* Srow = &S[(size_t)row * WW * WW];

    // ---- pass 1a: column max (thread owns column v=tid), coalesced
    float cm = -1e30f;
#pragma unroll 4
    for (int w = 0; w < WW; ++w)
        cm = fmaxf(cm, Srow[(size_t)w*WW + tid]);
    // ---- pass 1b: column exp-sum
    float cl = 0.f;
#pragma unroll 4
    for (int w = 0; w < WW; ++w)
        cl += __expf(Srow[(size_t)w*WW + tid] - cm);
    // ---- pass 1c: row max (thread owns row w=tid), float4 over own row
    const float4* rp = (const float4*)&Srow[(size_t)tid*WW];
    float rm = -1e30f;
#pragma unroll 4
    for (int v = 0; v < 80; ++v) {
        float4 s = rp[v];
        rm = fmaxf(fmaxf(fmaxf(rm, s.x), s.y), fmaxf(s.z, s.w));
    }
    // ---- pass 1d: row exp-sum
    float rl = 0.f;
#pragma unroll 4
    for (int v = 0; v < 80; ++v) {
        float4 s = rp[v];
        rl += __expf(s.x - rm) + __expf(s.y - rm)
            + __expf(s.z - rm) + __expf(s.w - rm);
    }
    rowmax[tid] = rm; rowinv[tid] = 1.f / rl;
    colmax[tid] = cm; colinv[tid] = 1.f / cl;
    __syncthreads();

    // ---- pass 2: normalize, transpose-write Ml2r, accumulate V
    const int myw = tid & 63;
    const int myg = tid / 64;          // 0..4
    for (int wt = 0; wt < 5; ++wt) {
        float vpart = 0.f;
        for (int vt = 0; vt < 5; ++vt) {
            for (int e = tid; e < 4096; e += 320) {
                int i = e >> 6, j = e & 63;
                int wgl = wt*64 + i, vgl = vt*64 + j;
                size_t si = (size_t)wgl*WW + vgl;
                float s = Srow[si];
                Srow[si] = __expf(s - rowmax[wgl]) * rowinv[wgl];
                T[j*65 + i] = __expf(s - colmax[vgl]) * colinv[vgl];
            }
            __syncthreads();
            for (int e = tid; e < 4096; e += 320) {
                int vr = e >> 6, wc = e & 63;
                Ml2r[((size_t)row*WW + vt*64 + vr)*WW + wt*64 + wc] = T[vr*65 + wc];
            }
            for (int j = myg; j < 64; j += 5) vpart += T[j*65 + myw];
            __syncthreads();
        }
        Vp2[myg*64 + myw] = vpart;
        __syncthreads();
        if (tid < 64) {
            float sv = 0.f;
#pragma unroll
            for (int g = 0; g < 5; ++g) sv += Vp2[g*64 + tid];
            Vout[(size_t)row*WW + wt*64 + tid] = (sv > 0.1f) ? 1.f : 0.f;
        }
        __syncthreads();
    }
}

// ---------------------------------------------------------------------------
// out_f[b,c,h,w] = sum_v M[row][w][v] * x_right[b,c,h,v]. grid: (5 wt, 1024)
__global__ __launch_bounds__(256) void k_outgemm(
    const float* __restrict__ M, const float* __restrict__ xr,
    float* __restrict__ outf)
{
    __shared__ __align__(16) float A[64*64];    // M tile  [w][v]
    __shared__ __align__(16) float Bt[64*64];   // xr tile [c][v]
    const int wt = blockIdx.x;
    const int row = blockIdx.y;
    const int b = row >> 7, h = row & 127;
    const int tid = threadIdx.x;
    const int wq = tid & 15, cq = tid >> 4;

    float acc[4][4];
#pragma unroll
    for (int i = 0; i < 4; ++i)
#pragma unroll
        for (int j = 0; j < 4; ++j) acc[i][j] = 0.f;

    for (int vt = 0; vt < 5; ++vt) {
        for (int e = tid; e < 1024; e += 256) {
            int i = e >> 4, k4 = (e & 15) * 4;
            *(float4*)&A[swz(i, k4)] =
                *(const float4*)&M[((size_t)row*WW + wt*64 + i)*WW + vt*64 + k4];
            *(float4*)&Bt[swz(i, k4)] =
                *(const float4*)&xr[(((size_t)b*CC + i)*HH + h)*WW + vt*64 + k4];
        }
        __syncthreads();
#pragma unroll
        for (int k4 = 0; k4 < 16; ++k4) {
            float4 a[4], bb[4];
#pragma unroll
            for (int i = 0; i < 4; ++i) {
                int r = wq + 16*i;
                a[i] = *(const float4*)&A[r*64 + ((k4*4) ^ (((r>>2)&7)<<2))];
            }
#pragma unroll
            for (int j = 0; j < 4; ++j) {
                int r = cq + 16*j;
                bb[j] = *(const float4*)&Bt[r*64 + ((k4*4) ^ (((r>>2)&7)<<2))];
            }
#pragma unroll
            for (int i = 0; i < 4; ++i)
#pragma unroll
                for (int j = 0; j < 4; ++j)
                    acc[i][j] += a[i].x*bb[j].x + a[i].y*bb[j].y
                               + a[i].z*bb[j].z + a[i].w*bb[j].w;
        }
        __syncthreads();
    }

#pragma unroll
    for (int j = 0; j < 4; ++j) {
        int c = cq + 16*j;
#pragma unroll
        for (int i = 0; i < 4; ++i) {
            int w = wt*64 + wq + 16*i;
            outf[(((size_t)b*CC + c)*HH + h)*WW + w] = acc[i][j];
        }
    }
}

// ---------------------------------------------------------------------------
extern "C" void kernel_launch(void* const* d_in, const int* in_sizes, int n_in,
                              void* d_out, int out_size, void* d_ws, size_t ws_size,
                              hipStream_t stream)
{
    const float* x_l = (const float*)d_in[0];
    const float* x_r = (const float*)d_in[1];
    const float* w1  = (const float*)d_in[2];
    const float* w2  = (const float*)d_in[3];
    const float* wl  = (const float*)d_in[4];
    const float* bl  = (const float*)d_in[5];
    const float* wr  = (const float*)d_in[6];
    const float* br  = (const float*)d_in[7];
    float* out = (float*)d_out;

    float* outf = out;
    float* Vp   = out + OFF_V;
    float* Ml2r = out + OFF_ML2R;
    float* Mr2l = out + OFF_MR2L;

    // scratch carved from output regions (everything rewritten later)
    float* r_l  = Ml2r;
    float* r_r  = Ml2r + (size_t)N_OUTF;
    float* bufl = Ml2r + 2*(size_t)N_OUTF;
    float* bufr = Ml2r + 3*(size_t)N_OUTF;
    float* F0   = Ml2r;                      // reuses r_l slot
    float* F1   = Ml2r + (size_t)N_OUTF;     // reuses r_r slot
    float* S    = Mr2l;
    float* WT   = out + ((size_t)OUT_TOTAL - WT_FLOATS);  // tail of Mr2l
    float* wT1 = WT, *wT2 = WT + 36864, *wlT = WT + 73728, *wrT = WT + 77824;

    k_wt<<<64, 256, 0, stream>>>(w1, w2, wl, wr, WT);

    dim3 cgrid(WW/64, HH, BB);
    k_conv3x3<<<cgrid, 256, 0, stream>>>(x_l, wT1, x_l, r_l, 0);
    k_conv3x3<<<cgrid, 256, 0, stream>>>(x_r, wT1, x_r, r_r, 0);
    k_conv3x3<<<cgrid, 256, 0, stream>>>(r_l, wT2, x_l, bufl, 1);
    k_conv3x3<<<cgrid, 256, 0, stream>>>(r_r, wT2, x_r, bufr, 1);

    int pblocks = (BB*HH*WW) / 256;          // 1280
    k_conv1x1<<<pblocks, 256, 0, stream>>>(bufl, wlT, bl, F0);
    k_conv1x1<<<pblocks, 256, 0, stream>>>(bufr, wrT, br, F1);

    dim3 sgrid(5, 5, BB*HH);
    k_sgemm<<<sgrid, 256, 0, stream>>>(F0, F1, S);

    k_softmax<<<BB*HH, 320, 0, stream>>>(S, Ml2r, Vp);

    dim3 ogrid(5, BB*HH);
    k_outgemm<<<ogrid, 256, 0, stream>>>(Mr2l, x_r, outf);
}

// Round 3
// 4304.355 us; speedup vs baseline: 1.1611x; 1.0420x over previous
//
#include <hip/hip_runtime.h>

#define BB 8
#define CC 64
#define HH 128
#define WW 320

// float offsets inside d_out
#define N_OUTF (BB*CC*HH*WW)           // 20,971,520
#define N_V    (BB*HH*WW)              // 327,680
#define N_M    (BB*HH*WW*WW)           // 104,857,600
#define OFF_V    (N_OUTF)
#define OFF_ML2R (N_OUTF + N_V)        // 21,299,200
#define OFF_MR2L (OFF_ML2R + N_M)      // 126,156,800
#define OUT_TOTAL (OFF_MR2L + N_M)     // 231,014,400
#define WT_FLOATS 81920                // 2*36864 + 2*4096

// ---------------------------------------------------------------------------
// Weight transpose: rb_w [co][ci][ky][kx] -> wT [ci][ky][kx][co]
//                   wl/wr [co][ci]        -> [ci][co]
__global__ __launch_bounds__(256) void k_wt(
    const float* __restrict__ w1, const float* __restrict__ w2,
    const float* __restrict__ wl, const float* __restrict__ wr,
    float* __restrict__ wt)
{
    int tid = blockIdx.x * 256 + threadIdx.x;
    int stride = gridDim.x * 256;
    for (int e = tid; e < 64*64*9; e += stride) {
        int co = e / 576;
        int r  = e - co * 576;          // ci*9 + ky*3 + kx
        wt[r*64 + co]          = w1[e];
        wt[36864 + r*64 + co]  = w2[e];
    }
    for (int e = tid; e < 4096; e += stride) {
        int co = e >> 6, ci = e & 63;
        wt[73728 + ci*64 + co] = wl[e];
        wt[77824 + ci*64 + co] = wr[e];
    }
}

// ---------------------------------------------------------------------------
// 3x3 conv, 64->64, pad 1, TWO output rows per block.
// mode 0: LeakyReLU(0.1). mode 1: += residual.
// block: 256 thr = 64 x-lanes * 4 co-groups(16 co each). grid: (W/64, H/2, B)
__global__ __launch_bounds__(256) void k_conv3x3(
    const float* __restrict__ in, const float* __restrict__ wT,
    const float* __restrict__ res, float* __restrict__ out, int mode)
{
    __shared__ float tile[CC*4*66];      // [ci][ry][xx], 67584 B
    const int tid = threadIdx.x;
    const int x0 = blockIdx.x * 64;
    const int y0 = blockIdx.y * 2;
    const int b  = blockIdx.z;

    {   // staging: 4 threads per ci; lanes 4k..4k+3 cover a row with phase k
        int ci = tid >> 2, sub = tid & 3;
        const float* ibase = &in[(size_t)(b*CC + ci)*HH*WW];
        float* trow = &tile[ci*264];
#pragma unroll
        for (int ry = 0; ry < 4; ++ry) {
            int gy = y0 + ry - 1;
            bool yok = (unsigned)gy < (unsigned)HH;
            const float* irow = &ibase[(size_t)gy*WW];
            for (int xx = sub; xx < 66; xx += 4) {
                int gx = x0 + xx - 1;
                float v = 0.f;
                if (yok && (unsigned)gx < (unsigned)WW) v = irow[gx];
                trow[ry*66 + xx] = v;
            }
        }
    }
    __syncthreads();

    const int xl = tid & 63;
    const int cg = __builtin_amdgcn_readfirstlane(tid >> 6);   // wave-uniform
    float acc0[16], acc1[16];
#pragma unroll
    for (int j = 0; j < 16; ++j) { acc0[j] = 0.f; acc1[j] = 0.f; }

    for (int ci = 0; ci < CC; ++ci) {
        const float* lr = &tile[ci*264 + xl];
        float rv[4][3];
#pragma unroll
        for (int ry = 0; ry < 4; ++ry) {
            rv[ry][0] = lr[ry*66 + 0];
            rv[ry][1] = lr[ry*66 + 1];
            rv[ry][2] = lr[ry*66 + 2];
        }
#pragma unroll
        for (int ky = 0; ky < 3; ++ky) {
            const float* wp = &wT[(ci*9 + ky*3)*64 + cg*16];   // scalar loads
#pragma unroll
            for (int j = 0; j < 16; ++j) {
                float w0 = wp[j], w1 = wp[64+j], w2 = wp[128+j];
                acc0[j] += rv[ky  ][0]*w0 + rv[ky  ][1]*w1 + rv[ky  ][2]*w2;
                acc1[j] += rv[ky+1][0]*w0 + rv[ky+1][1]*w1 + rv[ky+1][2]*w2;
            }
        }
    }

    const int gx = x0 + xl;
#pragma unroll
    for (int j = 0; j < 16; ++j) {
        int co = cg*16 + j;
        size_t oi0 = ((size_t)(b*CC + co)*HH + y0)*WW + gx;
        float v0 = acc0[j], v1 = acc1[j];
        if (mode == 0) {
            v0 = (v0 > 0.f) ? v0 : 0.1f*v0;
            v1 = (v1 > 0.f) ? v1 : 0.1f*v1;
        } else {
            v0 += res[oi0];
            v1 += res[oi0 + WW];
        }
        out[oi0]      = v0;
        out[oi0 + WW] = v1;
    }
}

// ---------------------------------------------------------------------------
// 1x1 conv + bias, (B,C,H,W) -> F layout (b,h,w,c). thread = one position.
__global__ __launch_bounds__(256) void k_conv1x1(
    const float* __restrict__ buf, const float* __restrict__ wT,
    const float* __restrict__ bias, float* __restrict__ F)
{
    int p = blockIdx.x * 256 + threadIdx.x;          // 0..B*H*W-1
    int b = p / (HH*WW);
    int rem = p - b*(HH*WW);
    const float* ip = &buf[(size_t)b*CC*HH*WW + rem];
    float acc[64];
#pragma unroll
    for (int j = 0; j < 64; ++j) acc[j] = bias[j];
    for (int ci = 0; ci < CC; ++ci) {
        float v = ip[(size_t)ci*HH*WW];
        const float* wp = &wT[ci*64];
#pragma unroll
        for (int j = 0; j < 64; ++j) acc[j] += v * wp[j];
    }
    float4* op = (float4*)&F[(size_t)p*64];
#pragma unroll
    for (int j = 0; j < 16; ++j)
        op[j] = make_float4(acc[4*j], acc[4*j+1], acc[4*j+2], acc[4*j+3]);
}

// ---------------------------------------------------------------------------
// XOR swizzle for 64-wide f32 LDS tiles read as float4 from 16 distinct rows.
// XOR value is a multiple of 4 -> 4-aligned float groups stay contiguous.
__device__ __forceinline__ int swz(int r, int c) {
    return r*64 + (c ^ (((r >> 2) & 7) << 2));
}

// S[row] (320x320) = F0row (320x64) @ F1row^T. grid: (5 wt, 5 vt, 1024 rows)
__global__ __launch_bounds__(256) void k_sgemm(
    const float* __restrict__ F0, const float* __restrict__ F1,
    float* __restrict__ S)
{
    __shared__ __align__(16) float A[64*64];
    __shared__ __align__(16) float Bt[64*64];
    const int wt = blockIdx.x, vt = blockIdx.y, row = blockIdx.z;
    const int tid = threadIdx.x;
    const float4* f04 = (const float4*)&F0[((size_t)row*WW + wt*64)*64];
    const float4* f14 = (const float4*)&F1[((size_t)row*WW + vt*64)*64];
    for (int e = tid; e < 1024; e += 256) {
        int i = e >> 4, c4 = (e & 15) * 4;
        *(float4*)&A[swz(i, c4)]  = f04[e];
        *(float4*)&Bt[swz(i, c4)] = f14[e];
    }
    __syncthreads();

    const int wq = tid >> 4, vq = tid & 15;
    float acc[4][4];
#pragma unroll
    for (int i = 0; i < 4; ++i)
#pragma unroll
        for (int j = 0; j < 4; ++j) acc[i][j] = 0.f;

#pragma unroll
    for (int k4 = 0; k4 < 16; ++k4) {
        float4 a[4], bb[4];
#pragma unroll
        for (int i = 0; i < 4; ++i) {
            int r = wq*4 + i;
            a[i] = *(const float4*)&A[r*64 + ((k4*4) ^ (((r>>2)&7)<<2))];
        }
#pragma unroll
        for (int j = 0; j < 4; ++j) {
            int r = vq*4 + j;
            bb[j] = *(const float4*)&Bt[r*64 + ((k4*4) ^ (((r>>2)&7)<<2))];
        }
#pragma unroll
        for (int i = 0; i < 4; ++i)
#pragma unroll
            for (int j = 0; j < 4; ++j)
                acc[i][j] += a[i].x*bb[j].x + a[i].y*bb[j].y
                           + a[i].z*bb[j].z + a[i].w*bb[j].w;
    }

    float* sp = &S[((size_t)row*WW + wt*64)*WW + vt*64];
#pragma unroll
    for (int i = 0; i < 4; ++i)
        *(float4*)&sp[(size_t)(wq*4 + i)*WW + vq*4] =
            make_float4(acc[i][0], acc[i][1], acc[i][2], acc[i][3]);
}

// ---------------------------------------------------------------------------
// Dual softmax per row. Pass 1: ONE merged sweep with branchless online
// max+sum for both the owned column (coalesced) and the owned row (float4).
// Pass 2: normalize, transpose-write Ml2r, accumulate V.
__global__ __launch_bounds__(320) void k_softmax(
    float* __restrict__ S, float* __restrict__ Ml2r, float* __restrict__ Vout)
{
    __shared__ float rowmax[320], rowinv[320], colmax[320], colinv[320];
    __shared__ float T[64*65];
    __shared__ float Vp2[5*64];
    const int row = blockIdx.x;
    const int tid = threadIdx.x;
    float* Srow = &S[(size_t)row * WW * WW];

    // ---- pass 1: online stats, 2x S traffic total
    float cm = -1e30f, cl = 0.f, rm = -1e30f, rl = 0.f;
    const float4* rp = (const float4*)&Srow[(size_t)tid*WW];
    const float* cp = &Srow[tid];
#pragma unroll 2
    for (int i = 0; i < 80; ++i) {
        float c0 = cp[(size_t)(4*i+0)*WW];
        float c1 = cp[(size_t)(4*i+1)*WW];
        float c2 = cp[(size_t)(4*i+2)*WW];
        float c3 = cp[(size_t)(4*i+3)*WW];
        float4 s = rp[i];
        float cm2 = fmaxf(fmaxf(fmaxf(cm, c0), c1), fmaxf(c2, c3));
        cl = cl*__expf(cm - cm2) + __expf(c0 - cm2) + __expf(c1 - cm2)
           + __expf(c2 - cm2) + __expf(c3 - cm2);
        cm = cm2;
        float rm2 = fmaxf(fmaxf(rm, fmaxf(s.x, s.y)), fmaxf(s.z, s.w));
        rl = rl*__expf(rm - rm2) + __expf(s.x - rm2) + __expf(s.y - rm2)
           + __expf(s.z - rm2) + __expf(s.w - rm2);
        rm = rm2;
    }
    rowmax[tid] = rm; rowinv[tid] = 1.f / rl;
    colmax[tid] = cm; colinv[tid] = 1.f / cl;
    __syncthreads();

    // ---- pass 2: normalize, transpose-write Ml2r, accumulate V
    const int myw = tid & 63;
    const int myg = tid / 64;          // 0..4
    for (int wt = 0; wt < 5; ++wt) {
        float vpart = 0.f;
        for (int vt = 0; vt < 5; ++vt) {
            for (int e = tid; e < 4096; e += 320) {
                int i = e >> 6, j = e & 63;
                int wgl = wt*64 + i, vgl = vt*64 + j;
                size_t si = (size_t)wgl*WW + vgl;
                float s = Srow[si];
                Srow[si] = __expf(s - rowmax[wgl]) * rowinv[wgl];
                T[j*65 + i] = __expf(s - colmax[vgl]) * colinv[vgl];
            }
            __syncthreads();
            for (int e = tid; e < 4096; e += 320) {
                int vr = e >> 6, wc = e & 63;
                Ml2r[((size_t)row*WW + vt*64 + vr)*WW + wt*64 + wc] = T[vr*65 + wc];
            }
            for (int j = myg; j < 64; j += 5) vpart += T[j*65 + myw];
            __syncthreads();
        }
        Vp2[myg*64 + myw] = vpart;
        __syncthreads();
        if (tid < 64) {
            float sv = 0.f;
#pragma unroll
            for (int g = 0; g < 5; ++g) sv += Vp2[g*64 + tid];
            Vout[(size_t)row*WW + wt*64 + tid] = (sv > 0.1f) ? 1.f : 0.f;
        }
        __syncthreads();
    }
}

// ---------------------------------------------------------------------------
// out_f[b,c,h,w] = sum_v M[row][w][v] * x_right[b,c,h,v]. grid: (5 wt, 1024)
__global__ __launch_bounds__(256) void k_outgemm(
    const float* __restrict__ M, const float* __restrict__ xr,
    float* __restrict__ outf)
{
    __shared__ __align__(16) float A[64*64];    // M tile  [w][v]
    __shared__ __align__(16) float Bt[64*64];   // xr tile [c][v]
    const int wt = blockIdx.x;
    const int row = blockIdx.y;
    const int b = row >> 7, h = row & 127;
    const int tid = threadIdx.x;
    const int wq = tid & 15, cq = tid >> 4;

    float acc[4][4];
#pragma unroll
    for (int i = 0; i < 4; ++i)
#pragma unroll
        for (int j = 0; j < 4; ++j) acc[i][j] = 0.f;

    for (int vt = 0; vt < 5; ++vt) {
        for (int e = tid; e < 1024; e += 256) {
            int i = e >> 4, k4 = (e & 15) * 4;
            *(float4*)&A[swz(i, k4)] =
                *(const float4*)&M[((size_t)row*WW + wt*64 + i)*WW + vt*64 + k4];
            *(float4*)&Bt[swz(i, k4)] =
                *(const float4*)&xr[(((size_t)b*CC + i)*HH + h)*WW + vt*64 + k4];
        }
        __syncthreads();
#pragma unroll
        for (int k4 = 0; k4 < 16; ++k4) {
            float4 a[4], bb[4];
#pragma unroll
            for (int i = 0; i < 4; ++i) {
                int r = wq + 16*i;
                a[i] = *(const float4*)&A[r*64 + ((k4*4) ^ (((r>>2)&7)<<2))];
            }
#pragma unroll
            for (int j = 0; j < 4; ++j) {
                int r = cq + 16*j;
                bb[j] = *(const float4*)&Bt[r*64 + ((k4*4) ^ (((r>>2)&7)<<2))];
            }
#pragma unroll
            for (int i = 0; i < 4; ++i)
#pragma unroll
                for (int j = 0; j < 4; ++j)
                    acc[i][j] += a[i].x*bb[j].x + a[i].y*bb[j].y
                               + a[i].z*bb[j].z + a[i].w*bb[j].w;
        }
        __syncthreads();
    }

#pragma unroll
    for (int j = 0; j < 4; ++j) {
        int c = cq + 16*j;
#pragma unroll
        for (int i = 0; i < 4; ++i) {
            int w = wt*64 + wq + 16*i;
            outf[(((size_t)b*CC + c)*HH + h)*WW + w] = acc[i][j];
        }
    }
}

// ---------------------------------------------------------------------------
extern "C" void kernel_launch(void* const* d_in, const int* in_sizes, int n_in,
                              void* d_out, int out_size, void* d_ws, size_t ws_size,
                              hipStream_t stream)
{
    const float* x_l = (const float*)d_in[0];
    const float* x_r = (const float*)d_in[1];
    const float* w1  = (const float*)d_in[2];
    const float* w2  = (const float*)d_in[3];
    const float* wl  = (const float*)d_in[4];
    const float* bl  = (const float*)d_in[5];
    const float* wr  = (const float*)d_in[6];
    const float* br  = (const float*)d_in[7];
    float* out = (float*)d_out;

    float* outf = out;
    float* Vp   = out + OFF_V;
    float* Ml2r = out + OFF_ML2R;
    float* Mr2l = out + OFF_MR2L;

    // scratch carved from output regions (everything rewritten later)
    float* r_l  = Ml2r;
    float* r_r  = Ml2r + (size_t)N_OUTF;
    float* bufl = Ml2r + 2*(size_t)N_OUTF;
    float* bufr = Ml2r + 3*(size_t)N_OUTF;
    float* F0   = Ml2r;                      // reuses r_l slot
    float* F1   = Ml2r + (size_t)N_OUTF;     // reuses r_r slot
    float* S    = Mr2l;
    float* WT   = out + ((size_t)OUT_TOTAL - WT_FLOATS);  // tail of Mr2l
    float* wT1 = WT, *wT2 = WT + 36864, *wlT = WT + 73728, *wrT = WT + 77824;

    k_wt<<<64, 256, 0, stream>>>(w1, w2, wl, wr, WT);

    dim3 cgrid(WW/64, HH/2, BB);
    k_conv3x3<<<cgrid, 256, 0, stream>>>(x_l, wT1, x_l, r_l, 0);
    k_conv3x3<<<cgrid, 256, 0, stream>>>(x_r, wT1, x_r, r_r, 0);
    k_conv3x3<<<cgrid, 256, 0, stream>>>(r_l, wT2, x_l, bufl, 1);
    k_conv3x3<<<cgrid, 256, 0, stream>>>(r_r, wT2, x_r, bufr, 1);

    int pblocks = (BB*HH*WW) / 256;          // 1280
    k_conv1x1<<<pblocks, 256, 0, stream>>>(bufl, wlT, bl, F0);
    k_conv1x1<<<pblocks, 256, 0, stream>>>(bufr, wrT, br, F1);

    dim3 sgrid(5, 5, BB*HH);
    k_sgemm<<<sgrid, 256, 0, stream>>>(F0, F1, S);

    k_softmax<<<BB*HH, 320, 0, stream>>>(S, Ml2r, Vp);

    dim3 ogrid(5, BB*HH);
    k_outgemm<<<ogrid, 256, 0, stream>>>(Mr2l, x_r, outf);
}

// Round 5
// 2282.870 us; speedup vs baseline: 2.1892x; 1.8855x over previous
//
#include <hip/hip_runtime.h>

#define BB 8
#define CC 64
#define HH 128
#define WW 320

// float offsets inside d_out
#define N_OUTF (BB*CC*HH*WW)           // 20,971,520
#define N_V    (BB*HH*WW)              // 327,680
#define N_M    (BB*HH*WW*WW)           // 104,857,600
#define OFF_V    (N_OUTF)
#define OFF_ML2R (N_OUTF + N_V)        // 21,299,200
#define OFF_MR2L (OFF_ML2R + N_M)      // 126,156,800
#define OUT_TOTAL (OFF_MR2L + N_M)     // 231,014,400
// weight tail (floats) in Ml2r region: wlT + wrT + 4x fp16 conv weight arrays
#define WT_FLOATS (4096 + 4096 + 4*18432)          // 81,920
#define NCL 20971520                   // halfs per channels-last buffer
#define INV512 (1.f/512.f)

typedef _Float16 half8 __attribute__((ext_vector_type(8)));
typedef float f32x4 __attribute__((ext_vector_type(4)));

// ---------------------------------------------------------------------------
// Weights prep: wl/wr [co][ci] -> fp32 [ci][co];
// rb_w -> fp16 hi/lo pairs [co][tap][ci], lo pre-scaled by 512.
__global__ __launch_bounds__(256) void k_wt(
    const float* __restrict__ w1, const float* __restrict__ w2,
    const float* __restrict__ wl, const float* __restrict__ wr,
    float* __restrict__ wlT, float* __restrict__ wrT,
    _Float16* __restrict__ wB1h, _Float16* __restrict__ wB1l,
    _Float16* __restrict__ wB2h, _Float16* __restrict__ wB2l)
{
    int tid = blockIdx.x * 256 + threadIdx.x;
    int stride = gridDim.x * 256;
    for (int e = tid; e < 64*9*64; e += stride) {   // e = co*576 + tap*64 + ci
        int co = e / 576;
        int rem = e - co*576;
        int tap = rem >> 6, ci = rem & 63;
        float v1 = w1[(co*64 + ci)*9 + tap];
        float v2 = w2[(co*64 + ci)*9 + tap];
        _Float16 h1 = (_Float16)v1, h2 = (_Float16)v2;
        wB1h[e] = h1; wB1l[e] = (_Float16)((v1 - (float)h1)*512.f);
        wB2h[e] = h2; wB2l[e] = (_Float16)((v2 - (float)h2)*512.f);
    }
    for (int e = tid; e < 4096; e += stride) {
        int co = e >> 6, ci = e & 63;
        wlT[ci*64 + co] = wl[e];
        wrT[ci*64 + co] = wr[e];
    }
}

// ---------------------------------------------------------------------------
// NCHW fp32 -> channels-last fp16 hi/lo [b][y][x][ci]. grid (5,128,8), 256thr
__global__ __launch_bounds__(256) void k_prep(
    const float* __restrict__ in,
    _Float16* __restrict__ oh, _Float16* __restrict__ ol)
{
    __shared__ float t[64][65];
    const int tid = threadIdx.x;
    const int x0 = blockIdx.x * 64, y = blockIdx.y, b = blockIdx.z;
    for (int e = tid; e < 4096; e += 256) {
        int ci = e >> 6, x = e & 63;
        t[ci][x] = in[((size_t)(b*64 + ci)*HH + y)*WW + x0 + x];
    }
    __syncthreads();
#pragma unroll
    for (int i = 0; i < 2; ++i) {
        int unit = tid + 256*i;            // 0..511
        int x = unit >> 3, u = unit & 7;
        half8 hh, hl;
#pragma unroll
        for (int j = 0; j < 8; ++j) {
            float v = t[u*8 + j][x];
            _Float16 h = (_Float16)v;
            hh[j] = h;
            hl[j] = (_Float16)((v - (float)h)*512.f);
        }
        size_t g = (((size_t)(b*HH + y)*WW) + x0 + x)*64 + u*8;
        *(half8*)&oh[g] = hh;
        *(half8*)&ol[g] = hl;
    }
}

// ---------------------------------------------------------------------------
// Split-fp16 MFMA 3x3 conv, 64->64, pad 1, channels-last hi/lo.
// acc_main += ah*wh ; acc_corr += al*wh + ah*wl ; out = main + corr/512.
// wave n = co-tile (16 co); 4 x-tiles of 16 per wave; K = 9 taps x 64 ci.
// mode 0: LeakyReLU(0.1). mode 1: += residual (hi/lo).
__global__ __launch_bounds__(256) void k_conv3(
    const _Float16* __restrict__ in_h, const _Float16* __restrict__ in_l,
    const _Float16* __restrict__ wBh, const _Float16* __restrict__ wBl,
    const _Float16* __restrict__ res_h, const _Float16* __restrict__ res_l,
    _Float16* __restrict__ out_h, _Float16* __restrict__ out_l, int mode)
{
    // hi tile [3][66][64ci], lo tile; 16B-unit swizzle u^=(xx&7).
    // out tiles alias the input tiles after the MFMA loop (barrier-guarded).
    __shared__ __align__(16) char smem[2*3*66*128];    // 50688 B
    char* in_sh = smem;
    char* in_sl = smem + 25344;
    const int tid = threadIdx.x;
    const int x0 = blockIdx.x * 64;
    const int y  = blockIdx.y;
    const int b  = blockIdx.z;
    const int lane = tid & 63;
    const int xq = lane & 15, kq = lane >> 4;
    const int n = tid >> 6;                            // wave = co-tile

    // B-frags for this wave's 16 co: 9 taps x 2 k-chunks, hi and lo
    half8 bwh[18], bwl[18];
    {
        const _Float16* wbh = &wBh[((size_t)(n*16 + xq)*9)*64 + kq*8];
        const _Float16* wbl = &wBl[((size_t)(n*16 + xq)*9)*64 + kq*8];
#pragma unroll
        for (int t = 0; t < 9; ++t)
#pragma unroll
            for (int c = 0; c < 2; ++c) {
                bwh[t*2 + c] = *(const half8*)&wbh[t*64 + c*32];
                bwl[t*2 + c] = *(const half8*)&wbl[t*64 + c*32];
            }
    }

    // stage input tiles (halo of 1 in x and y, zeros outside)
    for (int e = tid; e < 3*66*8; e += 256) {
        int ry = e / 528;
        int rem = e - ry*528;
        int xx = rem >> 3, u = rem & 7;
        int gy = y + ry - 1, gx = x0 + xx - 1;
        uint4 vh = make_uint4(0u,0u,0u,0u), vl = make_uint4(0u,0u,0u,0u);
        if ((unsigned)gy < (unsigned)HH && (unsigned)gx < (unsigned)WW) {
            size_t g = (((size_t)(b*HH + gy)*WW) + gx)*64 + u*8;
            vh = *(const uint4*)&in_h[g];
            vl = *(const uint4*)&in_l[g];
        }
        int off = ((ry*66 + xx)*8 + (u ^ (xx & 7)))*16;
        *(uint4*)&in_sh[off] = vh;
        *(uint4*)&in_sl[off] = vl;
    }
    __syncthreads();

    f32x4 accm[4], accc[4];
#pragma unroll
    for (int m = 0; m < 4; ++m) { accm[m] = (f32x4)0.f; accc[m] = (f32x4)0.f; }

#pragma unroll
    for (int m = 0; m < 4; ++m) {
        const int xb = m*16 + xq;
#pragma unroll
        for (int t = 0; t < 9; ++t) {
            const int ry = t / 3, kx = t - ry*3;
            const int xxx = xb + kx;
#pragma unroll
            for (int c = 0; c < 2; ++c) {
                const int u = c*4 + kq;
                int off = ((ry*66 + xxx)*8 + (u ^ (xxx & 7)))*16;
                half8 ah = *(const half8*)&in_sh[off];
                half8 al = *(const half8*)&in_sl[off];
                accm[m] = __builtin_amdgcn_mfma_f32_16x16x32_f16(
                    ah, bwh[t*2 + c], accm[m], 0, 0, 0);
                accc[m] = __builtin_amdgcn_mfma_f32_16x16x32_f16(
                    al, bwh[t*2 + c], accc[m], 0, 0, 0);
                accc[m] = __builtin_amdgcn_mfma_f32_16x16x32_f16(
                    ah, bwl[t*2 + c], accc[m], 0, 0, 0);
            }
        }
    }
    __syncthreads();            // all waves done reading input tiles

    // epilogue: split to hi/lo in swizzled LDS out tiles (alias input tiles)
    char* out_sh = smem;
    char* out_sl = smem + 8192;
#pragma unroll
    for (int m = 0; m < 4; ++m) {
#pragma unroll
        for (int r = 0; r < 4; ++r) {
            int x = m*16 + kq*4 + r;          // local x
            int co = n*16 + xq;
            float v = accm[m][r] + accc[m][r]*INV512;
            if (mode == 0) v = (v > 0.f) ? v : 0.1f*v;
            _Float16 vh = (_Float16)v;
            _Float16 vl = (_Float16)((v - (float)vh)*512.f);
            int boff = (x*8 + ((co >> 3) ^ (x & 7)))*16 + (co & 7)*2;
            *(_Float16*)&out_sh[boff] = vh;
            *(_Float16*)&out_sl[boff] = vl;
        }
    }
    __syncthreads();

    // coalesced store (+ residual re-split for mode 1)
#pragma unroll
    for (int i = 0; i < 2; ++i) {
        int unit = tid + 256*i;               // 0..511
        int x = unit >> 3, u = unit & 7;
        int loff = (x*8 + (u ^ (x & 7)))*16;
        half8 vh = *(half8*)&out_sh[loff];
        half8 vl = *(half8*)&out_sl[loff];
        size_t g = (((size_t)(b*HH + y)*WW) + x0 + x)*64 + u*8;
        if (mode == 1) {
            half8 rh = *(const half8*)&res_h[g];
            half8 rl = *(const half8*)&res_l[g];
            half8 ohv, olv;
#pragma unroll
            for (int e = 0; e < 8; ++e) {
                float s = (float)vh[e] + (float)vl[e]*INV512
                        + (float)rh[e] + (float)rl[e]*INV512;
                _Float16 h = (_Float16)s;
                ohv[e] = h;
                olv[e] = (_Float16)((s - (float)h)*512.f);
            }
            *(half8*)&out_h[g] = ohv;
            *(half8*)&out_l[g] = olv;
        } else {
            *(half8*)&out_h[g] = vh;
            *(half8*)&out_l[g] = vl;
        }
    }
}

// ---------------------------------------------------------------------------
// 1x1 conv + bias: channels-last hi/lo fp16 buf -> F (b,h,w,c) fp32.
__global__ __launch_bounds__(256) void k_conv1x1(
    const _Float16* __restrict__ bh, const _Float16* __restrict__ bl,
    const float* __restrict__ wT, const float* __restrict__ bias,
    float* __restrict__ F)
{
    int p = blockIdx.x * 256 + threadIdx.x;          // 0..B*H*W-1
    const _Float16* iph = &bh[(size_t)p*64];
    const _Float16* ipl = &bl[(size_t)p*64];
    float acc[64];
#pragma unroll
    for (int j = 0; j < 64; ++j) acc[j] = bias[j];
#pragma unroll 2
    for (int cu = 0; cu < 8; ++cu) {
        half8 hh = *(const half8*)&iph[cu*8];
        half8 hl = *(const half8*)&ipl[cu*8];
#pragma unroll
        for (int e = 0; e < 8; ++e) {
            float v = (float)hh[e] + (float)hl[e]*INV512;
            const float* wp = &wT[(cu*8 + e)*64];
#pragma unroll
            for (int j = 0; j < 64; ++j) acc[j] += v * wp[j];
        }
    }
    float4* op = (float4*)&F[(size_t)p*64];
#pragma unroll
    for (int j = 0; j < 16; ++j)
        op[j] = make_float4(acc[4*j], acc[4*j+1], acc[4*j+2], acc[4*j+3]);
}

// ---------------------------------------------------------------------------
// XOR swizzle for 64-wide f32 LDS tiles read as float4 from 16 distinct rows
// at 4-consecutive-row-per-thread mapping (r>>2 distinct across lanes).
__device__ __forceinline__ int swz(int r, int c) {
    return r*64 + (c ^ (((r >> 2) & 7) << 2));
}

// S[row] (320x320) = F0row (320x64) @ F1row^T. grid: (5 wt, 5 vt, 1024 rows)
__global__ __launch_bounds__(256) void k_sgemm(
    const float* __restrict__ F0, const float* __restrict__ F1,
    float* __restrict__ S)
{
    __shared__ __align__(16) float A[64*64];
    __shared__ __align__(16) float Bt[64*64];
    const int wt = blockIdx.x, vt = blockIdx.y, row = blockIdx.z;
    const int tid = threadIdx.x;
    const float4* f04 = (const float4*)&F0[((size_t)row*WW + wt*64)*64];
    const float4* f14 = (const float4*)&F1[((size_t)row*WW + vt*64)*64];
    for (int e = tid; e < 1024; e += 256) {
        int i = e >> 4, c4 = (e & 15) * 4;
        *(float4*)&A[swz(i, c4)]  = f04[e];
        *(float4*)&Bt[swz(i, c4)] = f14[e];
    }
    __syncthreads();

    const int wq = tid >> 4, vq = tid & 15;
    float acc[4][4];
#pragma unroll
    for (int i = 0; i < 4; ++i)
#pragma unroll
        for (int j = 0; j < 4; ++j) acc[i][j] = 0.f;

#pragma unroll
    for (int k4 = 0; k4 < 16; ++k4) {
        float4 a[4], bb[4];
#pragma unroll
        for (int i = 0; i < 4; ++i) {
            int r = wq*4 + i;
            a[i] = *(const float4*)&A[r*64 + ((k4*4) ^ (((r>>2)&7)<<2))];
        }
#pragma unroll
        for (int j = 0; j < 4; ++j) {
            int r = vq*4 + j;
            bb[j] = *(const float4*)&Bt[r*64 + ((k4*4) ^ (((r>>2)&7)<<2))];
        }
#pragma unroll
        for (int i = 0; i < 4; ++i)
#pragma unroll
            for (int j = 0; j < 4; ++j)
                acc[i][j] += a[i].x*bb[j].x + a[i].y*bb[j].y
                           + a[i].z*bb[j].z + a[i].w*bb[j].w;
    }

    float* sp = &S[((size_t)row*WW + wt*64)*WW + vt*64];
#pragma unroll
    for (int i = 0; i < 4; ++i)
        *(float4*)&sp[(size_t)(wq*4 + i)*WW + vq*4] =
            make_float4(acc[i][0], acc[i][1], acc[i][2], acc[i][3]);
}

// ---------------------------------------------------------------------------
// Dual softmax per row. Pass 1: ONE merged sweep with branchless online
// max+sum for both the owned column (coalesced) and the owned row (float4).
__global__ __launch_bounds__(320) void k_softmax(
    float* __restrict__ S, float* __restrict__ Ml2r, float* __restrict__ Vout)
{
    __shared__ float rowmax[320], rowinv[320], colmax[320], colinv[320];
    __shared__ float T[64*65];
    __shared__ float Vp2[5*64];
    const int row = blockIdx.x;
    const int tid = threadIdx.x;
    float* Srow = &S[(size_t)row * WW * WW];

    float cm = -1e30f, cl = 0.f, rm = -1e30f, rl = 0.f;
    const float4* rp = (const float4*)&Srow[(size_t)tid*WW];
    const float* cp = &Srow[tid];
#pragma unroll 2
    for (int i = 0; i < 80; ++i) {
        float c0 = cp[(size_t)(4*i+0)*WW];
        float c1 = cp[(size_t)(4*i+1)*WW];
        float c2 = cp[(size_t)(4*i+2)*WW];
        float c3 = cp[(size_t)(4*i+3)*WW];
        float4 s = rp[i];
        float cm2 = fmaxf(fmaxf(fmaxf(cm, c0), c1), fmaxf(c2, c3));
        cl = cl*__expf(cm - cm2) + __expf(c0 - cm2) + __expf(c1 - cm2)
           + __expf(c2 - cm2) + __expf(c3 - cm2);
        cm = cm2;
        float rm2 = fmaxf(fmaxf(rm, fmaxf(s.x, s.y)), fmaxf(s.z, s.w));
        rl = rl*__expf(rm - rm2) + __expf(s.x - rm2) + __expf(s.y - rm2)
           + __expf(s.z - rm2) + __expf(s.w - rm2);
        rm = rm2;
    }
    rowmax[tid] = rm; rowinv[tid] = 1.f / rl;
    colmax[tid] = cm; colinv[tid] = 1.f / cl;
    __syncthreads();

    const int myw = tid & 63;
    const int myg = tid / 64;          // 0..4
    for (int wt = 0; wt < 5; ++wt) {
        float vpart = 0.f;
        for (int vt = 0; vt < 5; ++vt) {
            for (int e = tid; e < 4096; e += 320) {
                int i = e >> 6, j = e & 63;
                int wgl = wt*64 + i, vgl = vt*64 + j;
                size_t si = (size_t)wgl*WW + vgl;
                float s = Srow[si];
                Srow[si] = __expf(s - rowmax[wgl]) * rowinv[wgl];
                T[j*65 + i] = __expf(s - colmax[vgl]) * colinv[vgl];
            }
            __syncthreads();
            for (int e = tid; e < 4096; e += 320) {
                int vr = e >> 6, wc = e & 63;
                Ml2r[((size_t)row*WW + vt*64 + vr)*WW + wt*64 + wc] = T[vr*65 + wc];
            }
            for (int j = myg; j < 64; j += 5) vpart += T[j*65 + myw];
            __syncthreads();
        }
        Vp2[myg*64 + myw] = vpart;
        __syncthreads();
        if (tid < 64) {
            float sv = 0.f;
#pragma unroll
            for (int g = 0; g < 5; ++g) sv += Vp2[g*64 + tid];
            Vout[(size_t)row*WW + wt*64 + tid] = (sv > 0.1f) ? 1.f : 0.f;
        }
        __syncthreads();
    }
}

// ---------------------------------------------------------------------------
// out_f[b,c,h,w] = sum_v M[row][w][v] * x_right[b,c,h,v]. grid: (5 wt, 1024)
// thread owns 4 consecutive w (wq*4..) and 4 consecutive c (cq*4..) -> swz ok.
__global__ __launch_bounds__(256) void k_outgemm(
    const float* __restrict__ M, const float* __restrict__ xr,
    float* __restrict__ outf)
{
    __shared__ __align__(16) float A[64*64];    // M tile  [w][v]
    __shared__ __align__(16) float Bt[64*64];   // xr tile [c][v]
    const int wt = blockIdx.x;
    const int row = blockIdx.y;
    const int b = row >> 7, h = row & 127;
    const int tid = threadIdx.x;
    const int wq = tid & 15, cq = tid >> 4;

    float acc[4][4];                            // [i=w][j=c]
#pragma unroll
    for (int i = 0; i < 4; ++i)
#pragma unroll
        for (int j = 0; j < 4; ++j) acc[i][j] = 0.f;

    for (int vt = 0; vt < 5; ++vt) {
        for (int e = tid; e < 1024; e += 256) {
            int i = e >> 4, k4 = (e & 15) * 4;
            *(float4*)&A[swz(i, k4)] =
                *(const float4*)&M[((size_t)row*WW + wt*64 + i)*WW + vt*64 + k4];
            *(float4*)&Bt[swz(i, k4)] =
                *(const float4*)&xr[(((size_t)b*CC + i)*HH + h)*WW + vt*64 + k4];
        }
        __syncthreads();
#pragma unroll 4
        for (int k4 = 0; k4 < 16; ++k4) {
            float4 a[4], bb[4];
#pragma unroll
            for (int i = 0; i < 4; ++i) {
                int r = wq*4 + i;
                a[i] = *(const float4*)&A[r*64 + ((k4*4) ^ (((r>>2)&7)<<2))];
            }
#pragma unroll
            for (int j = 0; j < 4; ++j) {
                int r = cq*4 + j;
                bb[j] = *(const float4*)&Bt[r*64 + ((k4*4) ^ (((r>>2)&7)<<2))];
            }
#pragma unroll
            for (int i = 0; i < 4; ++i)
#pragma unroll
                for (int j = 0; j < 4; ++j)
                    acc[i][j] += a[i].x*bb[j].x + a[i].y*bb[j].y
                               + a[i].z*bb[j].z + a[i].w*bb[j].w;
        }
        __syncthreads();
    }

#pragma unroll
    for (int j = 0; j < 4; ++j) {
        int c = cq*4 + j;
        *(float4*)&outf[(((size_t)b*CC + c)*HH + h)*WW + wt*64 + wq*4] =
            make_float4(acc[0][j], acc[1][j], acc[2][j], acc[3][j]);
    }
}

// ---------------------------------------------------------------------------
extern "C" void kernel_launch(void* const* d_in, const int* in_sizes, int n_in,
                              void* d_out, int out_size, void* d_ws, size_t ws_size,
                              hipStream_t stream)
{
    const float* x_l = (const float*)d_in[0];
    const float* x_r = (const float*)d_in[1];
    const float* w1  = (const float*)d_in[2];
    const float* w2  = (const float*)d_in[3];
    const float* wl  = (const float*)d_in[4];
    const float* bl  = (const float*)d_in[5];
    const float* wr  = (const float*)d_in[6];
    const float* br  = (const float*)d_in[7];
    float* out = (float*)d_out;

    float* outf = out;
    float* Vp   = out + OFF_V;
    float* Ml2r = out + OFF_ML2R;
    float* Mr2l = out + OFF_MR2L;

    // hi/lo fp16 channels-last scratch: 10 buffers fill the Mr2l region
    // exactly (10 * 10,485,760 floats = N_M). All dead before sgemm writes S.
    _Float16* base = (_Float16*)Mr2l;
    _Float16* xl_h = base + 0*(size_t)NCL;
    _Float16* xl_l = base + 1*(size_t)NCL;
    _Float16* xr_h = base + 2*(size_t)NCL;
    _Float16* xr_l = base + 3*(size_t)NCL;
    _Float16* r_h  = base + 4*(size_t)NCL;
    _Float16* r_l  = base + 5*(size_t)NCL;
    _Float16* bl_h = base + 6*(size_t)NCL;
    _Float16* bl_l = base + 7*(size_t)NCL;
    _Float16* br_h = base + 8*(size_t)NCL;
    _Float16* br_l = base + 9*(size_t)NCL;
    // F0/F1 fp32 at the start of Ml2r; weights at its tail (both dead
    // before softmax overwrites Ml2r).
    float* F0 = Ml2r;
    float* F1 = Ml2r + (size_t)N_OUTF;
    float* S  = Mr2l;
    float* WT  = Ml2r + (size_t)N_M - WT_FLOATS;
    float* wlT = WT;
    float* wrT = WT + 4096;
    _Float16* wB1h = (_Float16*)(WT + 8192);
    _Float16* wB1l = wB1h + 36864;
    _Float16* wB2h = wB1l + 36864;
    _Float16* wB2l = wB2h + 36864;

    k_wt<<<64, 256, 0, stream>>>(w1, w2, wl, wr, wlT, wrT,
                                 wB1h, wB1l, wB2h, wB2l);

    dim3 pgrid(WW/64, HH, BB);
    k_prep<<<pgrid, 256, 0, stream>>>(x_l, xl_h, xl_l);
    k_prep<<<pgrid, 256, 0, stream>>>(x_r, xr_h, xr_l);

    k_conv3<<<pgrid, 256, 0, stream>>>(xl_h, xl_l, wB1h, wB1l,
                                       xl_h, xl_l, r_h, r_l, 0);
    k_conv3<<<pgrid, 256, 0, stream>>>(r_h, r_l, wB2h, wB2l,
                                       xl_h, xl_l, bl_h, bl_l, 1);
    k_conv3<<<pgrid, 256, 0, stream>>>(xr_h, xr_l, wB1h, wB1l,
                                       xr_h, xr_l, r_h, r_l, 0);
    k_conv3<<<pgrid, 256, 0, stream>>>(r_h, r_l, wB2h, wB2l,
                                       xr_h, xr_l, br_h, br_l, 1);

    int pblocks = (BB*HH*WW) / 256;          // 1280
    k_conv1x1<<<pblocks, 256, 0, stream>>>(bl_h, bl_l, wlT, bl, F0);
    k_conv1x1<<<pblocks, 256, 0, stream>>>(br_h, br_l, wrT, br, F1);

    dim3 sgrid(5, 5, BB*HH);
    k_sgemm<<<sgrid, 256, 0, stream>>>(F0, F1, S);

    k_softmax<<<BB*HH, 320, 0, stream>>>(S, Ml2r, Vp);

    dim3 ogrid(5, BB*HH);
    k_outgemm<<<ogrid, 256, 0, stream>>>(Mr2l, x_r, outf);
}

// Round 6
// 1705.978 us; speedup vs baseline: 2.9295x; 1.3382x over previous
//
#include <hip/hip_runtime.h>

#define BB 8
#define CC 64
#define HH 128
#define WW 320

// float offsets inside d_out
#define N_OUTF (BB*CC*HH*WW)           // 20,971,520
#define N_V    (BB*HH*WW)              // 327,680
#define N_M    (BB*HH*WW*WW)           // 104,857,600
#define OFF_V    (N_OUTF)
#define OFF_ML2R (N_OUTF + N_V)        // 21,299,200
#define OFF_MR2L (OFF_ML2R + N_M)      // 126,156,800
#define OUT_TOTAL (OFF_MR2L + N_M)     // 231,014,400
// weight tail (floats) in Ml2r region: wlT + wrT + 4x fp16 conv weight arrays
#define WT_FLOATS (4096 + 4096 + 4*18432)          // 81,920
#define NCL 20971520                   // halfs per channels-last buffer
#define INV512 (1.f/512.f)

typedef _Float16 half8 __attribute__((ext_vector_type(8)));
typedef float f32x4 __attribute__((ext_vector_type(4)));

// ---------------------------------------------------------------------------
// Weights prep: wl/wr [co][ci] -> fp32 [ci][co];
// rb_w -> fp16 hi/lo pairs [co][tap][ci], lo pre-scaled by 512.
__global__ __launch_bounds__(256) void k_wt(
    const float* __restrict__ w1, const float* __restrict__ w2,
    const float* __restrict__ wl, const float* __restrict__ wr,
    float* __restrict__ wlT, float* __restrict__ wrT,
    _Float16* __restrict__ wB1h, _Float16* __restrict__ wB1l,
    _Float16* __restrict__ wB2h, _Float16* __restrict__ wB2l)
{
    int tid = blockIdx.x * 256 + threadIdx.x;
    int stride = gridDim.x * 256;
    for (int e = tid; e < 64*9*64; e += stride) {   // e = co*576 + tap*64 + ci
        int co = e / 576;
        int rem = e - co*576;
        int tap = rem >> 6, ci = rem & 63;
        float v1 = w1[(co*64 + ci)*9 + tap];
        float v2 = w2[(co*64 + ci)*9 + tap];
        _Float16 h1 = (_Float16)v1, h2 = (_Float16)v2;
        wB1h[e] = h1; wB1l[e] = (_Float16)((v1 - (float)h1)*512.f);
        wB2h[e] = h2; wB2l[e] = (_Float16)((v2 - (float)h2)*512.f);
    }
    for (int e = tid; e < 4096; e += stride) {
        int co = e >> 6, ci = e & 63;
        wlT[ci*64 + co] = wl[e];
        wrT[ci*64 + co] = wr[e];
    }
}

// ---------------------------------------------------------------------------
// NCHW fp32 -> channels-last fp16 hi/lo [b][y][x][ci]. grid (5,128,8), 256thr
__global__ __launch_bounds__(256) void k_prep(
    const float* __restrict__ in,
    _Float16* __restrict__ oh, _Float16* __restrict__ ol)
{
    __shared__ float t[64][65];
    const int tid = threadIdx.x;
    const int x0 = blockIdx.x * 64, y = blockIdx.y, b = blockIdx.z;
    for (int e = tid; e < 4096; e += 256) {
        int ci = e >> 6, x = e & 63;
        t[ci][x] = in[((size_t)(b*64 + ci)*HH + y)*WW + x0 + x];
    }
    __syncthreads();
#pragma unroll
    for (int i = 0; i < 2; ++i) {
        int unit = tid + 256*i;            // 0..511
        int x = unit >> 3, u = unit & 7;
        half8 hh, hl;
#pragma unroll
        for (int j = 0; j < 8; ++j) {
            float v = t[u*8 + j][x];
            _Float16 h = (_Float16)v;
            hh[j] = h;
            hl[j] = (_Float16)((v - (float)h)*512.f);
        }
        size_t g = (((size_t)(b*HH + y)*WW) + x0 + x)*64 + u*8;
        *(half8*)&oh[g] = hh;
        *(half8*)&ol[g] = hl;
    }
}

// ---------------------------------------------------------------------------
// Split-fp16 MFMA 3x3 conv, 64->64, pad 1, channels-last hi/lo.
__global__ __launch_bounds__(256) void k_conv3(
    const _Float16* __restrict__ in_h, const _Float16* __restrict__ in_l,
    const _Float16* __restrict__ wBh, const _Float16* __restrict__ wBl,
    const _Float16* __restrict__ res_h, const _Float16* __restrict__ res_l,
    _Float16* __restrict__ out_h, _Float16* __restrict__ out_l, int mode)
{
    __shared__ __align__(16) char smem[2*3*66*128];    // 50688 B
    char* in_sh = smem;
    char* in_sl = smem + 25344;
    const int tid = threadIdx.x;
    const int x0 = blockIdx.x * 64;
    const int y  = blockIdx.y;
    const int b  = blockIdx.z;
    const int lane = tid & 63;
    const int xq = lane & 15, kq = lane >> 4;
    const int n = tid >> 6;                            // wave = co-tile

    half8 bwh[18], bwl[18];
    {
        const _Float16* wbh = &wBh[((size_t)(n*16 + xq)*9)*64 + kq*8];
        const _Float16* wbl = &wBl[((size_t)(n*16 + xq)*9)*64 + kq*8];
#pragma unroll
        for (int t = 0; t < 9; ++t)
#pragma unroll
            for (int c = 0; c < 2; ++c) {
                bwh[t*2 + c] = *(const half8*)&wbh[t*64 + c*32];
                bwl[t*2 + c] = *(const half8*)&wbl[t*64 + c*32];
            }
    }

    for (int e = tid; e < 3*66*8; e += 256) {
        int ry = e / 528;
        int rem = e - ry*528;
        int xx = rem >> 3, u = rem & 7;
        int gy = y + ry - 1, gx = x0 + xx - 1;
        uint4 vh = make_uint4(0u,0u,0u,0u), vl = make_uint4(0u,0u,0u,0u);
        if ((unsigned)gy < (unsigned)HH && (unsigned)gx < (unsigned)WW) {
            size_t g = (((size_t)(b*HH + gy)*WW) + gx)*64 + u*8;
            vh = *(const uint4*)&in_h[g];
            vl = *(const uint4*)&in_l[g];
        }
        int off = ((ry*66 + xx)*8 + (u ^ (xx & 7)))*16;
        *(uint4*)&in_sh[off] = vh;
        *(uint4*)&in_sl[off] = vl;
    }
    __syncthreads();

    f32x4 accm[4], accc[4];
#pragma unroll
    for (int m = 0; m < 4; ++m) { accm[m] = (f32x4)0.f; accc[m] = (f32x4)0.f; }

#pragma unroll
    for (int m = 0; m < 4; ++m) {
        const int xb = m*16 + xq;
#pragma unroll
        for (int t = 0; t < 9; ++t) {
            const int ry = t / 3, kx = t - ry*3;
            const int xxx = xb + kx;
#pragma unroll
            for (int c = 0; c < 2; ++c) {
                const int u = c*4 + kq;
                int off = ((ry*66 + xxx)*8 + (u ^ (xxx & 7)))*16;
                half8 ah = *(const half8*)&in_sh[off];
                half8 al = *(const half8*)&in_sl[off];
                accm[m] = __builtin_amdgcn_mfma_f32_16x16x32_f16(
                    ah, bwh[t*2 + c], accm[m], 0, 0, 0);
                accc[m] = __builtin_amdgcn_mfma_f32_16x16x32_f16(
                    al, bwh[t*2 + c], accc[m], 0, 0, 0);
                accc[m] = __builtin_amdgcn_mfma_f32_16x16x32_f16(
                    ah, bwl[t*2 + c], accc[m], 0, 0, 0);
            }
        }
    }
    __syncthreads();            // all waves done reading input tiles

    char* out_sh = smem;
    char* out_sl = smem + 8192;
#pragma unroll
    for (int m = 0; m < 4; ++m) {
#pragma unroll
        for (int r = 0; r < 4; ++r) {
            int x = m*16 + kq*4 + r;          // local x
            int co = n*16 + xq;
            float v = accm[m][r] + accc[m][r]*INV512;
            if (mode == 0) v = (v > 0.f) ? v : 0.1f*v;
            _Float16 vh = (_Float16)v;
            _Float16 vl = (_Float16)((v - (float)vh)*512.f);
            int boff = (x*8 + ((co >> 3) ^ (x & 7)))*16 + (co & 7)*2;
            *(_Float16*)&out_sh[boff] = vh;
            *(_Float16*)&out_sl[boff] = vl;
        }
    }
    __syncthreads();

#pragma unroll
    for (int i = 0; i < 2; ++i) {
        int unit = tid + 256*i;               // 0..511
        int x = unit >> 3, u = unit & 7;
        int loff = (x*8 + (u ^ (x & 7)))*16;
        half8 vh = *(half8*)&out_sh[loff];
        half8 vl = *(half8*)&out_sl[loff];
        size_t g = (((size_t)(b*HH + y)*WW) + x0 + x)*64 + u*8;
        if (mode == 1) {
            half8 rh = *(const half8*)&res_h[g];
            half8 rl = *(const half8*)&res_l[g];
            half8 ohv, olv;
#pragma unroll
            for (int e = 0; e < 8; ++e) {
                float s = (float)vh[e] + (float)vl[e]*INV512
                        + (float)rh[e] + (float)rl[e]*INV512;
                _Float16 h = (_Float16)s;
                ohv[e] = h;
                olv[e] = (_Float16)((s - (float)h)*512.f);
            }
            *(half8*)&out_h[g] = ohv;
            *(half8*)&out_l[g] = olv;
        } else {
            *(half8*)&out_h[g] = vh;
            *(half8*)&out_l[g] = vl;
        }
    }
}

// ---------------------------------------------------------------------------
// 1x1 conv + bias: channels-last hi/lo fp16 buf -> F hi/lo fp16 (b,h,w,c).
__global__ __launch_bounds__(256) void k_conv1x1(
    const _Float16* __restrict__ bh, const _Float16* __restrict__ bl,
    const float* __restrict__ wT, const float* __restrict__ bias,
    _Float16* __restrict__ Fh, _Float16* __restrict__ Fl)
{
    int p = blockIdx.x * 256 + threadIdx.x;          // 0..B*H*W-1
    const _Float16* iph = &bh[(size_t)p*64];
    const _Float16* ipl = &bl[(size_t)p*64];
    float acc[64];
#pragma unroll
    for (int j = 0; j < 64; ++j) acc[j] = bias[j];
#pragma unroll 2
    for (int cu = 0; cu < 8; ++cu) {
        half8 hh = *(const half8*)&iph[cu*8];
        half8 hl = *(const half8*)&ipl[cu*8];
#pragma unroll
        for (int e = 0; e < 8; ++e) {
            float v = (float)hh[e] + (float)hl[e]*INV512;
            const float* wp = &wT[(cu*8 + e)*64];
#pragma unroll
            for (int j = 0; j < 64; ++j) acc[j] += v * wp[j];
        }
    }
#pragma unroll
    for (int u = 0; u < 8; ++u) {
        half8 hh, hl;
#pragma unroll
        for (int j = 0; j < 8; ++j) {
            float v = acc[u*8 + j];
            _Float16 h = (_Float16)v;
            hh[j] = h;
            hl[j] = (_Float16)((v - (float)h)*512.f);
        }
        *(half8*)&Fh[(size_t)p*64 + u*8] = hh;
        *(half8*)&Fl[(size_t)p*64 + u*8] = hl;
    }
}

// ---------------------------------------------------------------------------
// Split-fp16 MFMA S-GEMM + fused softmax stats.
// S tile 64x64 = F0[wt-strip] @ F1[vt-strip]^T, K=64. grid (5,5,1024), 4 wav.
// Writes S fp32 and per-tile partial stats:
//   rowmax_p/rowsum_p [row][vt][320]  (full row-in-tile reduce, over 64 v)
//   colmax_p/colsum_p [row][wt][320]  (full col-in-tile reduce, over 64 w)
__global__ __launch_bounds__(256) void k_sgemm(
    const _Float16* __restrict__ F0h, const _Float16* __restrict__ F0l,
    const _Float16* __restrict__ F1h, const _Float16* __restrict__ F1l,
    float* __restrict__ S,
    float* __restrict__ colmax_p, float* __restrict__ colsum_p,
    float* __restrict__ rowmax_p, float* __restrict__ rowsum_p)
{
    __shared__ __align__(16) char Ah[8192], Al[8192], Bh[8192], Bl[8192];
    __shared__ float cpm[4][64], cpl[4][64];
    const int wt = blockIdx.x, vt = blockIdx.y, row = blockIdx.z;
    const int tid = threadIdx.x, lane = tid & 63, wid = tid >> 6;

    for (int e = tid; e < 512; e += 256) {
        int i = e >> 3, u = e & 7;
        size_t ga = ((size_t)row*WW + wt*64 + i)*64 + u*8;
        size_t gb = ((size_t)row*WW + vt*64 + i)*64 + u*8;
        int off = (i*8 + (u ^ (i & 7)))*16;
        *(uint4*)&Ah[off] = *(const uint4*)&F0h[ga];
        *(uint4*)&Al[off] = *(const uint4*)&F0l[ga];
        *(uint4*)&Bh[off] = *(const uint4*)&F1h[gb];
        *(uint4*)&Bl[off] = *(const uint4*)&F1l[gb];
    }
    __syncthreads();

    f32x4 accm[4], accc[4];
#pragma unroll
    for (int n = 0; n < 4; ++n) { accm[n] = (f32x4)0.f; accc[n] = (f32x4)0.f; }

#pragma unroll
    for (int c = 0; c < 2; ++c) {
        const int u = c*4 + (lane >> 4);
        const int arow = wid*16 + (lane & 15);
        int aoff = (arow*8 + (u ^ (arow & 7)))*16;
        half8 ah = *(const half8*)&Ah[aoff];
        half8 al = *(const half8*)&Al[aoff];
#pragma unroll
        for (int n = 0; n < 4; ++n) {
            const int brow = n*16 + (lane & 15);
            int boff = (brow*8 + (u ^ (brow & 7)))*16;
            half8 bh = *(const half8*)&Bh[boff];
            half8 bl = *(const half8*)&Bl[boff];
            accm[n] = __builtin_amdgcn_mfma_f32_16x16x32_f16(ah, bh, accm[n], 0,0,0);
            accc[n] = __builtin_amdgcn_mfma_f32_16x16x32_f16(al, bh, accc[n], 0,0,0);
            accc[n] = __builtin_amdgcn_mfma_f32_16x16x32_f16(ah, bl, accc[n], 0,0,0);
        }
    }

    // final S values: frag n, reg r -> (w = wid*16+(lane>>4)*4+r, v = n*16+(lane&15))
    float sv[4][4];
#pragma unroll
    for (int n = 0; n < 4; ++n)
#pragma unroll
        for (int r = 0; r < 4; ++r)
            sv[n][r] = accm[n][r] + accc[n][r]*INV512;

    // store S (fp32)
#pragma unroll
    for (int n = 0; n < 4; ++n) {
        float* sp = &S[((size_t)row*WW + wt*64 + wid*16 + (lane>>4)*4)*WW
                       + vt*64 + n*16 + (lane & 15)];
#pragma unroll
        for (int r = 0; r < 4; ++r) sp[(size_t)r*WW] = sv[n][r];
    }

    // ---- row stats (over the 64 v of this tile; in-wave: lanes&15 span v)
    float rmax[4], rsum[4];
#pragma unroll
    for (int r = 0; r < 4; ++r) {
        float m = fmaxf(fmaxf(sv[0][r], sv[1][r]), fmaxf(sv[2][r], sv[3][r]));
        m = fmaxf(m, __shfl_xor(m, 1));
        m = fmaxf(m, __shfl_xor(m, 2));
        m = fmaxf(m, __shfl_xor(m, 4));
        m = fmaxf(m, __shfl_xor(m, 8));
        rmax[r] = m;
        float l = __expf(sv[0][r]-m) + __expf(sv[1][r]-m)
                + __expf(sv[2][r]-m) + __expf(sv[3][r]-m);
        l += __shfl_xor(l, 1); l += __shfl_xor(l, 2);
        l += __shfl_xor(l, 4); l += __shfl_xor(l, 8);
        rsum[r] = l;
    }
    if ((lane & 15) == 0) {
        size_t rbase = ((size_t)row*5 + vt)*WW + wt*64 + wid*16 + (lane>>4)*4;
#pragma unroll
        for (int r = 0; r < 4; ++r) {
            rowmax_p[rbase + r] = rmax[r];
            rowsum_p[rbase + r] = rsum[r];
        }
    }

    // ---- col stats (over the 64 w of this tile; regs + lane>>4 + waves)
#pragma unroll
    for (int n = 0; n < 4; ++n) {
        float m = fmaxf(fmaxf(sv[n][0], sv[n][1]), fmaxf(sv[n][2], sv[n][3]));
        m = fmaxf(m, __shfl_xor(m, 16));
        m = fmaxf(m, __shfl_xor(m, 32));
        float l = __expf(sv[n][0]-m) + __expf(sv[n][1]-m)
                + __expf(sv[n][2]-m) + __expf(sv[n][3]-m);
        l += __shfl_xor(l, 16); l += __shfl_xor(l, 32);
        if (lane < 16) { cpm[wid][n*16 + lane] = m; cpl[wid][n*16 + lane] = l; }
    }
    __syncthreads();
    if (tid < 64) {
        float m0 = cpm[0][tid], m1 = cpm[1][tid], m2 = cpm[2][tid], m3 = cpm[3][tid];
        float m = fmaxf(fmaxf(m0, m1), fmaxf(m2, m3));
        float l = cpl[0][tid]*__expf(m0 - m) + cpl[1][tid]*__expf(m1 - m)
                + cpl[2][tid]*__expf(m2 - m) + cpl[3][tid]*__expf(m3 - m);
        size_t cbase = ((size_t)row*5 + wt)*WW + vt*64 + tid;
        colmax_p[cbase] = m;
        colsum_p[cbase] = l;
    }
}

// ---------------------------------------------------------------------------
// Merge 5 partials per row/col into final max + 1/sum. grid 1024 x 320 thr.
__global__ __launch_bounds__(320) void k_smerge(
    const float* __restrict__ colmax_p, const float* __restrict__ colsum_p,
    const float* __restrict__ rowmax_p, const float* __restrict__ rowsum_p,
    float* __restrict__ colmax_f, float* __restrict__ colinv_f,
    float* __restrict__ rowmax_f, float* __restrict__ rowinv_f)
{
    const int row = blockIdx.x, tid = threadIdx.x;
    float m = -1e30f, l = 0.f;
#pragma unroll
    for (int t = 0; t < 5; ++t) {
        float pm = colmax_p[((size_t)row*5 + t)*WW + tid];
        float pl = colsum_p[((size_t)row*5 + t)*WW + tid];
        float m2 = fmaxf(m, pm);
        l = l*__expf(m - m2) + pl*__expf(pm - m2);
        m = m2;
    }
    colmax_f[(size_t)row*WW + tid] = m;
    colinv_f[(size_t)row*WW + tid] = 1.f/l;
    m = -1e30f; l = 0.f;
#pragma unroll
    for (int t = 0; t < 5; ++t) {
        float pm = rowmax_p[((size_t)row*5 + t)*WW + tid];
        float pl = rowsum_p[((size_t)row*5 + t)*WW + tid];
        float m2 = fmaxf(m, pm);
        l = l*__expf(m - m2) + pl*__expf(pm - m2);
        m = m2;
    }
    rowmax_f[(size_t)row*WW + tid] = m;
    rowinv_f[(size_t)row*WW + tid] = 1.f/l;
}

// ---------------------------------------------------------------------------
// Softmax apply (pass 2 only): M_r2l = softmax_v(S) in place; Ml2r = ^T;
// V from col sums. Stats preloaded from global. block/row, 320 threads.
__global__ __launch_bounds__(320) void k_softmax(
    float* __restrict__ S, float* __restrict__ Ml2r, float* __restrict__ Vout,
    const float* __restrict__ colmax_f, const float* __restrict__ colinv_f,
    const float* __restrict__ rowmax_f, const float* __restrict__ rowinv_f)
{
    __shared__ float rowmax[320], rowinv[320], colmax[320], colinv[320];
    __shared__ float T[64*65];
    __shared__ float Vp2[5*64];
    const int row = blockIdx.x;
    const int tid = threadIdx.x;
    float* Srow = &S[(size_t)row * WW * WW];

    rowmax[tid] = rowmax_f[(size_t)row*WW + tid];
    rowinv[tid] = rowinv_f[(size_t)row*WW + tid];
    colmax[tid] = colmax_f[(size_t)row*WW + tid];
    colinv[tid] = colinv_f[(size_t)row*WW + tid];
    __syncthreads();

    const int myw = tid & 63;
    const int myg = tid / 64;          // 0..4
    for (int wt = 0; wt < 5; ++wt) {
        float vpart = 0.f;
        for (int vt = 0; vt < 5; ++vt) {
            for (int e = tid; e < 4096; e += 320) {
                int i = e >> 6, j = e & 63;
                int wgl = wt*64 + i, vgl = vt*64 + j;
                size_t si = (size_t)wgl*WW + vgl;
                float s = Srow[si];
                Srow[si] = __expf(s - rowmax[wgl]) * rowinv[wgl];
                T[j*65 + i] = __expf(s - colmax[vgl]) * colinv[vgl];
            }
            __syncthreads();
            for (int e = tid; e < 4096; e += 320) {
                int vr = e >> 6, wc = e & 63;
                Ml2r[((size_t)row*WW + vt*64 + vr)*WW + wt*64 + wc] = T[vr*65 + wc];
            }
            for (int j = myg; j < 64; j += 5) vpart += T[j*65 + myw];
            __syncthreads();
        }
        Vp2[myg*64 + myw] = vpart;
        __syncthreads();
        if (tid < 64) {
            float sv = 0.f;
#pragma unroll
            for (int g = 0; g < 5; ++g) sv += Vp2[g*64 + tid];
            Vout[(size_t)row*WW + wt*64 + tid] = (sv > 0.1f) ? 1.f : 0.f;
        }
        __syncthreads();
    }
}

// ---------------------------------------------------------------------------
// fp16 MFMA out-GEMM: out_f[w][c] = sum_v M[w][v] * xr[c][v].
// grid (5 wt, 1024 row), 256 thr. M and xr cvt to fp16 during staging.
__global__ __launch_bounds__(256) void k_outgemm(
    const float* __restrict__ M, const float* __restrict__ xr,
    float* __restrict__ outf)
{
    __shared__ __align__(16) char Am[8192], Bm[8192];  // fp16 [64][64] swz
    const int wt = blockIdx.x;
    const int row = blockIdx.y;
    const int b = row >> 7, h = row & 127;
    const int tid = threadIdx.x, lane = tid & 63, wid = tid >> 6;

    f32x4 acc[4];
#pragma unroll
    for (int n = 0; n < 4; ++n) acc[n] = (f32x4)0.f;

    for (int vt = 0; vt < 5; ++vt) {
        if (vt) __syncthreads();
        for (int e = tid; e < 512; e += 256) {
            int i = e >> 3, u = e & 7;
            const float4* mp = (const float4*)
                &M[((size_t)row*WW + wt*64 + i)*WW + vt*64 + u*8];
            float4 a0 = mp[0], a1 = mp[1];
            const float4* xp = (const float4*)
                &xr[(((size_t)b*CC + i)*HH + h)*WW + vt*64 + u*8];
            float4 b0 = xp[0], b1 = xp[1];
            half8 ha, hb;
            ha[0]=(_Float16)a0.x; ha[1]=(_Float16)a0.y; ha[2]=(_Float16)a0.z;
            ha[3]=(_Float16)a0.w; ha[4]=(_Float16)a1.x; ha[5]=(_Float16)a1.y;
            ha[6]=(_Float16)a1.z; ha[7]=(_Float16)a1.w;
            hb[0]=(_Float16)b0.x; hb[1]=(_Float16)b0.y; hb[2]=(_Float16)b0.z;
            hb[3]=(_Float16)b0.w; hb[4]=(_Float16)b1.x; hb[5]=(_Float16)b1.y;
            hb[6]=(_Float16)b1.z; hb[7]=(_Float16)b1.w;
            int off = (i*8 + (u ^ (i & 7)))*16;
            *(half8*)&Am[off] = ha;
            *(half8*)&Bm[off] = hb;
        }
        __syncthreads();
#pragma unroll
        for (int c = 0; c < 2; ++c) {
            const int u = c*4 + (lane >> 4);
            const int arow = wid*16 + (lane & 15);
            half8 ah = *(const half8*)&Am[(arow*8 + (u ^ (arow & 7)))*16];
#pragma unroll
            for (int n = 0; n < 4; ++n) {
                const int brow = n*16 + (lane & 15);
                half8 bh = *(const half8*)&Bm[(brow*8 + (u ^ (brow & 7)))*16];
                acc[n] = __builtin_amdgcn_mfma_f32_16x16x32_f16(ah, bh, acc[n], 0,0,0);
            }
        }
    }

    // frag n, reg r -> (w = wt*64+wid*16+(lane>>4)*4+r, c = n*16+(lane&15))
#pragma unroll
    for (int n = 0; n < 4; ++n) {
        *(float4*)&outf[(((size_t)b*CC + n*16 + (lane & 15))*HH + h)*WW
                        + wt*64 + wid*16 + (lane>>4)*4] =
            make_float4(acc[n][0], acc[n][1], acc[n][2], acc[n][3]);
    }
}

// ---------------------------------------------------------------------------
extern "C" void kernel_launch(void* const* d_in, const int* in_sizes, int n_in,
                              void* d_out, int out_size, void* d_ws, size_t ws_size,
                              hipStream_t stream)
{
    const float* x_l = (const float*)d_in[0];
    const float* x_r = (const float*)d_in[1];
    const float* w1  = (const float*)d_in[2];
    const float* w2  = (const float*)d_in[3];
    const float* wl  = (const float*)d_in[4];
    const float* bl  = (const float*)d_in[5];
    const float* wr  = (const float*)d_in[6];
    const float* br  = (const float*)d_in[7];
    float* out = (float*)d_out;

    float* outf = out;
    float* Vp   = out + OFF_V;
    float* Ml2r = out + OFF_ML2R;
    float* Mr2l = out + OFF_MR2L;

    // hi/lo fp16 channels-last conv scratch: 10 buffers = Mr2l region exactly
    _Float16* base = (_Float16*)Mr2l;
    _Float16* xl_h = base + 0*(size_t)NCL;
    _Float16* xl_l = base + 1*(size_t)NCL;
    _Float16* xr_h = base + 2*(size_t)NCL;
    _Float16* xr_l = base + 3*(size_t)NCL;
    _Float16* r_h  = base + 4*(size_t)NCL;
    _Float16* r_l  = base + 5*(size_t)NCL;
    _Float16* bl_h = base + 6*(size_t)NCL;
    _Float16* bl_l = base + 7*(size_t)NCL;
    _Float16* br_h = base + 8*(size_t)NCL;
    _Float16* br_l = base + 9*(size_t)NCL;
    // F hi/lo fp16 arrays at the start of the Ml2r region (dead before
    // softmax overwrites Ml2r); conv weights at its tail.
    _Float16* F0h = (_Float16*)Ml2r;
    _Float16* F0l = F0h + (size_t)NCL;
    _Float16* F1h = F0l + (size_t)NCL;
    _Float16* F1l = F1h + (size_t)NCL;
    float* S  = Mr2l;
    float* WT  = Ml2r + (size_t)N_M - WT_FLOATS;
    float* wlT = WT;
    float* wrT = WT + 4096;
    _Float16* wB1h = (_Float16*)(WT + 8192);
    _Float16* wB1l = wB1h + 36864;
    _Float16* wB2h = wB1l + 36864;
    _Float16* wB2l = wB2h + 36864;
    // softmax stats live in the outf region (outf is written LAST)
    float* colmax_p = out + 0;          // [1024][5][320]
    float* colsum_p = out + 1700000;
    float* rowmax_p = out + 3400000;
    float* rowsum_p = out + 5100000;
    float* colmax_f = out + 6800000;    // [1024][320]
    float* colinv_f = out + 7200000;
    float* rowmax_f = out + 7600000;
    float* rowinv_f = out + 8000000;

    k_wt<<<64, 256, 0, stream>>>(w1, w2, wl, wr, wlT, wrT,
                                 wB1h, wB1l, wB2h, wB2l);

    dim3 pgrid(WW/64, HH, BB);
    k_prep<<<pgrid, 256, 0, stream>>>(x_l, xl_h, xl_l);
    k_prep<<<pgrid, 256, 0, stream>>>(x_r, xr_h, xr_l);

    k_conv3<<<pgrid, 256, 0, stream>>>(xl_h, xl_l, wB1h, wB1l,
                                       xl_h, xl_l, r_h, r_l, 0);
    k_conv3<<<pgrid, 256, 0, stream>>>(r_h, r_l, wB2h, wB2l,
                                       xl_h, xl_l, bl_h, bl_l, 1);
    k_conv3<<<pgrid, 256, 0, stream>>>(xr_h, xr_l, wB1h, wB1l,
                                       xr_h, xr_l, r_h, r_l, 0);
    k_conv3<<<pgrid, 256, 0, stream>>>(r_h, r_l, wB2h, wB2l,
                                       xr_h, xr_l, br_h, br_l, 1);

    int pblocks = (BB*HH*WW) / 256;          // 1280
    k_conv1x1<<<pblocks, 256, 0, stream>>>(bl_h, bl_l, wlT, bl, F0h, F0l);
    k_conv1x1<<<pblocks, 256, 0, stream>>>(br_h, br_l, wrT, br, F1h, F1l);

    dim3 sgrid(5, 5, BB*HH);
    k_sgemm<<<sgrid, 256, 0, stream>>>(F0h, F0l, F1h, F1l, S,
                                       colmax_p, colsum_p, rowmax_p, rowsum_p);

    k_smerge<<<BB*HH, 320, 0, stream>>>(colmax_p, colsum_p, rowmax_p, rowsum_p,
                                        colmax_f, colinv_f, rowmax_f, rowinv_f);

    k_softmax<<<BB*HH, 320, 0, stream>>>(S, Ml2r, Vp,
                                         colmax_f, colinv_f, rowmax_f, rowinv_f);

    dim3 ogrid(5, BB*HH);
    k_outgemm<<<ogrid, 256, 0, stream>>>(Mr2l, x_r, outf);
}

// Round 7
// 1528.022 us; speedup vs baseline: 3.2707x; 1.1165x over previous
//
#include <hip/hip_runtime.h>

#define BB 8
#define CC 64
#define HH 128
#define WW 320

// float offsets inside d_out
#define N_OUTF (BB*CC*HH*WW)           // 20,971,520
#define N_V    (BB*HH*WW)              // 327,680
#define N_M    (BB*HH*WW*WW)           // 104,857,600
#define OFF_V    (N_OUTF)
#define OFF_ML2R (N_OUTF + N_V)        // 21,299,200
#define OFF_MR2L (OFF_ML2R + N_M)      // 126,156,800
#define OUT_TOTAL (OFF_MR2L + N_M)     // 231,014,400
// weight tail (floats) in Ml2r region: wlT + wrT + 4x fp16 conv weight arrays
#define WT_FLOATS (4096 + 4096 + 4*18432)          // 81,920
#define NCL 20971520                   // halfs per channels-last buffer
#define INV512 (1.f/512.f)

typedef _Float16 half8 __attribute__((ext_vector_type(8)));
typedef _Float16 half4 __attribute__((ext_vector_type(4)));
typedef float f32x4 __attribute__((ext_vector_type(4)));

// ---------------------------------------------------------------------------
// Weights prep: wl/wr [co][ci] -> fp32 [ci][co];
// rb_w -> fp16 hi/lo pairs [co][tap][ci], lo pre-scaled by 512.
__global__ __launch_bounds__(256) void k_wt(
    const float* __restrict__ w1, const float* __restrict__ w2,
    const float* __restrict__ wl, const float* __restrict__ wr,
    float* __restrict__ wlT, float* __restrict__ wrT,
    _Float16* __restrict__ wB1h, _Float16* __restrict__ wB1l,
    _Float16* __restrict__ wB2h, _Float16* __restrict__ wB2l)
{
    int tid = blockIdx.x * 256 + threadIdx.x;
    int stride = gridDim.x * 256;
    for (int e = tid; e < 64*9*64; e += stride) {   // e = co*576 + tap*64 + ci
        int co = e / 576;
        int rem = e - co*576;
        int tap = rem >> 6, ci = rem & 63;
        float v1 = w1[(co*64 + ci)*9 + tap];
        float v2 = w2[(co*64 + ci)*9 + tap];
        _Float16 h1 = (_Float16)v1, h2 = (_Float16)v2;
        wB1h[e] = h1; wB1l[e] = (_Float16)((v1 - (float)h1)*512.f);
        wB2h[e] = h2; wB2l[e] = (_Float16)((v2 - (float)h2)*512.f);
    }
    for (int e = tid; e < 4096; e += stride) {
        int co = e >> 6, ci = e & 63;
        wlT[ci*64 + co] = wl[e];
        wrT[ci*64 + co] = wr[e];
    }
}

// ---------------------------------------------------------------------------
// NCHW fp32 -> channels-last fp16 hi/lo [b][y][x][ci]. grid (5,128,8), 256thr
__global__ __launch_bounds__(256) void k_prep(
    const float* __restrict__ in,
    _Float16* __restrict__ oh, _Float16* __restrict__ ol)
{
    __shared__ float t[64][65];
    const int tid = threadIdx.x;
    const int x0 = blockIdx.x * 64, y = blockIdx.y, b = blockIdx.z;
    for (int e = tid; e < 4096; e += 256) {
        int ci = e >> 6, x = e & 63;
        t[ci][x] = in[((size_t)(b*64 + ci)*HH + y)*WW + x0 + x];
    }
    __syncthreads();
#pragma unroll
    for (int i = 0; i < 2; ++i) {
        int unit = tid + 256*i;            // 0..511
        int x = unit >> 3, u = unit & 7;
        half8 hh, hl;
#pragma unroll
        for (int j = 0; j < 8; ++j) {
            float v = t[u*8 + j][x];
            _Float16 h = (_Float16)v;
            hh[j] = h;
            hl[j] = (_Float16)((v - (float)h)*512.f);
        }
        size_t g = (((size_t)(b*HH + y)*WW) + x0 + x)*64 + u*8;
        *(half8*)&oh[g] = hh;
        *(half8*)&ol[g] = hl;
    }
}

// ---------------------------------------------------------------------------
// Split-fp16 MFMA 3x3 conv, 64->64, pad 1, channels-last hi/lo.
__global__ __launch_bounds__(256) void k_conv3(
    const _Float16* __restrict__ in_h, const _Float16* __restrict__ in_l,
    const _Float16* __restrict__ wBh, const _Float16* __restrict__ wBl,
    const _Float16* __restrict__ res_h, const _Float16* __restrict__ res_l,
    _Float16* __restrict__ out_h, _Float16* __restrict__ out_l, int mode)
{
    __shared__ __align__(16) char smem[2*3*66*128];    // 50688 B
    char* in_sh = smem;
    char* in_sl = smem + 25344;
    const int tid = threadIdx.x;
    const int x0 = blockIdx.x * 64;
    const int y  = blockIdx.y;
    const int b  = blockIdx.z;
    const int lane = tid & 63;
    const int xq = lane & 15, kq = lane >> 4;
    const int n = tid >> 6;                            // wave = co-tile

    half8 bwh[18], bwl[18];
    {
        const _Float16* wbh = &wBh[((size_t)(n*16 + xq)*9)*64 + kq*8];
        const _Float16* wbl = &wBl[((size_t)(n*16 + xq)*9)*64 + kq*8];
#pragma unroll
        for (int t = 0; t < 9; ++t)
#pragma unroll
            for (int c = 0; c < 2; ++c) {
                bwh[t*2 + c] = *(const half8*)&wbh[t*64 + c*32];
                bwl[t*2 + c] = *(const half8*)&wbl[t*64 + c*32];
            }
    }

    for (int e = tid; e < 3*66*8; e += 256) {
        int ry = e / 528;
        int rem = e - ry*528;
        int xx = rem >> 3, u = rem & 7;
        int gy = y + ry - 1, gx = x0 + xx - 1;
        uint4 vh = make_uint4(0u,0u,0u,0u), vl = make_uint4(0u,0u,0u,0u);
        if ((unsigned)gy < (unsigned)HH && (unsigned)gx < (unsigned)WW) {
            size_t g = (((size_t)(b*HH + gy)*WW) + gx)*64 + u*8;
            vh = *(const uint4*)&in_h[g];
            vl = *(const uint4*)&in_l[g];
        }
        int off = ((ry*66 + xx)*8 + (u ^ (xx & 7)))*16;
        *(uint4*)&in_sh[off] = vh;
        *(uint4*)&in_sl[off] = vl;
    }
    __syncthreads();

    f32x4 accm[4], accc[4];
#pragma unroll
    for (int m = 0; m < 4; ++m) { accm[m] = (f32x4)0.f; accc[m] = (f32x4)0.f; }

#pragma unroll
    for (int m = 0; m < 4; ++m) {
        const int xb = m*16 + xq;
#pragma unroll
        for (int t = 0; t < 9; ++t) {
            const int ry = t / 3, kx = t - ry*3;
            const int xxx = xb + kx;
#pragma unroll
            for (int c = 0; c < 2; ++c) {
                const int u = c*4 + kq;
                int off = ((ry*66 + xxx)*8 + (u ^ (xxx & 7)))*16;
                half8 ah = *(const half8*)&in_sh[off];
                half8 al = *(const half8*)&in_sl[off];
                accm[m] = __builtin_amdgcn_mfma_f32_16x16x32_f16(
                    ah, bwh[t*2 + c], accm[m], 0, 0, 0);
                accc[m] = __builtin_amdgcn_mfma_f32_16x16x32_f16(
                    al, bwh[t*2 + c], accc[m], 0, 0, 0);
                accc[m] = __builtin_amdgcn_mfma_f32_16x16x32_f16(
                    ah, bwl[t*2 + c], accc[m], 0, 0, 0);
            }
        }
    }
    __syncthreads();            // all waves done reading input tiles

    char* out_sh = smem;
    char* out_sl = smem + 8192;
#pragma unroll
    for (int m = 0; m < 4; ++m) {
#pragma unroll
        for (int r = 0; r < 4; ++r) {
            int x = m*16 + kq*4 + r;          // local x
            int co = n*16 + xq;
            float v = accm[m][r] + accc[m][r]*INV512;
            if (mode == 0) v = (v > 0.f) ? v : 0.1f*v;
            _Float16 vh = (_Float16)v;
            _Float16 vl = (_Float16)((v - (float)vh)*512.f);
            int boff = (x*8 + ((co >> 3) ^ (x & 7)))*16 + (co & 7)*2;
            *(_Float16*)&out_sh[boff] = vh;
            *(_Float16*)&out_sl[boff] = vl;
        }
    }
    __syncthreads();

#pragma unroll
    for (int i = 0; i < 2; ++i) {
        int unit = tid + 256*i;               // 0..511
        int x = unit >> 3, u = unit & 7;
        int loff = (x*8 + (u ^ (x & 7)))*16;
        half8 vh = *(half8*)&out_sh[loff];
        half8 vl = *(half8*)&out_sl[loff];
        size_t g = (((size_t)(b*HH + y)*WW) + x0 + x)*64 + u*8;
        if (mode == 1) {
            half8 rh = *(const half8*)&res_h[g];
            half8 rl = *(const half8*)&res_l[g];
            half8 ohv, olv;
#pragma unroll
            for (int e = 0; e < 8; ++e) {
                float s = (float)vh[e] + (float)vl[e]*INV512
                        + (float)rh[e] + (float)rl[e]*INV512;
                _Float16 h = (_Float16)s;
                ohv[e] = h;
                olv[e] = (_Float16)((s - (float)h)*512.f);
            }
            *(half8*)&out_h[g] = ohv;
            *(half8*)&out_l[g] = olv;
        } else {
            *(half8*)&out_h[g] = vh;
            *(half8*)&out_l[g] = vl;
        }
    }
}

// ---------------------------------------------------------------------------
// 1x1 conv + bias: channels-last hi/lo fp16 buf -> F hi/lo fp16 (b,h,w,c).
__global__ __launch_bounds__(256) void k_conv1x1(
    const _Float16* __restrict__ bh, const _Float16* __restrict__ bl,
    const float* __restrict__ wT, const float* __restrict__ bias,
    _Float16* __restrict__ Fh, _Float16* __restrict__ Fl)
{
    int p = blockIdx.x * 256 + threadIdx.x;          // 0..B*H*W-1
    const _Float16* iph = &bh[(size_t)p*64];
    const _Float16* ipl = &bl[(size_t)p*64];
    float acc[64];
#pragma unroll
    for (int j = 0; j < 64; ++j) acc[j] = bias[j];
#pragma unroll 2
    for (int cu = 0; cu < 8; ++cu) {
        half8 hh = *(const half8*)&iph[cu*8];
        half8 hl = *(const half8*)&ipl[cu*8];
#pragma unroll
        for (int e = 0; e < 8; ++e) {
            float v = (float)hh[e] + (float)hl[e]*INV512;
            const float* wp = &wT[(cu*8 + e)*64];
#pragma unroll
            for (int j = 0; j < 64; ++j) acc[j] += v * wp[j];
        }
    }
#pragma unroll
    for (int u = 0; u < 8; ++u) {
        half8 hh, hl;
#pragma unroll
        for (int j = 0; j < 8; ++j) {
            float v = acc[u*8 + j];
            _Float16 h = (_Float16)v;
            hh[j] = h;
            hl[j] = (_Float16)((v - (float)h)*512.f);
        }
        *(half8*)&Fh[(size_t)p*64 + u*8] = hh;
        *(half8*)&Fl[(size_t)p*64 + u*8] = hl;
    }
}

// ---------------------------------------------------------------------------
// Split-fp16 MFMA S-GEMM + fused softmax stats (partials).
__global__ __launch_bounds__(256) void k_sgemm(
    const _Float16* __restrict__ F0h, const _Float16* __restrict__ F0l,
    const _Float16* __restrict__ F1h, const _Float16* __restrict__ F1l,
    float* __restrict__ S,
    float* __restrict__ colmax_p, float* __restrict__ colsum_p,
    float* __restrict__ rowmax_p, float* __restrict__ rowsum_p)
{
    __shared__ __align__(16) char Ah[8192], Al[8192], Bh[8192], Bl[8192];
    __shared__ float cpm[4][64], cpl[4][64];
    const int wt = blockIdx.x, vt = blockIdx.y, row = blockIdx.z;
    const int tid = threadIdx.x, lane = tid & 63, wid = tid >> 6;

    for (int e = tid; e < 512; e += 256) {
        int i = e >> 3, u = e & 7;
        size_t ga = ((size_t)row*WW + wt*64 + i)*64 + u*8;
        size_t gb = ((size_t)row*WW + vt*64 + i)*64 + u*8;
        int off = (i*8 + (u ^ (i & 7)))*16;
        *(uint4*)&Ah[off] = *(const uint4*)&F0h[ga];
        *(uint4*)&Al[off] = *(const uint4*)&F0l[ga];
        *(uint4*)&Bh[off] = *(const uint4*)&F1h[gb];
        *(uint4*)&Bl[off] = *(const uint4*)&F1l[gb];
    }
    __syncthreads();

    f32x4 accm[4], accc[4];
#pragma unroll
    for (int n = 0; n < 4; ++n) { accm[n] = (f32x4)0.f; accc[n] = (f32x4)0.f; }

#pragma unroll
    for (int c = 0; c < 2; ++c) {
        const int u = c*4 + (lane >> 4);
        const int arow = wid*16 + (lane & 15);
        int aoff = (arow*8 + (u ^ (arow & 7)))*16;
        half8 ah = *(const half8*)&Ah[aoff];
        half8 al = *(const half8*)&Al[aoff];
#pragma unroll
        for (int n = 0; n < 4; ++n) {
            const int brow = n*16 + (lane & 15);
            int boff = (brow*8 + (u ^ (brow & 7)))*16;
            half8 bh = *(const half8*)&Bh[boff];
            half8 bl = *(const half8*)&Bl[boff];
            accm[n] = __builtin_amdgcn_mfma_f32_16x16x32_f16(ah, bh, accm[n], 0,0,0);
            accc[n] = __builtin_amdgcn_mfma_f32_16x16x32_f16(al, bh, accc[n], 0,0,0);
            accc[n] = __builtin_amdgcn_mfma_f32_16x16x32_f16(ah, bl, accc[n], 0,0,0);
        }
    }

    float sv[4][4];
#pragma unroll
    for (int n = 0; n < 4; ++n)
#pragma unroll
        for (int r = 0; r < 4; ++r)
            sv[n][r] = accm[n][r] + accc[n][r]*INV512;

#pragma unroll
    for (int n = 0; n < 4; ++n) {
        float* sp = &S[((size_t)row*WW + wt*64 + wid*16 + (lane>>4)*4)*WW
                       + vt*64 + n*16 + (lane & 15)];
#pragma unroll
        for (int r = 0; r < 4; ++r) sp[(size_t)r*WW] = sv[n][r];
    }

    // ---- row stats (over the 64 v of this tile)
    float rmax[4], rsum[4];
#pragma unroll
    for (int r = 0; r < 4; ++r) {
        float m = fmaxf(fmaxf(sv[0][r], sv[1][r]), fmaxf(sv[2][r], sv[3][r]));
        m = fmaxf(m, __shfl_xor(m, 1));
        m = fmaxf(m, __shfl_xor(m, 2));
        m = fmaxf(m, __shfl_xor(m, 4));
        m = fmaxf(m, __shfl_xor(m, 8));
        rmax[r] = m;
        float l = __expf(sv[0][r]-m) + __expf(sv[1][r]-m)
                + __expf(sv[2][r]-m) + __expf(sv[3][r]-m);
        l += __shfl_xor(l, 1); l += __shfl_xor(l, 2);
        l += __shfl_xor(l, 4); l += __shfl_xor(l, 8);
        rsum[r] = l;
    }
    if ((lane & 15) == 0) {
        size_t rbase = ((size_t)row*5 + vt)*WW + wt*64 + wid*16 + (lane>>4)*4;
#pragma unroll
        for (int r = 0; r < 4; ++r) {
            rowmax_p[rbase + r] = rmax[r];
            rowsum_p[rbase + r] = rsum[r];
        }
    }

    // ---- col stats (over the 64 w of this tile)
#pragma unroll
    for (int n = 0; n < 4; ++n) {
        float m = fmaxf(fmaxf(sv[n][0], sv[n][1]), fmaxf(sv[n][2], sv[n][3]));
        m = fmaxf(m, __shfl_xor(m, 16));
        m = fmaxf(m, __shfl_xor(m, 32));
        float l = __expf(sv[n][0]-m) + __expf(sv[n][1]-m)
                + __expf(sv[n][2]-m) + __expf(sv[n][3]-m);
        l += __shfl_xor(l, 16); l += __shfl_xor(l, 32);
        if (lane < 16) { cpm[wid][n*16 + lane] = m; cpl[wid][n*16 + lane] = l; }
    }
    __syncthreads();
    if (tid < 64) {
        float m0 = cpm[0][tid], m1 = cpm[1][tid], m2 = cpm[2][tid], m3 = cpm[3][tid];
        float m = fmaxf(fmaxf(m0, m1), fmaxf(m2, m3));
        float l = cpl[0][tid]*__expf(m0 - m) + cpl[1][tid]*__expf(m1 - m)
                + cpl[2][tid]*__expf(m2 - m) + cpl[3][tid]*__expf(m3 - m);
        size_t cbase = ((size_t)row*5 + wt)*WW + vt*64 + tid;
        colmax_p[cbase] = m;
        colsum_p[cbase] = l;
    }
}

// ---------------------------------------------------------------------------
// Merge 5 partials per row/col into final max + 1/sum. grid 1024 x 320 thr.
__global__ __launch_bounds__(320) void k_smerge(
    const float* __restrict__ colmax_p, const float* __restrict__ colsum_p,
    const float* __restrict__ rowmax_p, const float* __restrict__ rowsum_p,
    float* __restrict__ colmax_f, float* __restrict__ colinv_f,
    float* __restrict__ rowmax_f, float* __restrict__ rowinv_f)
{
    const int row = blockIdx.x, tid = threadIdx.x;
    float m = -1e30f, l = 0.f;
#pragma unroll
    for (int t = 0; t < 5; ++t) {
        float pm = colmax_p[((size_t)row*5 + t)*WW + tid];
        float pl = colsum_p[((size_t)row*5 + t)*WW + tid];
        float m2 = fmaxf(m, pm);
        l = l*__expf(m - m2) + pl*__expf(pm - m2);
        m = m2;
    }
    colmax_f[(size_t)row*WW + tid] = m;
    colinv_f[(size_t)row*WW + tid] = 1.f/l;
    m = -1e30f; l = 0.f;
#pragma unroll
    for (int t = 0; t < 5; ++t) {
        float pm = rowmax_p[((size_t)row*5 + t)*WW + tid];
        float pl = rowsum_p[((size_t)row*5 + t)*WW + tid];
        float m2 = fmaxf(m, pm);
        l = l*__expf(m - m2) + pl*__expf(pm - m2);
        m = m2;
    }
    rowmax_f[(size_t)row*WW + tid] = m;
    rowinv_f[(size_t)row*WW + tid] = 1.f/l;
}

// ---------------------------------------------------------------------------
// FUSED softmax-apply + out-GEMM. grid (5 wt, 1024 row), 256 thr.
// Block (wt,row): reads S strip [64w][320v] once; writes Mr2l in place,
// Ml2r transposed, V for its strip (sum over v is block-local), and
// outf strip via fp16 MFMA P @ xr^T.
__global__ __launch_bounds__(256) void k_fused(
    float* __restrict__ S, float* __restrict__ Ml2r, float* __restrict__ Vout,
    const float* __restrict__ xr, float* __restrict__ outf,
    const float* __restrict__ colmax_f, const float* __restrict__ colinv_f,
    const float* __restrict__ rowmax_f, const float* __restrict__ rowinv_f)
{
    __shared__ __align__(16) char A[8192], Bm[8192];   // fp16 tiles, swizzled
    __shared__ float T[64*65];                          // Ml2r transpose tile
    __shared__ float cmx[320], cin[320], rmx[64], rin[64];
    const int wt = blockIdx.x, row = blockIdx.y;
    const int b = row >> 7, h = row & 127;
    const int tid = threadIdx.x, lane = tid & 63, wid = tid >> 6;
    const int wrow = tid >> 2, quad = tid & 3;

    for (int e = tid; e < 320; e += 256) {
        cmx[e] = colmax_f[(size_t)row*WW + e];
        cin[e] = colinv_f[(size_t)row*WW + e];
    }
    if (tid < 64) {
        rmx[tid] = rowmax_f[(size_t)row*WW + wt*64 + tid];
        rin[tid] = rowinv_f[(size_t)row*WW + wt*64 + tid];
    }
    __syncthreads();

    f32x4 acc[4];
#pragma unroll
    for (int n = 0; n < 4; ++n) acc[n] = (f32x4)0.f;
    float vsum = 0.f;
    float* Sbase = &S[((size_t)row*WW + wt*64 + wrow)*WW];
    const float rm = rmx[wrow], ri = rin[wrow];

    for (int vt = 0; vt < 5; ++vt) {
        if (vt) __syncthreads();
        // process 16 v per thread: float4 f = quad + 4i
#pragma unroll
        for (int i = 0; i < 4; ++i) {
            const int f = quad + 4*i;
            const int v0 = f*4;
            float4 s = *(float4*)&Sbase[vt*64 + v0];
            float4 pr;
            pr.x = __expf(s.x - rm)*ri;
            pr.y = __expf(s.y - rm)*ri;
            pr.z = __expf(s.z - rm)*ri;
            pr.w = __expf(s.w - rm)*ri;
            *(float4*)&Sbase[vt*64 + v0] = pr;      // Mr2l in place
            const int vg = vt*64 + v0;
            float p0 = __expf(s.x - cmx[vg+0])*cin[vg+0];
            float p1 = __expf(s.y - cmx[vg+1])*cin[vg+1];
            float p2 = __expf(s.z - cmx[vg+2])*cin[vg+2];
            float p3 = __expf(s.w - cmx[vg+3])*cin[vg+3];
            T[(v0+0)*65 + wrow] = p0;
            T[(v0+1)*65 + wrow] = p1;
            T[(v0+2)*65 + wrow] = p2;
            T[(v0+3)*65 + wrow] = p3;
            vsum += p0 + p1 + p2 + p3;
            half4 hp;
            hp[0] = (_Float16)pr.x; hp[1] = (_Float16)pr.y;
            hp[2] = (_Float16)pr.z; hp[3] = (_Float16)pr.w;
            *(half4*)&A[(wrow*8 + ((f>>1) ^ (wrow & 7)))*16 + (f & 1)*8] = hp;
        }
        // stage xr tile [64c][64v] -> fp16 swizzled
        for (int e = tid; e < 512; e += 256) {
            int i = e >> 3, u = e & 7;
            const float4* xp = (const float4*)
                &xr[(((size_t)b*CC + i)*HH + h)*WW + vt*64 + u*8];
            float4 b0 = xp[0], b1 = xp[1];
            half8 hb;
            hb[0]=(_Float16)b0.x; hb[1]=(_Float16)b0.y; hb[2]=(_Float16)b0.z;
            hb[3]=(_Float16)b0.w; hb[4]=(_Float16)b1.x; hb[5]=(_Float16)b1.y;
            hb[6]=(_Float16)b1.z; hb[7]=(_Float16)b1.w;
            *(half8*)&Bm[(i*8 + (u ^ (i & 7)))*16] = hb;
        }
        __syncthreads();
        // MFMA: out_f strip += P @ xr^T
#pragma unroll
        for (int c = 0; c < 2; ++c) {
            const int u = c*4 + (lane >> 4);
            const int arow = wid*16 + (lane & 15);
            half8 ah = *(const half8*)&A[(arow*8 + (u ^ (arow & 7)))*16];
#pragma unroll
            for (int n = 0; n < 4; ++n) {
                const int brow = n*16 + (lane & 15);
                half8 bh = *(const half8*)&Bm[(brow*8 + (u ^ (brow & 7)))*16];
                acc[n] = __builtin_amdgcn_mfma_f32_16x16x32_f16(ah, bh, acc[n], 0,0,0);
            }
        }
        // Ml2r transposed write
        for (int e = tid; e < 4096; e += 256) {
            int vr = e >> 6, wc = e & 63;
            Ml2r[((size_t)row*WW + vt*64 + vr)*WW + wt*64 + wc] = T[vr*65 + wc];
        }
    }

    // V: reduce over quads (lanes t, t^1, t^2 share wrow)
    vsum += __shfl_xor(vsum, 1);
    vsum += __shfl_xor(vsum, 2);
    if (quad == 0)
        Vout[(size_t)row*WW + wt*64 + wrow] = (vsum > 0.1f) ? 1.f : 0.f;

    // outf strip: frag n reg r -> (w = wt*64+wid*16+(lane>>4)*4+r, c = n*16+(lane&15))
#pragma unroll
    for (int n = 0; n < 4; ++n) {
        *(float4*)&outf[(((size_t)b*CC + n*16 + (lane & 15))*HH + h)*WW
                        + wt*64 + wid*16 + (lane>>4)*4] =
            make_float4(acc[n][0], acc[n][1], acc[n][2], acc[n][3]);
    }
}

// ---------------------------------------------------------------------------
// FALLBACK path (ws too small): separate softmax-apply and out-GEMM.
__global__ __launch_bounds__(320) void k_softmax(
    float* __restrict__ S, float* __restrict__ Ml2r, float* __restrict__ Vout,
    const float* __restrict__ colmax_f, const float* __restrict__ colinv_f,
    const float* __restrict__ rowmax_f, const float* __restrict__ rowinv_f)
{
    __shared__ float rowmax[320], rowinv[320], colmax[320], colinv[320];
    __shared__ float T[64*65];
    __shared__ float Vp2[5*64];
    const int row = blockIdx.x;
    const int tid = threadIdx.x;
    float* Srow = &S[(size_t)row * WW * WW];

    rowmax[tid] = rowmax_f[(size_t)row*WW + tid];
    rowinv[tid] = rowinv_f[(size_t)row*WW + tid];
    colmax[tid] = colmax_f[(size_t)row*WW + tid];
    colinv[tid] = colinv_f[(size_t)row*WW + tid];
    __syncthreads();

    const int myw = tid & 63;
    const int myg = tid / 64;          // 0..4
    for (int wt = 0; wt < 5; ++wt) {
        float vpart = 0.f;
        for (int vt = 0; vt < 5; ++vt) {
            for (int e = tid; e < 4096; e += 320) {
                int i = e >> 6, j = e & 63;
                int wgl = wt*64 + i, vgl = vt*64 + j;
                size_t si = (size_t)wgl*WW + vgl;
                float s = Srow[si];
                Srow[si] = __expf(s - rowmax[wgl]) * rowinv[wgl];
                T[j*65 + i] = __expf(s - colmax[vgl]) * colinv[vgl];
            }
            __syncthreads();
            for (int e = tid; e < 4096; e += 320) {
                int vr = e >> 6, wc = e & 63;
                Ml2r[((size_t)row*WW + vt*64 + vr)*WW + wt*64 + wc] = T[vr*65 + wc];
            }
            for (int j = myg; j < 64; j += 5) vpart += T[j*65 + myw];
            __syncthreads();
        }
        Vp2[myg*64 + myw] = vpart;
        __syncthreads();
        if (tid < 64) {
            float sv = 0.f;
#pragma unroll
            for (int g = 0; g < 5; ++g) sv += Vp2[g*64 + tid];
            Vout[(size_t)row*WW + wt*64 + tid] = (sv > 0.1f) ? 1.f : 0.f;
        }
        __syncthreads();
    }
}

__global__ __launch_bounds__(256) void k_outgemm(
    const float* __restrict__ M, const float* __restrict__ xr,
    float* __restrict__ outf)
{
    __shared__ __align__(16) char Am[8192], Bm[8192];  // fp16 [64][64] swz
    const int wt = blockIdx.x;
    const int row = blockIdx.y;
    const int b = row >> 7, h = row & 127;
    const int tid = threadIdx.x, lane = tid & 63, wid = tid >> 6;

    f32x4 acc[4];
#pragma unroll
    for (int n = 0; n < 4; ++n) acc[n] = (f32x4)0.f;

    for (int vt = 0; vt < 5; ++vt) {
        if (vt) __syncthreads();
        for (int e = tid; e < 512; e += 256) {
            int i = e >> 3, u = e & 7;
            const float4* mp = (const float4*)
                &M[((size_t)row*WW + wt*64 + i)*WW + vt*64 + u*8];
            float4 a0 = mp[0], a1 = mp[1];
            const float4* xp = (const float4*)
                &xr[(((size_t)b*CC + i)*HH + h)*WW + vt*64 + u*8];
            float4 b0 = xp[0], b1 = xp[1];
            half8 ha, hb;
            ha[0]=(_Float16)a0.x; ha[1]=(_Float16)a0.y; ha[2]=(_Float16)a0.z;
            ha[3]=(_Float16)a0.w; ha[4]=(_Float16)a1.x; ha[5]=(_Float16)a1.y;
            ha[6]=(_Float16)a1.z; ha[7]=(_Float16)a1.w;
            hb[0]=(_Float16)b0.x; hb[1]=(_Float16)b0.y; hb[2]=(_Float16)b0.z;
            hb[3]=(_Float16)b0.w; hb[4]=(_Float16)b1.x; hb[5]=(_Float16)b1.y;
            hb[6]=(_Float16)b1.z; hb[7]=(_Float16)b1.w;
            int off = (i*8 + (u ^ (i & 7)))*16;
            *(half8*)&Am[off] = ha;
            *(half8*)&Bm[off] = hb;
        }
        __syncthreads();
#pragma unroll
        for (int c = 0; c < 2; ++c) {
            const int u = c*4 + (lane >> 4);
            const int arow = wid*16 + (lane & 15);
            half8 ah = *(const half8*)&Am[(arow*8 + (u ^ (arow & 7)))*16];
#pragma unroll
            for (int n = 0; n < 4; ++n) {
                const int brow = n*16 + (lane & 15);
                half8 bh = *(const half8*)&Bm[(brow*8 + (u ^ (brow & 7)))*16];
                acc[n] = __builtin_amdgcn_mfma_f32_16x16x32_f16(ah, bh, acc[n], 0,0,0);
            }
        }
    }

#pragma unroll
    for (int n = 0; n < 4; ++n) {
        *(float4*)&outf[(((size_t)b*CC + n*16 + (lane & 15))*HH + h)*WW
                        + wt*64 + wid*16 + (lane>>4)*4] =
            make_float4(acc[n][0], acc[n][1], acc[n][2], acc[n][3]);
    }
}

// ---------------------------------------------------------------------------
extern "C" void kernel_launch(void* const* d_in, const int* in_sizes, int n_in,
                              void* d_out, int out_size, void* d_ws, size_t ws_size,
                              hipStream_t stream)
{
    const float* x_l = (const float*)d_in[0];
    const float* x_r = (const float*)d_in[1];
    const float* w1  = (const float*)d_in[2];
    const float* w2  = (const float*)d_in[3];
    const float* wl  = (const float*)d_in[4];
    const float* bl  = (const float*)d_in[5];
    const float* wr  = (const float*)d_in[6];
    const float* br  = (const float*)d_in[7];
    float* out = (float*)d_out;

    float* outf = out;
    float* Vp   = out + OFF_V;
    float* Ml2r = out + OFF_ML2R;
    float* Mr2l = out + OFF_MR2L;

    // hi/lo fp16 channels-last conv scratch: 10 buffers = Mr2l region exactly
    _Float16* base = (_Float16*)Mr2l;
    _Float16* xl_h = base + 0*(size_t)NCL;
    _Float16* xl_l = base + 1*(size_t)NCL;
    _Float16* xr_h = base + 2*(size_t)NCL;
    _Float16* xr_l = base + 3*(size_t)NCL;
    _Float16* r_h  = base + 4*(size_t)NCL;
    _Float16* r_l  = base + 5*(size_t)NCL;
    _Float16* bl_h = base + 6*(size_t)NCL;
    _Float16* bl_l = base + 7*(size_t)NCL;
    _Float16* br_h = base + 8*(size_t)NCL;
    _Float16* br_l = base + 9*(size_t)NCL;
    _Float16* F0h = (_Float16*)Ml2r;
    _Float16* F0l = F0h + (size_t)NCL;
    _Float16* F1h = F0l + (size_t)NCL;
    _Float16* F1l = F1h + (size_t)NCL;
    float* S  = Mr2l;
    float* WT  = Ml2r + (size_t)N_M - WT_FLOATS;
    float* wlT = WT;
    float* wrT = WT + 4096;
    _Float16* wB1h = (_Float16*)(WT + 8192);
    _Float16* wB1l = wB1h + 36864;
    _Float16* wB2h = wB1l + 36864;
    _Float16* wB2l = wB2h + 36864;
    // partial stats in the outf region (consumed by k_smerge, which runs
    // before anything writes outf — stream order serializes kernels)
    float* colmax_p = out + 0;          // [1024][5][320]
    float* colsum_p = out + 1700000;
    float* rowmax_p = out + 3400000;
    float* rowsum_p = out + 5100000;

    // finals: d_ws if big enough (fused path: k_fused writes outf, so finals
    // must live outside d_out); else outf region + fallback kernels.
    const size_t FIN_FLOATS = (size_t)1024*320;          // per array
    bool fused = ws_size >= 4*FIN_FLOATS*sizeof(float);  // 5.24 MB
    float* colmax_f, *colinv_f, *rowmax_f, *rowinv_f;
    if (fused) {
        float* ws = (float*)d_ws;
        colmax_f = ws + 0*FIN_FLOATS;
        colinv_f = ws + 1*FIN_FLOATS;
        rowmax_f = ws + 2*FIN_FLOATS;
        rowinv_f = ws + 3*FIN_FLOATS;
    } else {
        colmax_f = out + 6800000;
        colinv_f = out + 7200000;
        rowmax_f = out + 7600000;
        rowinv_f = out + 8000000;
    }

    k_wt<<<64, 256, 0, stream>>>(w1, w2, wl, wr, wlT, wrT,
                                 wB1h, wB1l, wB2h, wB2l);

    dim3 pgrid(WW/64, HH, BB);
    k_prep<<<pgrid, 256, 0, stream>>>(x_l, xl_h, xl_l);
    k_prep<<<pgrid, 256, 0, stream>>>(x_r, xr_h, xr_l);

    k_conv3<<<pgrid, 256, 0, stream>>>(xl_h, xl_l, wB1h, wB1l,
                                       xl_h, xl_l, r_h, r_l, 0);
    k_conv3<<<pgrid, 256, 0, stream>>>(r_h, r_l, wB2h, wB2l,
                                       xl_h, xl_l, bl_h, bl_l, 1);
    k_conv3<<<pgrid, 256, 0, stream>>>(xr_h, xr_l, wB1h, wB1l,
                                       xr_h, xr_l, r_h, r_l, 0);
    k_conv3<<<pgrid, 256, 0, stream>>>(r_h, r_l, wB2h, wB2l,
                                       xr_h, xr_l, br_h, br_l, 1);

    int pblocks = (BB*HH*WW) / 256;          // 1280
    k_conv1x1<<<pblocks, 256, 0, stream>>>(bl_h, bl_l, wlT, bl, F0h, F0l);
    k_conv1x1<<<pblocks, 256, 0, stream>>>(br_h, br_l, wrT, br, F1h, F1l);

    dim3 sgrid(5, 5, BB*HH);
    k_sgemm<<<sgrid, 256, 0, stream>>>(F0h, F0l, F1h, F1l, S,
                                       colmax_p, colsum_p, rowmax_p, rowsum_p);

    k_smerge<<<BB*HH, 320, 0, stream>>>(colmax_p, colsum_p, rowmax_p, rowsum_p,
                                        colmax_f, colinv_f, rowmax_f, rowinv_f);

    if (fused) {
        dim3 fgrid(5, BB*HH);
        k_fused<<<fgrid, 256, 0, stream>>>(S, Ml2r, Vp, x_r, outf,
                                           colmax_f, colinv_f,
                                           rowmax_f, rowinv_f);
    } else {
        k_softmax<<<BB*HH, 320, 0, stream>>>(S, Ml2r, Vp,
                                             colmax_f, colinv_f,
                                             rowmax_f, rowinv_f);
        dim3 ogrid(5, BB*HH);
        k_outgemm<<<ogrid, 256, 0, stream>>>(Mr2l, x_r, outf);
    }
}

// Round 8
// 1266.992 us; speedup vs baseline: 3.9445x; 1.2060x over previous
//
#include <hip/hip_runtime.h>

#define BB 8
#define CC 64
#define HH 128
#define WW 320

// float offsets inside d_out
#define N_OUTF (BB*CC*HH*WW)           // 20,971,520
#define N_V    (BB*HH*WW)              // 327,680
#define N_M    (BB*HH*WW*WW)           // 104,857,600
#define OFF_V    (N_OUTF)
#define OFF_ML2R (N_OUTF + N_V)        // 21,299,200
#define OFF_MR2L (OFF_ML2R + N_M)      // 126,156,800
#define OUT_TOTAL (OFF_MR2L + N_M)     // 231,014,400
// weight tail at end of Ml2r region: 4x conv (36864 h) + 4x 1x1 (4096 h)
#define WT_FLOATS ((4*36864 + 4*4096)/2)           // 81,920 floats
#define NCL 20971520                   // halfs per channels-last buffer
#define INV512 (1.f/512.f)

typedef _Float16 half8 __attribute__((ext_vector_type(8)));
typedef _Float16 half4 __attribute__((ext_vector_type(4)));
typedef float f32x4 __attribute__((ext_vector_type(4)));

// ---------------------------------------------------------------------------
// Weights prep: rb_w -> fp16 hi/lo [co][tap][ci]; 1x1 -> fp16 hi/lo [co][ci].
__global__ __launch_bounds__(256) void k_wt(
    const float* __restrict__ w1, const float* __restrict__ w2,
    const float* __restrict__ wl, const float* __restrict__ wr,
    _Float16* __restrict__ wB1h, _Float16* __restrict__ wB1l,
    _Float16* __restrict__ wB2h, _Float16* __restrict__ wB2l,
    _Float16* __restrict__ wl1h, _Float16* __restrict__ wl1l,
    _Float16* __restrict__ wr1h, _Float16* __restrict__ wr1l)
{
    int tid = blockIdx.x * 256 + threadIdx.x;
    int stride = gridDim.x * 256;
    for (int e = tid; e < 64*9*64; e += stride) {   // e = co*576 + tap*64 + ci
        int co = e / 576;
        int rem = e - co*576;
        int tap = rem >> 6, ci = rem & 63;
        float v1 = w1[(co*64 + ci)*9 + tap];
        float v2 = w2[(co*64 + ci)*9 + tap];
        _Float16 h1 = (_Float16)v1, h2 = (_Float16)v2;
        wB1h[e] = h1; wB1l[e] = (_Float16)((v1 - (float)h1)*512.f);
        wB2h[e] = h2; wB2l[e] = (_Float16)((v2 - (float)h2)*512.f);
    }
    for (int e = tid; e < 4096; e += stride) {      // e = co*64 + ci
        float vl = wl[e], vr = wr[e];
        _Float16 hl = (_Float16)vl, hr = (_Float16)vr;
        wl1h[e] = hl; wl1l[e] = (_Float16)((vl - (float)hl)*512.f);
        wr1h[e] = hr; wr1l[e] = (_Float16)((vr - (float)hr)*512.f);
    }
}

// ---------------------------------------------------------------------------
// conv_a = prep + conv1: fp32 NCHW in, split-fp16 MFMA 3x3, LeakyReLU(0.1),
// hi/lo channels-last out. grid (5, 128, 8), 256 thr.
__global__ __launch_bounds__(256) void k_conv_a(
    const float* __restrict__ in,
    const _Float16* __restrict__ wBh, const _Float16* __restrict__ wBl,
    _Float16* __restrict__ out_h, _Float16* __restrict__ out_l)
{
    __shared__ __align__(16) char smem[2*3*66*128];    // 50688 B
    char* in_sh = smem;
    char* in_sl = smem + 25344;
    const int tid = threadIdx.x;
    const int x0 = blockIdx.x * 64;
    const int y  = blockIdx.y;
    const int b  = blockIdx.z;
    const int lane = tid & 63;
    const int xq = lane & 15, kq = lane >> 4;
    const int n = tid >> 6;                            // wave = co-tile

    half8 bwh[18], bwl[18];
    {
        const _Float16* wbh = &wBh[((size_t)(n*16 + xq)*9)*64 + kq*8];
        const _Float16* wbl = &wBl[((size_t)(n*16 + xq)*9)*64 + kq*8];
#pragma unroll
        for (int t = 0; t < 9; ++t)
#pragma unroll
            for (int c = 0; c < 2; ++c) {
                bwh[t*2 + c] = *(const half8*)&wbh[t*64 + c*32];
                bwl[t*2 + c] = *(const half8*)&wbl[t*64 + c*32];
            }
    }

    // stage: gather 8 strided fp32 per (ry, ci-octet, xx), split, swizzle-store
    for (int e = tid; e < 1584; e += 256) {
        int t = e / 66;
        int xx = e - t*66;
        int ry = t >> 3, u = t & 7;
        int gy = y + ry - 1, gx = x0 + xx - 1;
        half8 hh, hl;
#pragma unroll
        for (int j = 0; j < 8; ++j) { hh[j] = (_Float16)0.f; hl[j] = (_Float16)0.f; }
        if ((unsigned)gy < (unsigned)HH && (unsigned)gx < (unsigned)WW) {
            const float* p = &in[((size_t)(b*CC + u*8)*HH + gy)*WW + gx];
#pragma unroll
            for (int j = 0; j < 8; ++j) {
                float v = p[(size_t)j*HH*WW];
                _Float16 h = (_Float16)v;
                hh[j] = h; hl[j] = (_Float16)((v - (float)h)*512.f);
            }
        }
        int off = ((ry*66 + xx)*8 + (u ^ (xx & 7)))*16;
        *(half8*)&in_sh[off] = hh;
        *(half8*)&in_sl[off] = hl;
    }
    __syncthreads();

    f32x4 accm[4], accc[4];
#pragma unroll
    for (int m = 0; m < 4; ++m) { accm[m] = (f32x4)0.f; accc[m] = (f32x4)0.f; }

#pragma unroll
    for (int m = 0; m < 4; ++m) {
        const int xb = m*16 + xq;
#pragma unroll
        for (int t = 0; t < 9; ++t) {
            const int ry = t / 3, kx = t - ry*3;
            const int xxx = xb + kx;
#pragma unroll
            for (int c = 0; c < 2; ++c) {
                const int u = c*4 + kq;
                int off = ((ry*66 + xxx)*8 + (u ^ (xxx & 7)))*16;
                half8 ah = *(const half8*)&in_sh[off];
                half8 al = *(const half8*)&in_sl[off];
                accm[m] = __builtin_amdgcn_mfma_f32_16x16x32_f16(
                    ah, bwh[t*2 + c], accm[m], 0, 0, 0);
                accc[m] = __builtin_amdgcn_mfma_f32_16x16x32_f16(
                    al, bwh[t*2 + c], accc[m], 0, 0, 0);
                accc[m] = __builtin_amdgcn_mfma_f32_16x16x32_f16(
                    ah, bwl[t*2 + c], accc[m], 0, 0, 0);
            }
        }
    }
    __syncthreads();            // all waves done reading input tiles

    char* out_sh = smem;
    char* out_sl = smem + 8192;
#pragma unroll
    for (int m = 0; m < 4; ++m) {
#pragma unroll
        for (int r = 0; r < 4; ++r) {
            int x = m*16 + kq*4 + r;          // local x
            int co = n*16 + xq;
            float v = accm[m][r] + accc[m][r]*INV512;
            v = (v > 0.f) ? v : 0.1f*v;       // LeakyReLU
            _Float16 vh = (_Float16)v;
            _Float16 vl = (_Float16)((v - (float)vh)*512.f);
            int boff = (x*8 + ((co >> 3) ^ (x & 7)))*16 + (co & 7)*2;
            *(_Float16*)&out_sh[boff] = vh;
            *(_Float16*)&out_sl[boff] = vl;
        }
    }
    __syncthreads();

#pragma unroll
    for (int i = 0; i < 2; ++i) {
        int unit = tid + 256*i;               // 0..511
        int x = unit >> 3, u = unit & 7;
        int loff = (x*8 + (u ^ (x & 7)))*16;
        size_t g = (((size_t)(b*HH + y)*WW) + x0 + x)*64 + u*8;
        *(half8*)&out_h[g] = *(half8*)&out_sh[loff];
        *(half8*)&out_l[g] = *(half8*)&out_sl[loff];
    }
}

// ---------------------------------------------------------------------------
// conv_b = conv2 + residual + 1x1 projection:
//   conv2 raw out (split-fp16 MFMA), then F = [W|W] @ [conv_out | res] + bias
//   as a K=128 split-fp16 GEMM (residual enters as k-chunks 2-3, never
//   materialized). F written hi/lo channels-last.
__global__ __launch_bounds__(256) void k_conv_b(
    const _Float16* __restrict__ in_h, const _Float16* __restrict__ in_l,
    const _Float16* __restrict__ wBh, const _Float16* __restrict__ wBl,
    const float* __restrict__ res,                    // fp32 NCHW x
    const _Float16* __restrict__ w1h, const _Float16* __restrict__ w1l,
    const float* __restrict__ bias,
    _Float16* __restrict__ Fh, _Float16* __restrict__ Fl)
{
    __shared__ __align__(16) char smem[2*3*66*128];    // 50688 B
    // phase 1: in_sh [0:25344], in_sl [25344:50688]
    // phase 2: out_sh [0:8192], out_sl [8192:16384], res_sh [16384:24576],
    //          res_sl [24576:32768], w_sh [32768:40960], w_sl [40960:49152]
    // phase 3: F_sh/F_sl alias res_sh/res_sl
    char* in_sh = smem;
    char* in_sl = smem + 25344;
    const int tid = threadIdx.x;
    const int x0 = blockIdx.x * 64;
    const int y  = blockIdx.y;
    const int b  = blockIdx.z;
    const int lane = tid & 63;
    const int xq = lane & 15, kq = lane >> 4;
    const int n = tid >> 6;

    half8 bwh[18], bwl[18];
    {
        const _Float16* wbh = &wBh[((size_t)(n*16 + xq)*9)*64 + kq*8];
        const _Float16* wbl = &wBl[((size_t)(n*16 + xq)*9)*64 + kq*8];
#pragma unroll
        for (int t = 0; t < 9; ++t)
#pragma unroll
            for (int c = 0; c < 2; ++c) {
                bwh[t*2 + c] = *(const half8*)&wbh[t*64 + c*32];
                bwl[t*2 + c] = *(const half8*)&wbl[t*64 + c*32];
            }
    }

    for (int e = tid; e < 3*66*8; e += 256) {
        int ry = e / 528;
        int rem = e - ry*528;
        int xx = rem >> 3, u = rem & 7;
        int gy = y + ry - 1, gx = x0 + xx - 1;
        uint4 vh = make_uint4(0u,0u,0u,0u), vl = make_uint4(0u,0u,0u,0u);
        if ((unsigned)gy < (unsigned)HH && (unsigned)gx < (unsigned)WW) {
            size_t g = (((size_t)(b*HH + gy)*WW) + gx)*64 + u*8;
            vh = *(const uint4*)&in_h[g];
            vl = *(const uint4*)&in_l[g];
        }
        int off = ((ry*66 + xx)*8 + (u ^ (xx & 7)))*16;
        *(uint4*)&in_sh[off] = vh;
        *(uint4*)&in_sl[off] = vl;
    }
    __syncthreads();

    f32x4 accm[4], accc[4];
#pragma unroll
    for (int m = 0; m < 4; ++m) { accm[m] = (f32x4)0.f; accc[m] = (f32x4)0.f; }

#pragma unroll
    for (int m = 0; m < 4; ++m) {
        const int xb = m*16 + xq;
#pragma unroll
        for (int t = 0; t < 9; ++t) {
            const int ry = t / 3, kx = t - ry*3;
            const int xxx = xb + kx;
#pragma unroll
            for (int c = 0; c < 2; ++c) {
                const int u = c*4 + kq;
                int off = ((ry*66 + xxx)*8 + (u ^ (xxx & 7)))*16;
                half8 ah = *(const half8*)&in_sh[off];
                half8 al = *(const half8*)&in_sl[off];
                accm[m] = __builtin_amdgcn_mfma_f32_16x16x32_f16(
                    ah, bwh[t*2 + c], accm[m], 0, 0, 0);
                accc[m] = __builtin_amdgcn_mfma_f32_16x16x32_f16(
                    al, bwh[t*2 + c], accc[m], 0, 0, 0);
                accc[m] = __builtin_amdgcn_mfma_f32_16x16x32_f16(
                    ah, bwl[t*2 + c], accc[m], 0, 0, 0);
            }
        }
    }
    __syncthreads();            // in_s dead; phase 2 regions live

    char* out_sh = smem;
    char* out_sl = smem + 8192;
    char* res_sh = smem + 16384;
    char* res_sl = smem + 24576;
    char* w_sh   = smem + 32768;
    char* w_sl   = smem + 40960;

    // stage residual (fp32 NCHW row y -> split hi/lo, swizzled)
#pragma unroll
    for (int i = 0; i < 2; ++i) {
        int unit = tid + 256*i;               // x = lane, cu = wid + 4i
        int x = unit & 63, cu = unit >> 6;
        const float* p = &res[((size_t)(b*CC + cu*8)*HH + y)*WW + x0 + x];
        half8 hh, hl;
#pragma unroll
        for (int j = 0; j < 8; ++j) {
            float v = p[(size_t)j*HH*WW];
            _Float16 h = (_Float16)v;
            hh[j] = h; hl[j] = (_Float16)((v - (float)h)*512.f);
        }
        int off = (x*8 + (cu ^ (x & 7)))*16;
        *(half8*)&res_sh[off] = hh;
        *(half8*)&res_sl[off] = hl;
    }
    // stage 1x1 weights [co][ci] hi/lo, swizzled
#pragma unroll
    for (int i = 0; i < 2; ++i) {
        int e = tid + 256*i;                  // 0..511
        int co = e >> 3, u = e & 7;
        int off = (co*8 + (u ^ (co & 7)))*16;
        *(half8*)&w_sh[off] = *(const half8*)&w1h[co*64 + u*8];
        *(half8*)&w_sl[off] = *(const half8*)&w1l[co*64 + u*8];
    }
    // conv2 raw output -> split hi/lo into out_s tiles (no activation)
#pragma unroll
    for (int m = 0; m < 4; ++m) {
#pragma unroll
        for (int r = 0; r < 4; ++r) {
            int x = m*16 + kq*4 + r;
            int co = n*16 + xq;
            float v = accm[m][r] + accc[m][r]*INV512;
            _Float16 vh = (_Float16)v;
            _Float16 vl = (_Float16)((v - (float)vh)*512.f);
            int boff = (x*8 + ((co >> 3) ^ (x & 7)))*16 + (co & 7)*2;
            *(_Float16*)&out_sh[boff] = vh;
            *(_Float16*)&out_sl[boff] = vl;
        }
    }
    __syncthreads();

    // 1x1 as K=128 split-fp16 GEMM: A = [out | res], B = [W | W]
    float bv[4];
#pragma unroll
    for (int nn = 0; nn < 4; ++nn) bv[nn] = bias[nn*16 + (lane & 15)];

    f32x4 am[4], ac[4];
#pragma unroll
    for (int nn = 0; nn < 4; ++nn) { am[nn] = (f32x4)0.f; ac[nn] = (f32x4)0.f; }

    const int arow = (tid >> 6)*16 + (lane & 15);     // wave's x-rows
#pragma unroll
    for (int c = 0; c < 4; ++c) {
        half8 ah, al;
        if (c < 2) {
            int u = c*4 + (lane >> 4);
            int off = (arow*8 + (u ^ (arow & 7)))*16;
            ah = *(const half8*)&out_sh[off];
            al = *(const half8*)&out_sl[off];
        } else {
            int u = (c - 2)*4 + (lane >> 4);
            int off = (arow*8 + (u ^ (arow & 7)))*16;
            ah = *(const half8*)&res_sh[off];
            al = *(const half8*)&res_sl[off];
        }
        int wu = (c & 1)*4 + (lane >> 4);
#pragma unroll
        for (int nn = 0; nn < 4; ++nn) {
            int brow = nn*16 + (lane & 15);
            int woff = (brow*8 + (wu ^ (brow & 7)))*16;
            half8 bh  = *(const half8*)&w_sh[woff];
            half8 blw = *(const half8*)&w_sl[woff];
            am[nn] = __builtin_amdgcn_mfma_f32_16x16x32_f16(ah, bh,  am[nn], 0,0,0);
            ac[nn] = __builtin_amdgcn_mfma_f32_16x16x32_f16(al, bh,  ac[nn], 0,0,0);
            ac[nn] = __builtin_amdgcn_mfma_f32_16x16x32_f16(ah, blw, ac[nn], 0,0,0);
        }
    }
    __syncthreads();            // res_s dead; F tiles may alias it

    char* F_sh = smem + 16384;
    char* F_sl = smem + 24576;
#pragma unroll
    for (int nn = 0; nn < 4; ++nn) {
#pragma unroll
        for (int r = 0; r < 4; ++r) {
            int x = (tid >> 6)*16 + (lane >> 4)*4 + r;
            int co = nn*16 + (lane & 15);
            float v = am[nn][r] + ac[nn][r]*INV512 + bv[nn];
            _Float16 vh = (_Float16)v;
            _Float16 vl = (_Float16)((v - (float)vh)*512.f);
            int boff = (x*8 + ((co >> 3) ^ (x & 7)))*16 + (co & 7)*2;
            *(_Float16*)&F_sh[boff] = vh;
            *(_Float16*)&F_sl[boff] = vl;
        }
    }
    __syncthreads();

#pragma unroll
    for (int i = 0; i < 2; ++i) {
        int unit = tid + 256*i;
        int x = unit >> 3, u = unit & 7;
        int loff = (x*8 + (u ^ (x & 7)))*16;
        size_t g = (((size_t)(b*HH + y)*WW) + x0 + x)*64 + u*8;
        *(half8*)&Fh[g] = *(half8*)&F_sh[loff];
        *(half8*)&Fl[g] = *(half8*)&F_sl[loff];
    }
}

// ---------------------------------------------------------------------------
// Split-fp16 MFMA S-GEMM + fused softmax stats (partials).
__global__ __launch_bounds__(256) void k_sgemm(
    const _Float16* __restrict__ F0h, const _Float16* __restrict__ F0l,
    const _Float16* __restrict__ F1h, const _Float16* __restrict__ F1l,
    float* __restrict__ S,
    float* __restrict__ colmax_p, float* __restrict__ colsum_p,
    float* __restrict__ rowmax_p, float* __restrict__ rowsum_p)
{
    __shared__ __align__(16) char Ah[8192], Al[8192], Bh[8192], Bl[8192];
    __shared__ float cpm[4][64], cpl[4][64];
    const int wt = blockIdx.x, vt = blockIdx.y, row = blockIdx.z;
    const int tid = threadIdx.x, lane = tid & 63, wid = tid >> 6;

    for (int e = tid; e < 512; e += 256) {
        int i = e >> 3, u = e & 7;
        size_t ga = ((size_t)row*WW + wt*64 + i)*64 + u*8;
        size_t gb = ((size_t)row*WW + vt*64 + i)*64 + u*8;
        int off = (i*8 + (u ^ (i & 7)))*16;
        *(uint4*)&Ah[off] = *(const uint4*)&F0h[ga];
        *(uint4*)&Al[off] = *(const uint4*)&F0l[ga];
        *(uint4*)&Bh[off] = *(const uint4*)&F1h[gb];
        *(uint4*)&Bl[off] = *(const uint4*)&F1l[gb];
    }
    __syncthreads();

    f32x4 accm[4], accc[4];
#pragma unroll
    for (int n = 0; n < 4; ++n) { accm[n] = (f32x4)0.f; accc[n] = (f32x4)0.f; }

#pragma unroll
    for (int c = 0; c < 2; ++c) {
        const int u = c*4 + (lane >> 4);
        const int arow = wid*16 + (lane & 15);
        int aoff = (arow*8 + (u ^ (arow & 7)))*16;
        half8 ah = *(const half8*)&Ah[aoff];
        half8 al = *(const half8*)&Al[aoff];
#pragma unroll
        for (int n = 0; n < 4; ++n) {
            const int brow = n*16 + (lane & 15);
            int boff = (brow*8 + (u ^ (brow & 7)))*16;
            half8 bh = *(const half8*)&Bh[boff];
            half8 bl = *(const half8*)&Bl[boff];
            accm[n] = __builtin_amdgcn_mfma_f32_16x16x32_f16(ah, bh, accm[n], 0,0,0);
            accc[n] = __builtin_amdgcn_mfma_f32_16x16x32_f16(al, bh, accc[n], 0,0,0);
            accc[n] = __builtin_amdgcn_mfma_f32_16x16x32_f16(ah, bl, accc[n], 0,0,0);
        }
    }

    float sv[4][4];
#pragma unroll
    for (int n = 0; n < 4; ++n)
#pragma unroll
        for (int r = 0; r < 4; ++r)
            sv[n][r] = accm[n][r] + accc[n][r]*INV512;

#pragma unroll
    for (int n = 0; n < 4; ++n) {
        float* sp = &S[((size_t)row*WW + wt*64 + wid*16 + (lane>>4)*4)*WW
                       + vt*64 + n*16 + (lane & 15)];
#pragma unroll
        for (int r = 0; r < 4; ++r) sp[(size_t)r*WW] = sv[n][r];
    }

    // ---- row stats (over the 64 v of this tile)
    float rmax[4], rsum[4];
#pragma unroll
    for (int r = 0; r < 4; ++r) {
        float m = fmaxf(fmaxf(sv[0][r], sv[1][r]), fmaxf(sv[2][r], sv[3][r]));
        m = fmaxf(m, __shfl_xor(m, 1));
        m = fmaxf(m, __shfl_xor(m, 2));
        m = fmaxf(m, __shfl_xor(m, 4));
        m = fmaxf(m, __shfl_xor(m, 8));
        rmax[r] = m;
        float l = __expf(sv[0][r]-m) + __expf(sv[1][r]-m)
                + __expf(sv[2][r]-m) + __expf(sv[3][r]-m);
        l += __shfl_xor(l, 1); l += __shfl_xor(l, 2);
        l += __shfl_xor(l, 4); l += __shfl_xor(l, 8);
        rsum[r] = l;
    }
    if ((lane & 15) == 0) {
        size_t rbase = ((size_t)row*5 + vt)*WW + wt*64 + wid*16 + (lane>>4)*4;
#pragma unroll
        for (int r = 0; r < 4; ++r) {
            rowmax_p[rbase + r] = rmax[r];
            rowsum_p[rbase + r] = rsum[r];
        }
    }

    // ---- col stats (over the 64 w of this tile)
#pragma unroll
    for (int n = 0; n < 4; ++n) {
        float m = fmaxf(fmaxf(sv[n][0], sv[n][1]), fmaxf(sv[n][2], sv[n][3]));
        m = fmaxf(m, __shfl_xor(m, 16));
        m = fmaxf(m, __shfl_xor(m, 32));
        float l = __expf(sv[n][0]-m) + __expf(sv[n][1]-m)
                + __expf(sv[n][2]-m) + __expf(sv[n][3]-m);
        l += __shfl_xor(l, 16); l += __shfl_xor(l, 32);
        if (lane < 16) { cpm[wid][n*16 + lane] = m; cpl[wid][n*16 + lane] = l; }
    }
    __syncthreads();
    if (tid < 64) {
        float m0 = cpm[0][tid], m1 = cpm[1][tid], m2 = cpm[2][tid], m3 = cpm[3][tid];
        float m = fmaxf(fmaxf(m0, m1), fmaxf(m2, m3));
        float l = cpl[0][tid]*__expf(m0 - m) + cpl[1][tid]*__expf(m1 - m)
                + cpl[2][tid]*__expf(m2 - m) + cpl[3][tid]*__expf(m3 - m);
        size_t cbase = ((size_t)row*5 + wt)*WW + vt*64 + tid;
        colmax_p[cbase] = m;
        colsum_p[cbase] = l;
    }
}

// ---------------------------------------------------------------------------
// Merge 5 partials per row/col into final max + 1/sum. grid 1024 x 320 thr.
__global__ __launch_bounds__(320) void k_smerge(
    const float* __restrict__ colmax_p, const float* __restrict__ colsum_p,
    const float* __restrict__ rowmax_p, const float* __restrict__ rowsum_p,
    float* __restrict__ colmax_f, float* __restrict__ colinv_f,
    float* __restrict__ rowmax_f, float* __restrict__ rowinv_f)
{
    const int row = blockIdx.x, tid = threadIdx.x;
    float m = -1e30f, l = 0.f;
#pragma unroll
    for (int t = 0; t < 5; ++t) {
        float pm = colmax_p[((size_t)row*5 + t)*WW + tid];
        float pl = colsum_p[((size_t)row*5 + t)*WW + tid];
        float m2 = fmaxf(m, pm);
        l = l*__expf(m - m2) + pl*__expf(pm - m2);
        m = m2;
    }
    colmax_f[(size_t)row*WW + tid] = m;
    colinv_f[(size_t)row*WW + tid] = 1.f/l;
    m = -1e30f; l = 0.f;
#pragma unroll
    for (int t = 0; t < 5; ++t) {
        float pm = rowmax_p[((size_t)row*5 + t)*WW + tid];
        float pl = rowsum_p[((size_t)row*5 + t)*WW + tid];
        float m2 = fmaxf(m, pm);
        l = l*__expf(m - m2) + pl*__expf(pm - m2);
        m = m2;
    }
    rowmax_f[(size_t)row*WW + tid] = m;
    rowinv_f[(size_t)row*WW + tid] = 1.f/l;
}

// ---------------------------------------------------------------------------
// FUSED softmax-apply + out-GEMM. grid (5 wt, 1024 row), 256 thr.
__global__ __launch_bounds__(256) void k_fused(
    float* __restrict__ S, float* __restrict__ Ml2r, float* __restrict__ Vout,
    const float* __restrict__ xr, float* __restrict__ outf,
    const float* __restrict__ colmax_f, const float* __restrict__ colinv_f,
    const float* __restrict__ rowmax_f, const float* __restrict__ rowinv_f)
{
    __shared__ __align__(16) char A[8192], Bm[8192];   // fp16 tiles, swizzled
    __shared__ float T[64*65];                          // Ml2r transpose tile
    __shared__ float cmx[320], cin[320], rmx[64], rin[64];
    const int wt = blockIdx.x, row = blockIdx.y;
    const int b = row >> 7, h = row & 127;
    const int tid = threadIdx.x, lane = tid & 63, wid = tid >> 6;
    const int wrow = tid >> 2, quad = tid & 3;

    for (int e = tid; e < 320; e += 256) {
        cmx[e] = colmax_f[(size_t)row*WW + e];
        cin[e] = colinv_f[(size_t)row*WW + e];
    }
    if (tid < 64) {
        rmx[tid] = rowmax_f[(size_t)row*WW + wt*64 + tid];
        rin[tid] = rowinv_f[(size_t)row*WW + wt*64 + tid];
    }
    __syncthreads();

    f32x4 acc[4];
#pragma unroll
    for (int n = 0; n < 4; ++n) acc[n] = (f32x4)0.f;
    float vsum = 0.f;
    float* Sbase = &S[((size_t)row*WW + wt*64 + wrow)*WW];
    const float rm = rmx[wrow], ri = rin[wrow];

    for (int vt = 0; vt < 5; ++vt) {
        if (vt) __syncthreads();
#pragma unroll
        for (int i = 0; i < 4; ++i) {
            const int f = quad + 4*i;
            const int v0 = f*4;
            float4 s = *(float4*)&Sbase[vt*64 + v0];
            float4 pr;
            pr.x = __expf(s.x - rm)*ri;
            pr.y = __expf(s.y - rm)*ri;
            pr.z = __expf(s.z - rm)*ri;
            pr.w = __expf(s.w - rm)*ri;
            *(float4*)&Sbase[vt*64 + v0] = pr;      // Mr2l in place
            const int vg = vt*64 + v0;
            float p0 = __expf(s.x - cmx[vg+0])*cin[vg+0];
            float p1 = __expf(s.y - cmx[vg+1])*cin[vg+1];
            float p2 = __expf(s.z - cmx[vg+2])*cin[vg+2];
            float p3 = __expf(s.w - cmx[vg+3])*cin[vg+3];
            T[(v0+0)*65 + wrow] = p0;
            T[(v0+1)*65 + wrow] = p1;
            T[(v0+2)*65 + wrow] = p2;
            T[(v0+3)*65 + wrow] = p3;
            vsum += p0 + p1 + p2 + p3;
            half4 hp;
            hp[0] = (_Float16)pr.x; hp[1] = (_Float16)pr.y;
            hp[2] = (_Float16)pr.z; hp[3] = (_Float16)pr.w;
            *(half4*)&A[(wrow*8 + ((f>>1) ^ (wrow & 7)))*16 + (f & 1)*8] = hp;
        }
        for (int e = tid; e < 512; e += 256) {
            int i = e >> 3, u = e & 7;
            const float4* xp = (const float4*)
                &xr[(((size_t)b*CC + i)*HH + h)*WW + vt*64 + u*8];
            float4 b0 = xp[0], b1 = xp[1];
            half8 hb;
            hb[0]=(_Float16)b0.x; hb[1]=(_Float16)b0.y; hb[2]=(_Float16)b0.z;
            hb[3]=(_Float16)b0.w; hb[4]=(_Float16)b1.x; hb[5]=(_Float16)b1.y;
            hb[6]=(_Float16)b1.z; hb[7]=(_Float16)b1.w;
            *(half8*)&Bm[(i*8 + (u ^ (i & 7)))*16] = hb;
        }
        __syncthreads();
#pragma unroll
        for (int c = 0; c < 2; ++c) {
            const int u = c*4 + (lane >> 4);
            const int arow = wid*16 + (lane & 15);
            half8 ah = *(const half8*)&A[(arow*8 + (u ^ (arow & 7)))*16];
#pragma unroll
            for (int n = 0; n < 4; ++n) {
                const int brow = n*16 + (lane & 15);
                half8 bh = *(const half8*)&Bm[(brow*8 + (u ^ (brow & 7)))*16];
                acc[n] = __builtin_amdgcn_mfma_f32_16x16x32_f16(ah, bh, acc[n], 0,0,0);
            }
        }
        for (int e = tid; e < 4096; e += 256) {
            int vr = e >> 6, wc = e & 63;
            Ml2r[((size_t)row*WW + vt*64 + vr)*WW + wt*64 + wc] = T[vr*65 + wc];
        }
    }

    vsum += __shfl_xor(vsum, 1);
    vsum += __shfl_xor(vsum, 2);
    if (quad == 0)
        Vout[(size_t)row*WW + wt*64 + wrow] = (vsum > 0.1f) ? 1.f : 0.f;

#pragma unroll
    for (int n = 0; n < 4; ++n) {
        *(float4*)&outf[(((size_t)b*CC + n*16 + (lane & 15))*HH + h)*WW
                        + wt*64 + wid*16 + (lane>>4)*4] =
            make_float4(acc[n][0], acc[n][1], acc[n][2], acc[n][3]);
    }
}

// ---------------------------------------------------------------------------
// FALLBACK path (ws too small): separate softmax-apply and out-GEMM.
__global__ __launch_bounds__(320) void k_softmax(
    float* __restrict__ S, float* __restrict__ Ml2r, float* __restrict__ Vout,
    const float* __restrict__ colmax_f, const float* __restrict__ colinv_f,
    const float* __restrict__ rowmax_f, const float* __restrict__ rowinv_f)
{
    __shared__ float rowmax[320], rowinv[320], colmax[320], colinv[320];
    __shared__ float T[64*65];
    __shared__ float Vp2[5*64];
    const int row = blockIdx.x;
    const int tid = threadIdx.x;
    float* Srow = &S[(size_t)row * WW * WW];

    rowmax[tid] = rowmax_f[(size_t)row*WW + tid];
    rowinv[tid] = rowinv_f[(size_t)row*WW + tid];
    colmax[tid] = colmax_f[(size_t)row*WW + tid];
    colinv[tid] = colinv_f[(size_t)row*WW + tid];
    __syncthreads();

    const int myw = tid & 63;
    const int myg = tid / 64;
    for (int wt = 0; wt < 5; ++wt) {
        float vpart = 0.f;
        for (int vt = 0; vt < 5; ++vt) {
            for (int e = tid; e < 4096; e += 320) {
                int i = e >> 6, j = e & 63;
                int wgl = wt*64 + i, vgl = vt*64 + j;
                size_t si = (size_t)wgl*WW + vgl;
                float s = Srow[si];
                Srow[si] = __expf(s - rowmax[wgl]) * rowinv[wgl];
                T[j*65 + i] = __expf(s - colmax[vgl]) * colinv[vgl];
            }
            __syncthreads();
            for (int e = tid; e < 4096; e += 320) {
                int vr = e >> 6, wc = e & 63;
                Ml2r[((size_t)row*WW + vt*64 + vr)*WW + wt*64 + wc] = T[vr*65 + wc];
            }
            for (int j = myg; j < 64; j += 5) vpart += T[j*65 + myw];
            __syncthreads();
        }
        Vp2[myg*64 + myw] = vpart;
        __syncthreads();
        if (tid < 64) {
            float sv = 0.f;
#pragma unroll
            for (int g = 0; g < 5; ++g) sv += Vp2[g*64 + tid];
            Vout[(size_t)row*WW + wt*64 + tid] = (sv > 0.1f) ? 1.f : 0.f;
        }
        __syncthreads();
    }
}

__global__ __launch_bounds__(256) void k_outgemm(
    const float* __restrict__ M, const float* __restrict__ xr,
    float* __restrict__ outf)
{
    __shared__ __align__(16) char Am[8192], Bm[8192];
    const int wt = blockIdx.x;
    const int row = blockIdx.y;
    const int b = row >> 7, h = row & 127;
    const int tid = threadIdx.x, lane = tid & 63, wid = tid >> 6;

    f32x4 acc[4];
#pragma unroll
    for (int n = 0; n < 4; ++n) acc[n] = (f32x4)0.f;

    for (int vt = 0; vt < 5; ++vt) {
        if (vt) __syncthreads();
        for (int e = tid; e < 512; e += 256) {
            int i = e >> 3, u = e & 7;
            const float4* mp = (const float4*)
                &M[((size_t)row*WW + wt*64 + i)*WW + vt*64 + u*8];
            float4 a0 = mp[0], a1 = mp[1];
            const float4* xp = (const float4*)
                &xr[(((size_t)b*CC + i)*HH + h)*WW + vt*64 + u*8];
            float4 b0 = xp[0], b1 = xp[1];
            half8 ha, hb;
            ha[0]=(_Float16)a0.x; ha[1]=(_Float16)a0.y; ha[2]=(_Float16)a0.z;
            ha[3]=(_Float16)a0.w; ha[4]=(_Float16)a1.x; ha[5]=(_Float16)a1.y;
            ha[6]=(_Float16)a1.z; ha[7]=(_Float16)a1.w;
            hb[0]=(_Float16)b0.x; hb[1]=(_Float16)b0.y; hb[2]=(_Float16)b0.z;
            hb[3]=(_Float16)b0.w; hb[4]=(_Float16)b1.x; hb[5]=(_Float16)b1.y;
            hb[6]=(_Float16)b1.z; hb[7]=(_Float16)b1.w;
            int off = (i*8 + (u ^ (i & 7)))*16;
            *(half8*)&Am[off] = ha;
            *(half8*)&Bm[off] = hb;
        }
        __syncthreads();
#pragma unroll
        for (int c = 0; c < 2; ++c) {
            const int u = c*4 + (lane >> 4);
            const int arow = wid*16 + (lane & 15);
            half8 ah = *(const half8*)&Am[(arow*8 + (u ^ (arow & 7)))*16];
#pragma unroll
            for (int n = 0; n < 4; ++n) {
                const int brow = n*16 + (lane & 15);
                half8 bh = *(const half8*)&Bm[(brow*8 + (u ^ (brow & 7)))*16];
                acc[n] = __builtin_amdgcn_mfma_f32_16x16x32_f16(ah, bh, acc[n], 0,0,0);
            }
        }
    }

#pragma unroll
    for (int n = 0; n < 4; ++n) {
        *(float4*)&outf[(((size_t)b*CC + n*16 + (lane & 15))*HH + h)*WW
                        + wt*64 + wid*16 + (lane>>4)*4] =
            make_float4(acc[n][0], acc[n][1], acc[n][2], acc[n][3]);
    }
}

// ---------------------------------------------------------------------------
extern "C" void kernel_launch(void* const* d_in, const int* in_sizes, int n_in,
                              void* d_out, int out_size, void* d_ws, size_t ws_size,
                              hipStream_t stream)
{
    const float* x_l = (const float*)d_in[0];
    const float* x_r = (const float*)d_in[1];
    const float* w1  = (const float*)d_in[2];
    const float* w2  = (const float*)d_in[3];
    const float* wl  = (const float*)d_in[4];
    const float* bl  = (const float*)d_in[5];
    const float* wr  = (const float*)d_in[6];
    const float* br  = (const float*)d_in[7];
    float* out = (float*)d_out;

    float* outf = out;
    float* Vp   = out + OFF_V;
    float* Ml2r = out + OFF_ML2R;
    float* Mr2l = out + OFF_MR2L;

    // r (conv1 output) hi/lo in Mr2l region; reused for left then right side
    _Float16* r_h = (_Float16*)Mr2l;
    _Float16* r_l = r_h + (size_t)NCL;
    // F hi/lo in Ml2r region; conv/1x1 weights at its tail
    _Float16* F0h = (_Float16*)Ml2r;
    _Float16* F0l = F0h + (size_t)NCL;
    _Float16* F1h = F0l + (size_t)NCL;
    _Float16* F1l = F1h + (size_t)NCL;
    float* S  = Mr2l;
    _Float16* WTH = (_Float16*)(Ml2r + (size_t)N_M - WT_FLOATS);
    _Float16* wB1h = WTH;
    _Float16* wB1l = WTH + 36864;
    _Float16* wB2h = WTH + 73728;
    _Float16* wB2l = WTH + 110592;
    _Float16* wl1h = WTH + 147456;
    _Float16* wl1l = WTH + 151552;
    _Float16* wr1h = WTH + 155648;
    _Float16* wr1l = WTH + 159744;
    // partial stats in the outf region (consumed before outf is written)
    float* colmax_p = out + 0;          // [1024][5][320]
    float* colsum_p = out + 1700000;
    float* rowmax_p = out + 3400000;
    float* rowsum_p = out + 5100000;

    const size_t FIN_FLOATS = (size_t)1024*320;
    bool fused = ws_size >= 4*FIN_FLOATS*sizeof(float);  // 5.24 MB
    float* colmax_f, *colinv_f, *rowmax_f, *rowinv_f;
    if (fused) {
        float* ws = (float*)d_ws;
        colmax_f = ws + 0*FIN_FLOATS;
        colinv_f = ws + 1*FIN_FLOATS;
        rowmax_f = ws + 2*FIN_FLOATS;
        rowinv_f = ws + 3*FIN_FLOATS;
    } else {
        colmax_f = out + 6800000;
        colinv_f = out + 7200000;
        rowmax_f = out + 7600000;
        rowinv_f = out + 8000000;
    }

    k_wt<<<64, 256, 0, stream>>>(w1, w2, wl, wr,
                                 wB1h, wB1l, wB2h, wB2l,
                                 wl1h, wl1l, wr1h, wr1l);

    dim3 pgrid(WW/64, HH, BB);
    k_conv_a<<<pgrid, 256, 0, stream>>>(x_l, wB1h, wB1l, r_h, r_l);
    k_conv_b<<<pgrid, 256, 0, stream>>>(r_h, r_l, wB2h, wB2l, x_l,
                                        wl1h, wl1l, bl, F0h, F0l);
    k_conv_a<<<pgrid, 256, 0, stream>>>(x_r, wB1h, wB1l, r_h, r_l);
    k_conv_b<<<pgrid, 256, 0, stream>>>(r_h, r_l, wB2h, wB2l, x_r,
                                        wr1h, wr1l, br, F1h, F1l);

    dim3 sgrid(5, 5, BB*HH);
    k_sgemm<<<sgrid, 256, 0, stream>>>(F0h, F0l, F1h, F1l, S,
                                       colmax_p, colsum_p, rowmax_p, rowsum_p);

    k_smerge<<<BB*HH, 320, 0, stream>>>(colmax_p, colsum_p, rowmax_p, rowsum_p,
                                        colmax_f, colinv_f, rowmax_f, rowinv_f);

    if (fused) {
        dim3 fgrid(5, BB*HH);
        k_fused<<<fgrid, 256, 0, stream>>>(S, Ml2r, Vp, x_r, outf,
                                           colmax_f, colinv_f,
                                           rowmax_f, rowinv_f);
    } else {
        k_softmax<<<BB*HH, 320, 0, stream>>>(S, Ml2r, Vp,
                                             colmax_f, colinv_f,
                                             rowmax_f, rowinv_f);
        dim3 ogrid(5, BB*HH);
        k_outgemm<<<ogrid, 256, 0, stream>>>(Mr2l, x_r, outf);
    }
}

// Round 9
// 1165.687 us; speedup vs baseline: 4.2873x; 1.0869x over previous
//
#include <hip/hip_runtime.h>

#define BB 8
#define CC 64
#define HH 128
#define WW 320

// float offsets inside d_out
#define N_OUTF (BB*CC*HH*WW)           // 20,971,520
#define N_V    (BB*HH*WW)              // 327,680
#define N_M    (BB*HH*WW*WW)           // 104,857,600
#define OFF_V    (N_OUTF)
#define OFF_ML2R (N_OUTF + N_V)        // 21,299,200
#define OFF_MR2L (OFF_ML2R + N_M)      // 126,156,800
#define OUT_TOTAL (OFF_MR2L + N_M)     // 231,014,400
// weight tail at end of Ml2r region: 4x conv (36864 h) + 4x 1x1 (4096 h)
#define WT_FLOATS ((4*36864 + 4*4096)/2)           // 81,920 floats
#define NCL 20971520                   // halfs per channels-last buffer
#define INV512 (1.f/512.f)

typedef _Float16 half8 __attribute__((ext_vector_type(8)));
typedef _Float16 half4 __attribute__((ext_vector_type(4)));
typedef float f32x4 __attribute__((ext_vector_type(4)));

// ---------------------------------------------------------------------------
// Weights prep: rb_w -> fp16 hi/lo [co][tap][ci]; 1x1 -> fp16 hi/lo [co][ci].
__global__ __launch_bounds__(256) void k_wt(
    const float* __restrict__ w1, const float* __restrict__ w2,
    const float* __restrict__ wl, const float* __restrict__ wr,
    _Float16* __restrict__ wB1h, _Float16* __restrict__ wB1l,
    _Float16* __restrict__ wB2h, _Float16* __restrict__ wB2l,
    _Float16* __restrict__ wl1h, _Float16* __restrict__ wl1l,
    _Float16* __restrict__ wr1h, _Float16* __restrict__ wr1l)
{
    int tid = blockIdx.x * 256 + threadIdx.x;
    int stride = gridDim.x * 256;
    for (int e = tid; e < 64*9*64; e += stride) {   // e = co*576 + tap*64 + ci
        int co = e / 576;
        int rem = e - co*576;
        int tap = rem >> 6, ci = rem & 63;
        float v1 = w1[(co*64 + ci)*9 + tap];
        float v2 = w2[(co*64 + ci)*9 + tap];
        _Float16 h1 = (_Float16)v1, h2 = (_Float16)v2;
        wB1h[e] = h1; wB1l[e] = (_Float16)((v1 - (float)h1)*512.f);
        wB2h[e] = h2; wB2l[e] = (_Float16)((v2 - (float)h2)*512.f);
    }
    for (int e = tid; e < 4096; e += stride) {      // e = co*64 + ci
        float vl = wl[e], vr = wr[e];
        _Float16 hl = (_Float16)vl, hr = (_Float16)vr;
        wl1h[e] = hl; wl1l[e] = (_Float16)((vl - (float)hl)*512.f);
        wr1h[e] = hr; wr1l[e] = (_Float16)((vr - (float)hr)*512.f);
    }
}

// ---------------------------------------------------------------------------
// conv_a = prep + conv1: fp32 NCHW in, split-fp16 MFMA 3x3, LeakyReLU(0.1),
// hi/lo channels-last out. 2 rows x 32 cols per block. grid (10, 64, 8).
__global__ __launch_bounds__(256) void k_conv_a(
    const float* __restrict__ in,
    const _Float16* __restrict__ wBh, const _Float16* __restrict__ wBl,
    _Float16* __restrict__ out_h, _Float16* __restrict__ out_l)
{
    __shared__ __align__(16) char smem[2*4*34*128];    // 34816 B
    char* in_sh = smem;
    char* in_sl = smem + 17408;
    const int tid = threadIdx.x;
    const int x0 = blockIdx.x * 32;
    const int y0 = blockIdx.y * 2;
    const int b  = blockIdx.z;
    const int lane = tid & 63;
    const int xq = lane & 15, kq = lane >> 4;
    const int n = tid >> 6;                            // wave = co-tile

    half8 bwh[18], bwl[18];
    {
        const _Float16* wbh = &wBh[((size_t)(n*16 + xq)*9)*64 + kq*8];
        const _Float16* wbl = &wBl[((size_t)(n*16 + xq)*9)*64 + kq*8];
#pragma unroll
        for (int t = 0; t < 9; ++t)
#pragma unroll
            for (int c = 0; c < 2; ++c) {
                bwh[t*2 + c] = *(const half8*)&wbh[t*64 + c*32];
                bwl[t*2 + c] = *(const half8*)&wbl[t*64 + c*32];
            }
    }

    // stage 4 rows x 34 xx x 8 ci-octets
    for (int e = tid; e < 1088; e += 256) {
        int t = e / 34;
        int xx = e - t*34;
        int ry = t >> 3, u = t & 7;
        int gy = y0 + ry - 1, gx = x0 + xx - 1;
        half8 hh, hl;
#pragma unroll
        for (int j = 0; j < 8; ++j) { hh[j] = (_Float16)0.f; hl[j] = (_Float16)0.f; }
        if ((unsigned)gy < (unsigned)HH && (unsigned)gx < (unsigned)WW) {
            const float* p = &in[((size_t)(b*CC + u*8)*HH + gy)*WW + gx];
#pragma unroll
            for (int j = 0; j < 8; ++j) {
                float v = p[(size_t)j*HH*WW];
                _Float16 h = (_Float16)v;
                hh[j] = h; hl[j] = (_Float16)((v - (float)h)*512.f);
            }
        }
        int off = ((ry*34 + xx)*8 + (u ^ (xx & 7)))*16;
        *(half8*)&in_sh[off] = hh;
        *(half8*)&in_sl[off] = hl;
    }
    __syncthreads();

    f32x4 accm[2][2], accc[2][2];                      // [rr][m]
#pragma unroll
    for (int rr = 0; rr < 2; ++rr)
#pragma unroll
        for (int m = 0; m < 2; ++m) { accm[rr][m] = (f32x4)0.f; accc[rr][m] = (f32x4)0.f; }

#pragma unroll
    for (int rr = 0; rr < 2; ++rr) {
#pragma unroll
        for (int m = 0; m < 2; ++m) {
            const int xb = m*16 + xq;
#pragma unroll
            for (int t = 0; t < 9; ++t) {
                const int ry = t / 3, kx = t - ry*3;
                const int trow = rr + ry;
                const int xxx = xb + kx;
#pragma unroll
                for (int c = 0; c < 2; ++c) {
                    const int u = c*4 + kq;
                    int off = ((trow*34 + xxx)*8 + (u ^ (xxx & 7)))*16;
                    half8 ah = *(const half8*)&in_sh[off];
                    half8 al = *(const half8*)&in_sl[off];
                    accm[rr][m] = __builtin_amdgcn_mfma_f32_16x16x32_f16(
                        ah, bwh[t*2 + c], accm[rr][m], 0, 0, 0);
                    accc[rr][m] = __builtin_amdgcn_mfma_f32_16x16x32_f16(
                        al, bwh[t*2 + c], accc[rr][m], 0, 0, 0);
                    accc[rr][m] = __builtin_amdgcn_mfma_f32_16x16x32_f16(
                        ah, bwl[t*2 + c], accc[rr][m], 0, 0, 0);
                }
            }
        }
    }
    __syncthreads();

    char* out_sh = smem;                // [rr*32+x][co], 8192 B each
    char* out_sl = smem + 8192;
#pragma unroll
    for (int rr = 0; rr < 2; ++rr) {
#pragma unroll
        for (int m = 0; m < 2; ++m) {
#pragma unroll
            for (int r = 0; r < 4; ++r) {
                int x = m*16 + kq*4 + r;          // 0..31
                int co = n*16 + xq;
                float v = accm[rr][m][r] + accc[rr][m][r]*INV512;
                v = (v > 0.f) ? v : 0.1f*v;       // LeakyReLU
                _Float16 vh = (_Float16)v;
                _Float16 vl = (_Float16)((v - (float)vh)*512.f);
                int boff = ((rr*32 + x)*8 + ((co >> 3) ^ (x & 7)))*16 + (co & 7)*2;
                *(_Float16*)&out_sh[boff] = vh;
                *(_Float16*)&out_sl[boff] = vl;
            }
        }
    }
    __syncthreads();

#pragma unroll
    for (int i = 0; i < 2; ++i) {
        int unit = tid + 256*i;               // 0..511
        int rr = unit >> 8, x = (unit >> 3) & 31, u = unit & 7;
        int loff = ((rr*32 + x)*8 + (u ^ (x & 7)))*16;
        size_t g = (((size_t)(b*HH + y0 + rr)*WW) + x0 + x)*64 + u*8;
        *(half8*)&out_h[g] = *(half8*)&out_sh[loff];
        *(half8*)&out_l[g] = *(half8*)&out_sl[loff];
    }
}

// ---------------------------------------------------------------------------
// conv_b = conv2 + residual + 1x1 projection (K=128 GEMM). 2 rows x 32 cols.
__global__ __launch_bounds__(256) void k_conv_b(
    const _Float16* __restrict__ in_h, const _Float16* __restrict__ in_l,
    const _Float16* __restrict__ wBh, const _Float16* __restrict__ wBl,
    const float* __restrict__ res,                    // fp32 NCHW x
    const _Float16* __restrict__ w1h, const _Float16* __restrict__ w1l,
    const float* __restrict__ bias,
    _Float16* __restrict__ Fh, _Float16* __restrict__ Fl)
{
    __shared__ __align__(16) char smem[49152];
    // phase 1: in_sh [0:17408], in_sl [17408:34816]
    // phase 2: out [0:16384], res [16384:32768], w [32768:49152]
    char* in_sh = smem;
    char* in_sl = smem + 17408;
    const int tid = threadIdx.x;
    const int x0 = blockIdx.x * 32;
    const int y0 = blockIdx.y * 2;
    const int b  = blockIdx.z;
    const int lane = tid & 63;
    const int xq = lane & 15, kq = lane >> 4;
    const int n = tid >> 6;

    half8 bwh[18], bwl[18];
    {
        const _Float16* wbh = &wBh[((size_t)(n*16 + xq)*9)*64 + kq*8];
        const _Float16* wbl = &wBl[((size_t)(n*16 + xq)*9)*64 + kq*8];
#pragma unroll
        for (int t = 0; t < 9; ++t)
#pragma unroll
            for (int c = 0; c < 2; ++c) {
                bwh[t*2 + c] = *(const half8*)&wbh[t*64 + c*32];
                bwl[t*2 + c] = *(const half8*)&wbl[t*64 + c*32];
            }
    }

    for (int e = tid; e < 1088; e += 256) {
        int t = e / 34;
        int xx = e - t*34;
        int ry = t >> 3, u = t & 7;
        int gy = y0 + ry - 1, gx = x0 + xx - 1;
        uint4 vh = make_uint4(0u,0u,0u,0u), vl = make_uint4(0u,0u,0u,0u);
        if ((unsigned)gy < (unsigned)HH && (unsigned)gx < (unsigned)WW) {
            size_t g = (((size_t)(b*HH + gy)*WW) + gx)*64 + u*8;
            vh = *(const uint4*)&in_h[g];
            vl = *(const uint4*)&in_l[g];
        }
        int off = ((ry*34 + xx)*8 + (u ^ (xx & 7)))*16;
        *(uint4*)&in_sh[off] = vh;
        *(uint4*)&in_sl[off] = vl;
    }
    __syncthreads();

    f32x4 accm[2][2], accc[2][2];
#pragma unroll
    for (int rr = 0; rr < 2; ++rr)
#pragma unroll
        for (int m = 0; m < 2; ++m) { accm[rr][m] = (f32x4)0.f; accc[rr][m] = (f32x4)0.f; }

#pragma unroll
    for (int rr = 0; rr < 2; ++rr) {
#pragma unroll
        for (int m = 0; m < 2; ++m) {
            const int xb = m*16 + xq;
#pragma unroll
            for (int t = 0; t < 9; ++t) {
                const int ry = t / 3, kx = t - ry*3;
                const int trow = rr + ry;
                const int xxx = xb + kx;
#pragma unroll
                for (int c = 0; c < 2; ++c) {
                    const int u = c*4 + kq;
                    int off = ((trow*34 + xxx)*8 + (u ^ (xxx & 7)))*16;
                    half8 ah = *(const half8*)&in_sh[off];
                    half8 al = *(const half8*)&in_sl[off];
                    accm[rr][m] = __builtin_amdgcn_mfma_f32_16x16x32_f16(
                        ah, bwh[t*2 + c], accm[rr][m], 0, 0, 0);
                    accc[rr][m] = __builtin_amdgcn_mfma_f32_16x16x32_f16(
                        al, bwh[t*2 + c], accc[rr][m], 0, 0, 0);
                    accc[rr][m] = __builtin_amdgcn_mfma_f32_16x16x32_f16(
                        ah, bwl[t*2 + c], accc[rr][m], 0, 0, 0);
                }
            }
        }
    }
    __syncthreads();            // in_s dead

    char* out_sh = smem;
    char* out_sl = smem + 8192;
    char* res_sh = smem + 16384;
    char* res_sl = smem + 24576;
    char* w_sh   = smem + 32768;
    char* w_sl   = smem + 40960;

    // stage residual: 2 rows x 32 x x 8 cu
#pragma unroll
    for (int i = 0; i < 2; ++i) {
        int e = tid + 256*i;                  // 0..511
        int rr = e >> 8, x = (e >> 3) & 31, cu = e & 7;
        const float* p = &res[((size_t)(b*CC + cu*8)*HH + y0 + rr)*WW + x0 + x];
        half8 hh, hl;
#pragma unroll
        for (int j = 0; j < 8; ++j) {
            float v = p[(size_t)j*HH*WW];
            _Float16 h = (_Float16)v;
            hh[j] = h; hl[j] = (_Float16)((v - (float)h)*512.f);
        }
        int off = ((rr*32 + x)*8 + (cu ^ (x & 7)))*16;
        *(half8*)&res_sh[off] = hh;
        *(half8*)&res_sl[off] = hl;
    }
    // stage 1x1 weights
#pragma unroll
    for (int i = 0; i < 2; ++i) {
        int e = tid + 256*i;
        int co = e >> 3, u = e & 7;
        int off = (co*8 + (u ^ (co & 7)))*16;
        *(half8*)&w_sh[off] = *(const half8*)&w1h[co*64 + u*8];
        *(half8*)&w_sl[off] = *(const half8*)&w1l[co*64 + u*8];
    }
    // conv2 raw out -> out tiles
#pragma unroll
    for (int rr = 0; rr < 2; ++rr) {
#pragma unroll
        for (int m = 0; m < 2; ++m) {
#pragma unroll
            for (int r = 0; r < 4; ++r) {
                int x = m*16 + kq*4 + r;
                int co = n*16 + xq;
                float v = accm[rr][m][r] + accc[rr][m][r]*INV512;
                _Float16 vh = (_Float16)v;
                _Float16 vl = (_Float16)((v - (float)vh)*512.f);
                int boff = ((rr*32 + x)*8 + ((co >> 3) ^ (x & 7)))*16 + (co & 7)*2;
                *(_Float16*)&out_sh[boff] = vh;
                *(_Float16*)&out_sl[boff] = vl;
            }
        }
    }
    __syncthreads();

    // 1x1 as K=128 split-fp16 GEMM over 64 positions (2 rows x 32 x)
    float bv[4];
#pragma unroll
    for (int nn = 0; nn < 4; ++nn) bv[nn] = bias[nn*16 + (lane & 15)];

    f32x4 am[4], ac[4];
#pragma unroll
    for (int nn = 0; nn < 4; ++nn) { am[nn] = (f32x4)0.f; ac[nn] = (f32x4)0.f; }

    const int arow = n*16 + (lane & 15);
#pragma unroll
    for (int c = 0; c < 4; ++c) {
        half8 ah, al;
        int u = (c & 1)*4 + (lane >> 4);
        int off = (arow*8 + (u ^ (arow & 7)))*16;
        if (c < 2) {
            ah = *(const half8*)&out_sh[off];
            al = *(const half8*)&out_sl[off];
        } else {
            ah = *(const half8*)&res_sh[off];
            al = *(const half8*)&res_sl[off];
        }
#pragma unroll
        for (int nn = 0; nn < 4; ++nn) {
            int brow = nn*16 + (lane & 15);
            int woff = (brow*8 + (u ^ (brow & 7)))*16;
            half8 bh  = *(const half8*)&w_sh[woff];
            half8 blw = *(const half8*)&w_sl[woff];
            am[nn] = __builtin_amdgcn_mfma_f32_16x16x32_f16(ah, bh,  am[nn], 0,0,0);
            ac[nn] = __builtin_amdgcn_mfma_f32_16x16x32_f16(al, bh,  ac[nn], 0,0,0);
            ac[nn] = __builtin_amdgcn_mfma_f32_16x16x32_f16(ah, blw, ac[nn], 0,0,0);
        }
    }
    __syncthreads();            // res tiles dead; F aliases them

    char* F_sh = smem + 16384;
    char* F_sl = smem + 24576;
#pragma unroll
    for (int nn = 0; nn < 4; ++nn) {
#pragma unroll
        for (int r = 0; r < 4; ++r) {
            int pos = n*16 + (lane >> 4)*4 + r;      // 0..63
            int co = nn*16 + (lane & 15);
            float v = am[nn][r] + ac[nn][r]*INV512 + bv[nn];
            _Float16 vh = (_Float16)v;
            _Float16 vl = (_Float16)((v - (float)vh)*512.f);
            int boff = (pos*8 + ((co >> 3) ^ (pos & 7)))*16 + (co & 7)*2;
            *(_Float16*)&F_sh[boff] = vh;
            *(_Float16*)&F_sl[boff] = vl;
        }
    }
    __syncthreads();

#pragma unroll
    for (int i = 0; i < 2; ++i) {
        int unit = tid + 256*i;
        int rr = unit >> 8, x = (unit >> 3) & 31, u = unit & 7;
        int loff = ((rr*32 + x)*8 + (u ^ (x & 7)))*16;
        size_t g = (((size_t)(b*HH + y0 + rr)*WW) + x0 + x)*64 + u*8;
        *(half8*)&Fh[g] = *(half8*)&F_sh[loff];
        *(half8*)&Fl[g] = *(half8*)&F_sl[loff];
    }
}

// ---------------------------------------------------------------------------
// Row-strip S-GEMM: block (wt,row) computes 64w x 320v. A-frags in registers,
// B double-buffered in LDS. Writes S, FINAL row stats, col partials per vt.
__global__ __launch_bounds__(256) void k_sgemm(
    const _Float16* __restrict__ F0h, const _Float16* __restrict__ F0l,
    const _Float16* __restrict__ F1h, const _Float16* __restrict__ F1l,
    float* __restrict__ S,
    float* __restrict__ colmax_p, float* __restrict__ colsum_p,
    float* __restrict__ rowmax_f, float* __restrict__ rowinv_f)
{
    __shared__ __align__(16) char smem[32768];   // R0: A then odd-vt B; R1: even-vt B
    __shared__ float cpm[2][4][64], cpl[2][4][64];
    const int wt = blockIdx.x, row = blockIdx.y;
    const int tid = threadIdx.x, lane = tid & 63, wid = tid >> 6;
    char* R0 = smem;
    char* R1 = smem + 16384;

    // prologue: A strip -> R0, B(vt=0) -> R1
    for (int e = tid; e < 512; e += 256) {
        int i = e >> 3, u = e & 7;
        int off = (i*8 + (u ^ (i & 7)))*16;
        size_t ga = ((size_t)row*WW + wt*64 + i)*64 + u*8;
        *(uint4*)&R0[off]        = *(const uint4*)&F0h[ga];
        *(uint4*)&R0[8192 + off] = *(const uint4*)&F0l[ga];
        size_t gb = ((size_t)row*WW + i)*64 + u*8;
        *(uint4*)&R1[off]        = *(const uint4*)&F1h[gb];
        *(uint4*)&R1[8192 + off] = *(const uint4*)&F1l[gb];
    }
    __syncthreads();

    half8 ah[2], al[2];
    {
        const int arow = wid*16 + (lane & 15);
#pragma unroll
        for (int c = 0; c < 2; ++c) {
            int u = c*4 + (lane >> 4);
            int aoff = (arow*8 + (u ^ (arow & 7)))*16;
            ah[c] = *(const half8*)&R0[aoff];
            al[c] = *(const half8*)&R0[8192 + aoff];
        }
    }

    float rm[4], rl[4];
#pragma unroll
    for (int r = 0; r < 4; ++r) { rm[r] = -1e30f; rl[r] = 0.f; }

    for (int vt = 0; vt < 5; ++vt) {
        char* cur = (vt & 1) ? R0 : R1;
        __syncthreads();
        if (vt < 4) {               // stage next B into the other buffer
            char* nxt = (vt & 1) ? R1 : R0;
            for (int e = tid; e < 512; e += 256) {
                int i = e >> 3, u = e & 7;
                int off = (i*8 + (u ^ (i & 7)))*16;
                size_t gb = ((size_t)row*WW + (vt+1)*64 + i)*64 + u*8;
                *(uint4*)&nxt[off]        = *(const uint4*)&F1h[gb];
                *(uint4*)&nxt[8192 + off] = *(const uint4*)&F1l[gb];
            }
        }
        if (vt > 0 && tid < 64) {   // merge col partials for vt-1
            int pb = (vt-1) & 1;
            float m0 = cpm[pb][0][tid], m1 = cpm[pb][1][tid];
            float m2 = cpm[pb][2][tid], m3 = cpm[pb][3][tid];
            float m = fmaxf(fmaxf(m0, m1), fmaxf(m2, m3));
            float l = cpl[pb][0][tid]*__expf(m0-m) + cpl[pb][1][tid]*__expf(m1-m)
                    + cpl[pb][2][tid]*__expf(m2-m) + cpl[pb][3][tid]*__expf(m3-m);
            size_t cbase = ((size_t)row*5 + wt)*WW + (size_t)(vt-1)*64 + tid;
            colmax_p[cbase] = m;
            colsum_p[cbase] = l;
        }

        f32x4 accm[4], accc[4];
#pragma unroll
        for (int n = 0; n < 4; ++n) { accm[n] = (f32x4)0.f; accc[n] = (f32x4)0.f; }
#pragma unroll
        for (int c = 0; c < 2; ++c) {
            const int u = c*4 + (lane >> 4);
#pragma unroll
            for (int n = 0; n < 4; ++n) {
                const int brow = n*16 + (lane & 15);
                int boff = (brow*8 + (u ^ (brow & 7)))*16;
                half8 bh = *(const half8*)&cur[boff];
                half8 bl = *(const half8*)&cur[8192 + boff];
                accm[n] = __builtin_amdgcn_mfma_f32_16x16x32_f16(ah[c], bh, accm[n], 0,0,0);
                accc[n] = __builtin_amdgcn_mfma_f32_16x16x32_f16(al[c], bh, accc[n], 0,0,0);
                accc[n] = __builtin_amdgcn_mfma_f32_16x16x32_f16(ah[c], bl, accc[n], 0,0,0);
            }
        }

        float sv[4][4];
#pragma unroll
        for (int n = 0; n < 4; ++n)
#pragma unroll
            for (int r = 0; r < 4; ++r)
                sv[n][r] = accm[n][r] + accc[n][r]*INV512;

#pragma unroll
        for (int n = 0; n < 4; ++n) {
            float* sp = &S[((size_t)row*WW + wt*64 + wid*16 + (lane>>4)*4)*WW
                           + vt*64 + n*16 + (lane & 15)];
#pragma unroll
            for (int r = 0; r < 4; ++r) sp[(size_t)r*WW] = sv[n][r];
        }

        // online row stats (this lane's 4 v-values per row)
#pragma unroll
        for (int r = 0; r < 4; ++r) {
            float tmax = fmaxf(fmaxf(sv[0][r], sv[1][r]), fmaxf(sv[2][r], sv[3][r]));
            float newm = fmaxf(rm[r], tmax);
            rl[r] = rl[r]*__expf(rm[r] - newm)
                  + __expf(sv[0][r]-newm) + __expf(sv[1][r]-newm)
                  + __expf(sv[2][r]-newm) + __expf(sv[3][r]-newm);
            rm[r] = newm;
        }

        // per-wave col stats -> cpm[vt&1]
#pragma unroll
        for (int n = 0; n < 4; ++n) {
            float m = fmaxf(fmaxf(sv[n][0], sv[n][1]), fmaxf(sv[n][2], sv[n][3]));
            m = fmaxf(m, __shfl_xor(m, 16));
            m = fmaxf(m, __shfl_xor(m, 32));
            float l = __expf(sv[n][0]-m) + __expf(sv[n][1]-m)
                    + __expf(sv[n][2]-m) + __expf(sv[n][3]-m);
            l += __shfl_xor(l, 16); l += __shfl_xor(l, 32);
            if (lane < 16) { cpm[vt&1][wid][n*16 + lane] = m;
                             cpl[vt&1][wid][n*16 + lane] = l; }
        }
    }
    __syncthreads();
    if (tid < 64) {                 // merge col partials for vt=4 (buffer 0)
        float m0 = cpm[0][0][tid], m1 = cpm[0][1][tid];
        float m2 = cpm[0][2][tid], m3 = cpm[0][3][tid];
        float m = fmaxf(fmaxf(m0, m1), fmaxf(m2, m3));
        float l = cpl[0][0][tid]*__expf(m0-m) + cpl[0][1][tid]*__expf(m1-m)
                + cpl[0][2][tid]*__expf(m2-m) + cpl[0][3][tid]*__expf(m3-m);
        size_t cbase = ((size_t)row*5 + wt)*WW + 4*64 + tid;
        colmax_p[cbase] = m;
        colsum_p[cbase] = l;
    }

    // final row stats: merge across the 16-lane (lane&15) group
#pragma unroll
    for (int r = 0; r < 4; ++r) {
#pragma unroll
        for (int o = 1; o < 16; o <<= 1) {
            float m2 = __shfl_xor(rm[r], o);
            float l2 = __shfl_xor(rl[r], o);
            float mm = fmaxf(rm[r], m2);
            rl[r] = rl[r]*__expf(rm[r] - mm) + l2*__expf(m2 - mm);
            rm[r] = mm;
        }
    }
    if ((lane & 15) == 0) {
        size_t rbase = (size_t)row*WW + wt*64 + wid*16 + (lane>>4)*4;
#pragma unroll
        for (int r = 0; r < 4; ++r) {
            rowmax_f[rbase + r] = rm[r];
            rowinv_f[rbase + r] = 1.f / rl[r];
        }
    }
}

// ---------------------------------------------------------------------------
// Merge 5 col partials per row into final max + 1/sum. grid 1024 x 320 thr.
__global__ __launch_bounds__(320) void k_smerge(
    const float* __restrict__ colmax_p, const float* __restrict__ colsum_p,
    float* __restrict__ colmax_f, float* __restrict__ colinv_f)
{
    const int row = blockIdx.x, tid = threadIdx.x;
    float m = -1e30f, l = 0.f;
#pragma unroll
    for (int t = 0; t < 5; ++t) {
        float pm = colmax_p[((size_t)row*5 + t)*WW + tid];
        float pl = colsum_p[((size_t)row*5 + t)*WW + tid];
        float m2 = fmaxf(m, pm);
        l = l*__expf(m - m2) + pl*__expf(pm - m2);
        m = m2;
    }
    colmax_f[(size_t)row*WW + tid] = m;
    colinv_f[(size_t)row*WW + tid] = 1.f/l;
}

// ---------------------------------------------------------------------------
// FUSED softmax-apply + out-GEMM. grid (5 wt, 1024 row), 256 thr.
__global__ __launch_bounds__(256) void k_fused(
    float* __restrict__ S, float* __restrict__ Ml2r, float* __restrict__ Vout,
    const float* __restrict__ xr, float* __restrict__ outf,
    const float* __restrict__ colmax_f, const float* __restrict__ colinv_f,
    const float* __restrict__ rowmax_f, const float* __restrict__ rowinv_f)
{
    __shared__ __align__(16) char A[8192], Bm[8192];   // fp16 tiles, swizzled
    __shared__ float T[64*65];                          // Ml2r transpose tile
    __shared__ float cmx[320], cin[320], rmx[64], rin[64];
    const int wt = blockIdx.x, row = blockIdx.y;
    const int b = row >> 7, h = row & 127;
    const int tid = threadIdx.x, lane = tid & 63, wid = tid >> 6;
    const int wrow = tid >> 2, quad = tid & 3;

    for (int e = tid; e < 320; e += 256) {
        cmx[e] = colmax_f[(size_t)row*WW + e];
        cin[e] = colinv_f[(size_t)row*WW + e];
    }
    if (tid < 64) {
        rmx[tid] = rowmax_f[(size_t)row*WW + wt*64 + tid];
        rin[tid] = rowinv_f[(size_t)row*WW + wt*64 + tid];
    }
    __syncthreads();

    f32x4 acc[4];
#pragma unroll
    for (int n = 0; n < 4; ++n) acc[n] = (f32x4)0.f;
    float vsum = 0.f;
    float* Sbase = &S[((size_t)row*WW + wt*64 + wrow)*WW];
    const float rm = rmx[wrow], ri = rin[wrow];

    for (int vt = 0; vt < 5; ++vt) {
        if (vt) __syncthreads();
#pragma unroll
        for (int i = 0; i < 4; ++i) {
            const int f = quad + 4*i;
            const int v0 = f*4;
            float4 s = *(float4*)&Sbase[vt*64 + v0];
            float4 pr;
            pr.x = __expf(s.x - rm)*ri;
            pr.y = __expf(s.y - rm)*ri;
            pr.z = __expf(s.z - rm)*ri;
            pr.w = __expf(s.w - rm)*ri;
            *(float4*)&Sbase[vt*64 + v0] = pr;      // Mr2l in place
            const int vg = vt*64 + v0;
            float p0 = __expf(s.x - cmx[vg+0])*cin[vg+0];
            float p1 = __expf(s.y - cmx[vg+1])*cin[vg+1];
            float p2 = __expf(s.z - cmx[vg+2])*cin[vg+2];
            float p3 = __expf(s.w - cmx[vg+3])*cin[vg+3];
            T[(v0+0)*65 + wrow] = p0;
            T[(v0+1)*65 + wrow] = p1;
            T[(v0+2)*65 + wrow] = p2;
            T[(v0+3)*65 + wrow] = p3;
            vsum += p0 + p1 + p2 + p3;
            half4 hp;
            hp[0] = (_Float16)pr.x; hp[1] = (_Float16)pr.y;
            hp[2] = (_Float16)pr.z; hp[3] = (_Float16)pr.w;
            *(half4*)&A[(wrow*8 + ((f>>1) ^ (wrow & 7)))*16 + (f & 1)*8] = hp;
        }
        for (int e = tid; e < 512; e += 256) {
            int i = e >> 3, u = e & 7;
            const float4* xp = (const float4*)
                &xr[(((size_t)b*CC + i)*HH + h)*WW + vt*64 + u*8];
            float4 b0 = xp[0], b1 = xp[1];
            half8 hb;
            hb[0]=(_Float16)b0.x; hb[1]=(_Float16)b0.y; hb[2]=(_Float16)b0.z;
            hb[3]=(_Float16)b0.w; hb[4]=(_Float16)b1.x; hb[5]=(_Float16)b1.y;
            hb[6]=(_Float16)b1.z; hb[7]=(_Float16)b1.w;
            *(half8*)&Bm[(i*8 + (u ^ (i & 7)))*16] = hb;
        }
        __syncthreads();
#pragma unroll
        for (int c = 0; c < 2; ++c) {
            const int u = c*4 + (lane >> 4);
            const int arow = wid*16 + (lane & 15);
            half8 ah = *(const half8*)&A[(arow*8 + (u ^ (arow & 7)))*16];
#pragma unroll
            for (int n = 0; n < 4; ++n) {
                const int brow = n*16 + (lane & 15);
                half8 bh = *(const half8*)&Bm[(brow*8 + (u ^ (brow & 7)))*16];
                acc[n] = __builtin_amdgcn_mfma_f32_16x16x32_f16(ah, bh, acc[n], 0,0,0);
            }
        }
        // Ml2r transposed write, float4
        for (int e = tid; e < 1024; e += 256) {
            int vr = e >> 4, wc4 = (e & 15)*4;
            const float* tp = &T[vr*65 + wc4];
            *(float4*)&Ml2r[((size_t)row*WW + vt*64 + vr)*WW + wt*64 + wc4] =
                make_float4(tp[0], tp[1], tp[2], tp[3]);
        }
    }

    vsum += __shfl_xor(vsum, 1);
    vsum += __shfl_xor(vsum, 2);
    if (quad == 0)
        Vout[(size_t)row*WW + wt*64 + wrow] = (vsum > 0.1f) ? 1.f : 0.f;

#pragma unroll
    for (int n = 0; n < 4; ++n) {
        *(float4*)&outf[(((size_t)b*CC + n*16 + (lane & 15))*HH + h)*WW
                        + wt*64 + wid*16 + (lane>>4)*4] =
            make_float4(acc[n][0], acc[n][1], acc[n][2], acc[n][3]);
    }
}

// ---------------------------------------------------------------------------
// FALLBACK path (ws too small): separate softmax-apply and out-GEMM.
__global__ __launch_bounds__(320) void k_softmax(
    float* __restrict__ S, float* __restrict__ Ml2r, float* __restrict__ Vout,
    const float* __restrict__ colmax_f, const float* __restrict__ colinv_f,
    const float* __restrict__ rowmax_f, const float* __restrict__ rowinv_f)
{
    __shared__ float rowmax[320], rowinv[320], colmax[320], colinv[320];
    __shared__ float T[64*65];
    __shared__ float Vp2[5*64];
    const int row = blockIdx.x;
    const int tid = threadIdx.x;
    float* Srow = &S[(size_t)row * WW * WW];

    rowmax[tid] = rowmax_f[(size_t)row*WW + tid];
    rowinv[tid] = rowinv_f[(size_t)row*WW + tid];
    colmax[tid] = colmax_f[(size_t)row*WW + tid];
    colinv[tid] = colinv_f[(size_t)row*WW + tid];
    __syncthreads();

    const int myw = tid & 63;
    const int myg = tid / 64;
    for (int wt = 0; wt < 5; ++wt) {
        float vpart = 0.f;
        for (int vt = 0; vt < 5; ++vt) {
            for (int e = tid; e < 4096; e += 320) {
                int i = e >> 6, j = e & 63;
                int wgl = wt*64 + i, vgl = vt*64 + j;
                size_t si = (size_t)wgl*WW + vgl;
                float s = Srow[si];
                Srow[si] = __expf(s - rowmax[wgl]) * rowinv[wgl];
                T[j*65 + i] = __expf(s - colmax[vgl]) * colinv[vgl];
            }
            __syncthreads();
            for (int e = tid; e < 4096; e += 320) {
                int vr = e >> 6, wc = e & 63;
                Ml2r[((size_t)row*WW + vt*64 + vr)*WW + wt*64 + wc] = T[vr*65 + wc];
            }
            for (int j = myg; j < 64; j += 5) vpart += T[j*65 + myw];
            __syncthreads();
        }
        Vp2[myg*64 + myw] = vpart;
        __syncthreads();
        if (tid < 64) {
            float sv = 0.f;
#pragma unroll
            for (int g = 0; g < 5; ++g) sv += Vp2[g*64 + tid];
            Vout[(size_t)row*WW + wt*64 + tid] = (sv > 0.1f) ? 1.f : 0.f;
        }
        __syncthreads();
    }
}

__global__ __launch_bounds__(256) void k_outgemm(
    const float* __restrict__ M, const float* __restrict__ xr,
    float* __restrict__ outf)
{
    __shared__ __align__(16) char Am[8192], Bm[8192];
    const int wt = blockIdx.x;
    const int row = blockIdx.y;
    const int b = row >> 7, h = row & 127;
    const int tid = threadIdx.x, lane = tid & 63, wid = tid >> 6;

    f32x4 acc[4];
#pragma unroll
    for (int n = 0; n < 4; ++n) acc[n] = (f32x4)0.f;

    for (int vt = 0; vt < 5; ++vt) {
        if (vt) __syncthreads();
        for (int e = tid; e < 512; e += 256) {
            int i = e >> 3, u = e & 7;
            const float4* mp = (const float4*)
                &M[((size_t)row*WW + wt*64 + i)*WW + vt*64 + u*8];
            float4 a0 = mp[0], a1 = mp[1];
            const float4* xp = (const float4*)
                &xr[(((size_t)b*CC + i)*HH + h)*WW + vt*64 + u*8];
            float4 b0 = xp[0], b1 = xp[1];
            half8 ha, hb;
            ha[0]=(_Float16)a0.x; ha[1]=(_Float16)a0.y; ha[2]=(_Float16)a0.z;
            ha[3]=(_Float16)a0.w; ha[4]=(_Float16)a1.x; ha[5]=(_Float16)a1.y;
            ha[6]=(_Float16)a1.z; ha[7]=(_Float16)a1.w;
            hb[0]=(_Float16)b0.x; hb[1]=(_Float16)b0.y; hb[2]=(_Float16)b0.z;
            hb[3]=(_Float16)b0.w; hb[4]=(_Float16)b1.x; hb[5]=(_Float16)b1.y;
            hb[6]=(_Float16)b1.z; hb[7]=(_Float16)b1.w;
            int off = (i*8 + (u ^ (i & 7)))*16;
            *(half8*)&Am[off] = ha;
            *(half8*)&Bm[off] = hb;
        }
        __syncthreads();
#pragma unroll
        for (int c = 0; c < 2; ++c) {
            const int u = c*4 + (lane >> 4);
            const int arow = wid*16 + (lane & 15);
            half8 ah = *(const half8*)&Am[(arow*8 + (u ^ (arow & 7)))*16];
#pragma unroll
            for (int n = 0; n < 4; ++n) {
                const int brow = n*16 + (lane & 15);
                half8 bh = *(const half8*)&Bm[(brow*8 + (u ^ (brow & 7)))*16];
                acc[n] = __builtin_amdgcn_mfma_f32_16x16x32_f16(ah, bh, acc[n], 0,0,0);
            }
        }
    }

#pragma unroll
    for (int n = 0; n < 4; ++n) {
        *(float4*)&outf[(((size_t)b*CC + n*16 + (lane & 15))*HH + h)*WW
                        + wt*64 + wid*16 + (lane>>4)*4] =
            make_float4(acc[n][0], acc[n][1], acc[n][2], acc[n][3]);
    }
}

// ---------------------------------------------------------------------------
extern "C" void kernel_launch(void* const* d_in, const int* in_sizes, int n_in,
                              void* d_out, int out_size, void* d_ws, size_t ws_size,
                              hipStream_t stream)
{
    const float* x_l = (const float*)d_in[0];
    const float* x_r = (const float*)d_in[1];
    const float* w1  = (const float*)d_in[2];
    const float* w2  = (const float*)d_in[3];
    const float* wl  = (const float*)d_in[4];
    const float* bl  = (const float*)d_in[5];
    const float* wr  = (const float*)d_in[6];
    const float* br  = (const float*)d_in[7];
    float* out = (float*)d_out;

    float* outf = out;
    float* Vp   = out + OFF_V;
    float* Ml2r = out + OFF_ML2R;
    float* Mr2l = out + OFF_MR2L;

    // r (conv1 output) hi/lo in Mr2l region; reused for left then right side
    _Float16* r_h = (_Float16*)Mr2l;
    _Float16* r_l = r_h + (size_t)NCL;
    // F hi/lo in Ml2r region; conv/1x1 weights at its tail
    _Float16* F0h = (_Float16*)Ml2r;
    _Float16* F0l = F0h + (size_t)NCL;
    _Float16* F1h = F0l + (size_t)NCL;
    _Float16* F1l = F1h + (size_t)NCL;
    float* S  = Mr2l;
    _Float16* WTH = (_Float16*)(Ml2r + (size_t)N_M - WT_FLOATS);
    _Float16* wB1h = WTH;
    _Float16* wB1l = WTH + 36864;
    _Float16* wB2h = WTH + 73728;
    _Float16* wB2l = WTH + 110592;
    _Float16* wl1h = WTH + 147456;
    _Float16* wl1l = WTH + 151552;
    _Float16* wr1h = WTH + 155648;
    _Float16* wr1l = WTH + 159744;
    // col partials in the outf region (consumed before outf is written)
    float* colmax_p = out + 0;          // [1024][5][320]
    float* colsum_p = out + 1700000;

    const size_t FIN_FLOATS = (size_t)1024*320;
    bool fused = ws_size >= 4*FIN_FLOATS*sizeof(float);  // 5.24 MB
    float* colmax_f, *colinv_f, *rowmax_f, *rowinv_f;
    if (fused) {
        float* ws = (float*)d_ws;
        colmax_f = ws + 0*FIN_FLOATS;
        colinv_f = ws + 1*FIN_FLOATS;
        rowmax_f = ws + 2*FIN_FLOATS;
        rowinv_f = ws + 3*FIN_FLOATS;
    } else {
        colmax_f = out + 6800000;
        colinv_f = out + 7200000;
        rowmax_f = out + 7600000;
        rowinv_f = out + 8000000;
    }

    k_wt<<<64, 256, 0, stream>>>(w1, w2, wl, wr,
                                 wB1h, wB1l, wB2h, wB2l,
                                 wl1h, wl1l, wr1h, wr1l);

    dim3 pgrid(WW/32, HH/2, BB);
    k_conv_a<<<pgrid, 256, 0, stream>>>(x_l, wB1h, wB1l, r_h, r_l);
    k_conv_b<<<pgrid, 256, 0, stream>>>(r_h, r_l, wB2h, wB2l, x_l,
                                        wl1h, wl1l, bl, F0h, F0l);
    k_conv_a<<<pgrid, 256, 0, stream>>>(x_r, wB1h, wB1l, r_h, r_l);
    k_conv_b<<<pgrid, 256, 0, stream>>>(r_h, r_l, wB2h, wB2l, x_r,
                                        wr1h, wr1l, br, F1h, F1l);

    dim3 sgrid(5, BB*HH);
    k_sgemm<<<sgrid, 256, 0, stream>>>(F0h, F0l, F1h, F1l, S,
                                       colmax_p, colsum_p,
                                       rowmax_f, rowinv_f);

    k_smerge<<<BB*HH, 320, 0, stream>>>(colmax_p, colsum_p,
                                        colmax_f, colinv_f);

    if (fused) {
        dim3 fgrid(5, BB*HH);
        k_fused<<<fgrid, 256, 0, stream>>>(S, Ml2r, Vp, x_r, outf,
                                           colmax_f, colinv_f,
                                           rowmax_f, rowinv_f);
    } else {
        k_softmax<<<BB*HH, 320, 0, stream>>>(S, Ml2r, Vp,
                                             colmax_f, colinv_f,
                                             rowmax_f, rowinv_f);
        dim3 ogrid(5, BB*HH);
        k_outgemm<<<ogrid, 256, 0, stream>>>(Mr2l, x_r, outf);
    }
}

// Round 10
// 1116.724 us; speedup vs baseline: 4.4753x; 1.0438x over previous
//
#include <hip/hip_runtime.h>

#define BB 8
#define CC 64
#define HH 128
#define WW 320

// float offsets inside d_out
#define N_OUTF (BB*CC*HH*WW)           // 20,971,520
#define N_V    (BB*HH*WW)              // 327,680
#define N_M    (BB*HH*WW*WW)           // 104,857,600
#define OFF_V    (N_OUTF)
#define OFF_ML2R (N_OUTF + N_V)        // 21,299,200
#define OFF_MR2L (OFF_ML2R + N_M)      // 126,156,800
#define OUT_TOTAL (OFF_MR2L + N_M)     // 231,014,400
// weight tail at end of Ml2r region: 4x conv (36864 h) + 4x 1x1 (4096 h)
#define WT_FLOATS ((4*36864 + 4*4096)/2)           // 81,920 floats
#define NCL 20971520                   // halfs per channels-last buffer
#define INV512 (1.f/512.f)

typedef _Float16 half8 __attribute__((ext_vector_type(8)));
typedef _Float16 half4 __attribute__((ext_vector_type(4)));
typedef float f32x4 __attribute__((ext_vector_type(4)));

// ---------------------------------------------------------------------------
// Weights prep: rb_w -> fp16 hi/lo [co][tap][ci]; 1x1 -> fp16 hi/lo [co][ci].
__global__ __launch_bounds__(256) void k_wt(
    const float* __restrict__ w1, const float* __restrict__ w2,
    const float* __restrict__ wl, const float* __restrict__ wr,
    _Float16* __restrict__ wB1h, _Float16* __restrict__ wB1l,
    _Float16* __restrict__ wB2h, _Float16* __restrict__ wB2l,
    _Float16* __restrict__ wl1h, _Float16* __restrict__ wl1l,
    _Float16* __restrict__ wr1h, _Float16* __restrict__ wr1l)
{
    int tid = blockIdx.x * 256 + threadIdx.x;
    int stride = gridDim.x * 256;
    for (int e = tid; e < 64*9*64; e += stride) {   // e = co*576 + tap*64 + ci
        int co = e / 576;
        int rem = e - co*576;
        int tap = rem >> 6, ci = rem & 63;
        float v1 = w1[(co*64 + ci)*9 + tap];
        float v2 = w2[(co*64 + ci)*9 + tap];
        _Float16 h1 = (_Float16)v1, h2 = (_Float16)v2;
        wB1h[e] = h1; wB1l[e] = (_Float16)((v1 - (float)h1)*512.f);
        wB2h[e] = h2; wB2l[e] = (_Float16)((v2 - (float)h2)*512.f);
    }
    for (int e = tid; e < 4096; e += stride) {      // e = co*64 + ci
        float vl = wl[e], vr = wr[e];
        _Float16 hl = (_Float16)vl, hr = (_Float16)vr;
        wl1h[e] = hl; wl1l[e] = (_Float16)((vl - (float)hl)*512.f);
        wr1h[e] = hr; wr1l[e] = (_Float16)((vr - (float)hr)*512.f);
    }
}

// ---------------------------------------------------------------------------
// conv_a = prep + conv1 for BOTH sides: fp32 NCHW in, split-fp16 MFMA 3x3,
// LeakyReLU(0.1), hi/lo channels-last out. 2 rows x 32 cols per block.
// grid (10, 64, 16): z>>3 = side, z&7 = batch.
__global__ __launch_bounds__(256) void k_conv_a(
    const float* __restrict__ in_l_, const float* __restrict__ in_r_,
    const _Float16* __restrict__ wBh, const _Float16* __restrict__ wBl,
    _Float16* __restrict__ r_lh, _Float16* __restrict__ r_ll,
    _Float16* __restrict__ r_rh, _Float16* __restrict__ r_rl)
{
    __shared__ __align__(16) char smem[2*4*34*128];    // 34816 B
    char* in_sh = smem;
    char* in_sl = smem + 17408;
    const int tid = threadIdx.x;
    const int x0 = blockIdx.x * 32;
    const int y0 = blockIdx.y * 2;
    const int z  = blockIdx.z;
    const int side = z >> 3, b = z & 7;
    const float* in = side ? in_r_ : in_l_;
    _Float16* out_h = side ? r_rh : r_lh;
    _Float16* out_l = side ? r_rl : r_ll;
    const int lane = tid & 63;
    const int xq = lane & 15, kq = lane >> 4;
    const int n = tid >> 6;                            // wave = co-tile

    half8 bwh[18], bwl[18];
    {
        const _Float16* wbh = &wBh[((size_t)(n*16 + xq)*9)*64 + kq*8];
        const _Float16* wbl = &wBl[((size_t)(n*16 + xq)*9)*64 + kq*8];
#pragma unroll
        for (int t = 0; t < 9; ++t)
#pragma unroll
            for (int c = 0; c < 2; ++c) {
                bwh[t*2 + c] = *(const half8*)&wbh[t*64 + c*32];
                bwl[t*2 + c] = *(const half8*)&wbl[t*64 + c*32];
            }
    }

    // stage 4 rows x 34 xx x 8 ci-octets
    for (int e = tid; e < 1088; e += 256) {
        int t = e / 34;
        int xx = e - t*34;
        int ry = t >> 3, u = t & 7;
        int gy = y0 + ry - 1, gx = x0 + xx - 1;
        half8 hh, hl;
#pragma unroll
        for (int j = 0; j < 8; ++j) { hh[j] = (_Float16)0.f; hl[j] = (_Float16)0.f; }
        if ((unsigned)gy < (unsigned)HH && (unsigned)gx < (unsigned)WW) {
            const float* p = &in[((size_t)(b*CC + u*8)*HH + gy)*WW + gx];
#pragma unroll
            for (int j = 0; j < 8; ++j) {
                float v = p[(size_t)j*HH*WW];
                _Float16 h = (_Float16)v;
                hh[j] = h; hl[j] = (_Float16)((v - (float)h)*512.f);
            }
        }
        int off = ((ry*34 + xx)*8 + (u ^ (xx & 7)))*16;
        *(half8*)&in_sh[off] = hh;
        *(half8*)&in_sl[off] = hl;
    }
    __syncthreads();

    f32x4 accm[2][2], accc[2][2];                      // [rr][m]
#pragma unroll
    for (int rr = 0; rr < 2; ++rr)
#pragma unroll
        for (int m = 0; m < 2; ++m) { accm[rr][m] = (f32x4)0.f; accc[rr][m] = (f32x4)0.f; }

#pragma unroll
    for (int rr = 0; rr < 2; ++rr) {
#pragma unroll
        for (int m = 0; m < 2; ++m) {
            const int xb = m*16 + xq;
#pragma unroll
            for (int t = 0; t < 9; ++t) {
                const int ry = t / 3, kx = t - ry*3;
                const int trow = rr + ry;
                const int xxx = xb + kx;
#pragma unroll
                for (int c = 0; c < 2; ++c) {
                    const int u = c*4 + kq;
                    int off = ((trow*34 + xxx)*8 + (u ^ (xxx & 7)))*16;
                    half8 ah = *(const half8*)&in_sh[off];
                    half8 al = *(const half8*)&in_sl[off];
                    accm[rr][m] = __builtin_amdgcn_mfma_f32_16x16x32_f16(
                        ah, bwh[t*2 + c], accm[rr][m], 0, 0, 0);
                    accc[rr][m] = __builtin_amdgcn_mfma_f32_16x16x32_f16(
                        al, bwh[t*2 + c], accc[rr][m], 0, 0, 0);
                    accc[rr][m] = __builtin_amdgcn_mfma_f32_16x16x32_f16(
                        ah, bwl[t*2 + c], accc[rr][m], 0, 0, 0);
                }
            }
        }
    }
    __syncthreads();

    char* out_sh = smem;                // [rr*32+x][co], 8192 B each
    char* out_sl = smem + 8192;
#pragma unroll
    for (int rr = 0; rr < 2; ++rr) {
#pragma unroll
        for (int m = 0; m < 2; ++m) {
#pragma unroll
            for (int r = 0; r < 4; ++r) {
                int x = m*16 + kq*4 + r;          // 0..31
                int co = n*16 + xq;
                float v = accm[rr][m][r] + accc[rr][m][r]*INV512;
                v = (v > 0.f) ? v : 0.1f*v;       // LeakyReLU
                _Float16 vh = (_Float16)v;
                _Float16 vl = (_Float16)((v - (float)vh)*512.f);
                int boff = ((rr*32 + x)*8 + ((co >> 3) ^ (x & 7)))*16 + (co & 7)*2;
                *(_Float16*)&out_sh[boff] = vh;
                *(_Float16*)&out_sl[boff] = vl;
            }
        }
    }
    __syncthreads();

#pragma unroll
    for (int i = 0; i < 2; ++i) {
        int unit = tid + 256*i;               // 0..511
        int rr = unit >> 8, x = (unit >> 3) & 31, u = unit & 7;
        int loff = ((rr*32 + x)*8 + (u ^ (x & 7)))*16;
        size_t g = (((size_t)(b*HH + y0 + rr)*WW) + x0 + x)*64 + u*8;
        *(half8*)&out_h[g] = *(half8*)&out_sh[loff];
        *(half8*)&out_l[g] = *(half8*)&out_sl[loff];
    }
}

// ---------------------------------------------------------------------------
// conv_b = conv2 + residual + 1x1 projection (K=128 GEMM), BOTH sides.
// grid (10, 64, 16): z>>3 = side, z&7 = batch.
__global__ __launch_bounds__(256) void k_conv_b(
    const _Float16* __restrict__ r_lh, const _Float16* __restrict__ r_ll,
    const _Float16* __restrict__ r_rh, const _Float16* __restrict__ r_rl,
    const _Float16* __restrict__ wBh, const _Float16* __restrict__ wBl,
    const float* __restrict__ res_l, const float* __restrict__ res_r,
    const _Float16* __restrict__ wl1h, const _Float16* __restrict__ wl1l,
    const _Float16* __restrict__ wr1h, const _Float16* __restrict__ wr1l,
    const float* __restrict__ bias_l, const float* __restrict__ bias_r,
    _Float16* __restrict__ F0h, _Float16* __restrict__ F0l,
    _Float16* __restrict__ F1h, _Float16* __restrict__ F1l)
{
    __shared__ __align__(16) char smem[49152];
    char* in_sh = smem;
    char* in_sl = smem + 17408;
    const int tid = threadIdx.x;
    const int x0 = blockIdx.x * 32;
    const int y0 = blockIdx.y * 2;
    const int z  = blockIdx.z;
    const int side = z >> 3, b = z & 7;
    const _Float16* in_h = side ? r_rh : r_lh;
    const _Float16* in_l = side ? r_rl : r_ll;
    const float* res = side ? res_r : res_l;
    const _Float16* w1h = side ? wr1h : wl1h;
    const _Float16* w1l = side ? wr1l : wl1l;
    const float* bias = side ? bias_r : bias_l;
    _Float16* Fh = side ? F1h : F0h;
    _Float16* Fl = side ? F1l : F0l;
    const int lane = tid & 63;
    const int xq = lane & 15, kq = lane >> 4;
    const int n = tid >> 6;

    half8 bwh[18], bwl[18];
    {
        const _Float16* wbh = &wBh[((size_t)(n*16 + xq)*9)*64 + kq*8];
        const _Float16* wbl = &wBl[((size_t)(n*16 + xq)*9)*64 + kq*8];
#pragma unroll
        for (int t = 0; t < 9; ++t)
#pragma unroll
            for (int c = 0; c < 2; ++c) {
                bwh[t*2 + c] = *(const half8*)&wbh[t*64 + c*32];
                bwl[t*2 + c] = *(const half8*)&wbl[t*64 + c*32];
            }
    }

    for (int e = tid; e < 1088; e += 256) {
        int t = e / 34;
        int xx = e - t*34;
        int ry = t >> 3, u = t & 7;
        int gy = y0 + ry - 1, gx = x0 + xx - 1;
        uint4 vh = make_uint4(0u,0u,0u,0u), vl = make_uint4(0u,0u,0u,0u);
        if ((unsigned)gy < (unsigned)HH && (unsigned)gx < (unsigned)WW) {
            size_t g = (((size_t)(b*HH + gy)*WW) + gx)*64 + u*8;
            vh = *(const uint4*)&in_h[g];
            vl = *(const uint4*)&in_l[g];
        }
        int off = ((ry*34 + xx)*8 + (u ^ (xx & 7)))*16;
        *(uint4*)&in_sh[off] = vh;
        *(uint4*)&in_sl[off] = vl;
    }
    __syncthreads();

    f32x4 accm[2][2], accc[2][2];
#pragma unroll
    for (int rr = 0; rr < 2; ++rr)
#pragma unroll
        for (int m = 0; m < 2; ++m) { accm[rr][m] = (f32x4)0.f; accc[rr][m] = (f32x4)0.f; }

#pragma unroll
    for (int rr = 0; rr < 2; ++rr) {
#pragma unroll
        for (int m = 0; m < 2; ++m) {
            const int xb = m*16 + xq;
#pragma unroll
            for (int t = 0; t < 9; ++t) {
                const int ry = t / 3, kx = t - ry*3;
                const int trow = rr + ry;
                const int xxx = xb + kx;
#pragma unroll
                for (int c = 0; c < 2; ++c) {
                    const int u = c*4 + kq;
                    int off = ((trow*34 + xxx)*8 + (u ^ (xxx & 7)))*16;
                    half8 ah = *(const half8*)&in_sh[off];
                    half8 al = *(const half8*)&in_sl[off];
                    accm[rr][m] = __builtin_amdgcn_mfma_f32_16x16x32_f16(
                        ah, bwh[t*2 + c], accm[rr][m], 0, 0, 0);
                    accc[rr][m] = __builtin_amdgcn_mfma_f32_16x16x32_f16(
                        al, bwh[t*2 + c], accc[rr][m], 0, 0, 0);
                    accc[rr][m] = __builtin_amdgcn_mfma_f32_16x16x32_f16(
                        ah, bwl[t*2 + c], accc[rr][m], 0, 0, 0);
                }
            }
        }
    }
    __syncthreads();            // in_s dead

    char* out_sh = smem;
    char* out_sl = smem + 8192;
    char* res_sh = smem + 16384;
    char* res_sl = smem + 24576;
    char* w_sh   = smem + 32768;
    char* w_sl   = smem + 40960;

    // stage residual: 2 rows x 32 x x 8 cu
#pragma unroll
    for (int i = 0; i < 2; ++i) {
        int e = tid + 256*i;                  // 0..511
        int rr = e >> 8, x = (e >> 3) & 31, cu = e & 7;
        const float* p = &res[((size_t)(b*CC + cu*8)*HH + y0 + rr)*WW + x0 + x];
        half8 hh, hl;
#pragma unroll
        for (int j = 0; j < 8; ++j) {
            float v = p[(size_t)j*HH*WW];
            _Float16 h = (_Float16)v;
            hh[j] = h; hl[j] = (_Float16)((v - (float)h)*512.f);
        }
        int off = ((rr*32 + x)*8 + (cu ^ (x & 7)))*16;
        *(half8*)&res_sh[off] = hh;
        *(half8*)&res_sl[off] = hl;
    }
    // stage 1x1 weights
#pragma unroll
    for (int i = 0; i < 2; ++i) {
        int e = tid + 256*i;
        int co = e >> 3, u = e & 7;
        int off = (co*8 + (u ^ (co & 7)))*16;
        *(half8*)&w_sh[off] = *(const half8*)&w1h[co*64 + u*8];
        *(half8*)&w_sl[off] = *(const half8*)&w1l[co*64 + u*8];
    }
    // conv2 raw out -> out tiles
#pragma unroll
    for (int rr = 0; rr < 2; ++rr) {
#pragma unroll
        for (int m = 0; m < 2; ++m) {
#pragma unroll
            for (int r = 0; r < 4; ++r) {
                int x = m*16 + kq*4 + r;
                int co = n*16 + xq;
                float v = accm[rr][m][r] + accc[rr][m][r]*INV512;
                _Float16 vh = (_Float16)v;
                _Float16 vl = (_Float16)((v - (float)vh)*512.f);
                int boff = ((rr*32 + x)*8 + ((co >> 3) ^ (x & 7)))*16 + (co & 7)*2;
                *(_Float16*)&out_sh[boff] = vh;
                *(_Float16*)&out_sl[boff] = vl;
            }
        }
    }
    __syncthreads();

    // 1x1 as K=128 split-fp16 GEMM over 64 positions (2 rows x 32 x)
    float bv[4];
#pragma unroll
    for (int nn = 0; nn < 4; ++nn) bv[nn] = bias[nn*16 + (lane & 15)];

    f32x4 am[4], ac[4];
#pragma unroll
    for (int nn = 0; nn < 4; ++nn) { am[nn] = (f32x4)0.f; ac[nn] = (f32x4)0.f; }

    const int arow = n*16 + (lane & 15);
#pragma unroll
    for (int c = 0; c < 4; ++c) {
        half8 ah, al;
        int u = (c & 1)*4 + (lane >> 4);
        int off = (arow*8 + (u ^ (arow & 7)))*16;
        if (c < 2) {
            ah = *(const half8*)&out_sh[off];
            al = *(const half8*)&out_sl[off];
        } else {
            ah = *(const half8*)&res_sh[off];
            al = *(const half8*)&res_sl[off];
        }
#pragma unroll
        for (int nn = 0; nn < 4; ++nn) {
            int brow = nn*16 + (lane & 15);
            int woff = (brow*8 + (u ^ (brow & 7)))*16;
            half8 bh  = *(const half8*)&w_sh[woff];
            half8 blw = *(const half8*)&w_sl[woff];
            am[nn] = __builtin_amdgcn_mfma_f32_16x16x32_f16(ah, bh,  am[nn], 0,0,0);
            ac[nn] = __builtin_amdgcn_mfma_f32_16x16x32_f16(al, bh,  ac[nn], 0,0,0);
            ac[nn] = __builtin_amdgcn_mfma_f32_16x16x32_f16(ah, blw, ac[nn], 0,0,0);
        }
    }
    __syncthreads();            // res tiles dead; F aliases them

    char* F_sh = smem + 16384;
    char* F_sl = smem + 24576;
#pragma unroll
    for (int nn = 0; nn < 4; ++nn) {
#pragma unroll
        for (int r = 0; r < 4; ++r) {
            int pos = n*16 + (lane >> 4)*4 + r;      // 0..63
            int co = nn*16 + (lane & 15);
            float v = am[nn][r] + ac[nn][r]*INV512 + bv[nn];
            _Float16 vh = (_Float16)v;
            _Float16 vl = (_Float16)((v - (float)vh)*512.f);
            int boff = (pos*8 + ((co >> 3) ^ (pos & 7)))*16 + (co & 7)*2;
            *(_Float16*)&F_sh[boff] = vh;
            *(_Float16*)&F_sl[boff] = vl;
        }
    }
    __syncthreads();

#pragma unroll
    for (int i = 0; i < 2; ++i) {
        int unit = tid + 256*i;
        int rr = unit >> 8, x = (unit >> 3) & 31, u = unit & 7;
        int loff = ((rr*32 + x)*8 + (u ^ (x & 7)))*16;
        size_t g = (((size_t)(b*HH + y0 + rr)*WW) + x0 + x)*64 + u*8;
        *(half8*)&Fh[g] = *(half8*)&F_sh[loff];
        *(half8*)&Fl[g] = *(half8*)&F_sl[loff];
    }
}

// ---------------------------------------------------------------------------
// Row-strip S-GEMM: block (wt,row) computes 64w x 320v. A-frags in registers,
// B double-buffered in LDS. Writes S, FINAL row stats, col partials per vt.
__global__ __launch_bounds__(256) void k_sgemm(
    const _Float16* __restrict__ F0h, const _Float16* __restrict__ F0l,
    const _Float16* __restrict__ F1h, const _Float16* __restrict__ F1l,
    float* __restrict__ S,
    float* __restrict__ colmax_p, float* __restrict__ colsum_p,
    float* __restrict__ rowmax_f, float* __restrict__ rowinv_f)
{
    __shared__ __align__(16) char smem[32768];   // R0: A then odd-vt B; R1: even-vt B
    __shared__ float cpm[2][4][64], cpl[2][4][64];
    const int wt = blockIdx.x, row = blockIdx.y;
    const int tid = threadIdx.x, lane = tid & 63, wid = tid >> 6;
    char* R0 = smem;
    char* R1 = smem + 16384;

    // prologue: A strip -> R0, B(vt=0) -> R1
    for (int e = tid; e < 512; e += 256) {
        int i = e >> 3, u = e & 7;
        int off = (i*8 + (u ^ (i & 7)))*16;
        size_t ga = ((size_t)row*WW + wt*64 + i)*64 + u*8;
        *(uint4*)&R0[off]        = *(const uint4*)&F0h[ga];
        *(uint4*)&R0[8192 + off] = *(const uint4*)&F0l[ga];
        size_t gb = ((size_t)row*WW + i)*64 + u*8;
        *(uint4*)&R1[off]        = *(const uint4*)&F1h[gb];
        *(uint4*)&R1[8192 + off] = *(const uint4*)&F1l[gb];
    }
    __syncthreads();

    half8 ah[2], al[2];
    {
        const int arow = wid*16 + (lane & 15);
#pragma unroll
        for (int c = 0; c < 2; ++c) {
            int u = c*4 + (lane >> 4);
            int aoff = (arow*8 + (u ^ (arow & 7)))*16;
            ah[c] = *(const half8*)&R0[aoff];
            al[c] = *(const half8*)&R0[8192 + aoff];
        }
    }

    float rm[4], rl[4];
#pragma unroll
    for (int r = 0; r < 4; ++r) { rm[r] = -1e30f; rl[r] = 0.f; }

    for (int vt = 0; vt < 5; ++vt) {
        char* cur = (vt & 1) ? R0 : R1;
        __syncthreads();
        if (vt < 4) {               // stage next B into the other buffer
            char* nxt = (vt & 1) ? R1 : R0;
            for (int e = tid; e < 512; e += 256) {
                int i = e >> 3, u = e & 7;
                int off = (i*8 + (u ^ (i & 7)))*16;
                size_t gb = ((size_t)row*WW + (vt+1)*64 + i)*64 + u*8;
                *(uint4*)&nxt[off]        = *(const uint4*)&F1h[gb];
                *(uint4*)&nxt[8192 + off] = *(const uint4*)&F1l[gb];
            }
        }
        if (vt > 0 && tid < 64) {   // merge col partials for vt-1
            int pb = (vt-1) & 1;
            float m0 = cpm[pb][0][tid], m1 = cpm[pb][1][tid];
            float m2 = cpm[pb][2][tid], m3 = cpm[pb][3][tid];
            float m = fmaxf(fmaxf(m0, m1), fmaxf(m2, m3));
            float l = cpl[pb][0][tid]*__expf(m0-m) + cpl[pb][1][tid]*__expf(m1-m)
                    + cpl[pb][2][tid]*__expf(m2-m) + cpl[pb][3][tid]*__expf(m3-m);
            size_t cbase = ((size_t)row*5 + wt)*WW + (size_t)(vt-1)*64 + tid;
            colmax_p[cbase] = m;
            colsum_p[cbase] = l;
        }

        f32x4 accm[4], accc[4];
#pragma unroll
        for (int n = 0; n < 4; ++n) { accm[n] = (f32x4)0.f; accc[n] = (f32x4)0.f; }
#pragma unroll
        for (int c = 0; c < 2; ++c) {
            const int u = c*4 + (lane >> 4);
#pragma unroll
            for (int n = 0; n < 4; ++n) {
                const int brow = n*16 + (lane & 15);
                int boff = (brow*8 + (u ^ (brow & 7)))*16;
                half8 bh = *(const half8*)&cur[boff];
                half8 bl = *(const half8*)&cur[8192 + boff];
                accm[n] = __builtin_amdgcn_mfma_f32_16x16x32_f16(ah[c], bh, accm[n], 0,0,0);
                accc[n] = __builtin_amdgcn_mfma_f32_16x16x32_f16(al[c], bh, accc[n], 0,0,0);
                accc[n] = __builtin_amdgcn_mfma_f32_16x16x32_f16(ah[c], bl, accc[n], 0,0,0);
            }
        }

        float sv[4][4];
#pragma unroll
        for (int n = 0; n < 4; ++n)
#pragma unroll
            for (int r = 0; r < 4; ++r)
                sv[n][r] = accm[n][r] + accc[n][r]*INV512;

#pragma unroll
        for (int n = 0; n < 4; ++n) {
            float* sp = &S[((size_t)row*WW + wt*64 + wid*16 + (lane>>4)*4)*WW
                           + vt*64 + n*16 + (lane & 15)];
#pragma unroll
            for (int r = 0; r < 4; ++r) sp[(size_t)r*WW] = sv[n][r];
        }

        // online row stats (this lane's 4 v-values per row)
#pragma unroll
        for (int r = 0; r < 4; ++r) {
            float tmax = fmaxf(fmaxf(sv[0][r], sv[1][r]), fmaxf(sv[2][r], sv[3][r]));
            float newm = fmaxf(rm[r], tmax);
            rl[r] = rl[r]*__expf(rm[r] - newm)
                  + __expf(sv[0][r]-newm) + __expf(sv[1][r]-newm)
                  + __expf(sv[2][r]-newm) + __expf(sv[3][r]-newm);
            rm[r] = newm;
        }

        // per-wave col stats -> cpm[vt&1]
#pragma unroll
        for (int n = 0; n < 4; ++n) {
            float m = fmaxf(fmaxf(sv[n][0], sv[n][1]), fmaxf(sv[n][2], sv[n][3]));
            m = fmaxf(m, __shfl_xor(m, 16));
            m = fmaxf(m, __shfl_xor(m, 32));
            float l = __expf(sv[n][0]-m) + __expf(sv[n][1]-m)
                    + __expf(sv[n][2]-m) + __expf(sv[n][3]-m);
            l += __shfl_xor(l, 16); l += __shfl_xor(l, 32);
            if (lane < 16) { cpm[vt&1][wid][n*16 + lane] = m;
                             cpl[vt&1][wid][n*16 + lane] = l; }
        }
    }
    __syncthreads();
    if (tid < 64) {                 // merge col partials for vt=4 (buffer 0)
        float m0 = cpm[0][0][tid], m1 = cpm[0][1][tid];
        float m2 = cpm[0][2][tid], m3 = cpm[0][3][tid];
        float m = fmaxf(fmaxf(m0, m1), fmaxf(m2, m3));
        float l = cpl[0][0][tid]*__expf(m0-m) + cpl[0][1][tid]*__expf(m1-m)
                + cpl[0][2][tid]*__expf(m2-m) + cpl[0][3][tid]*__expf(m3-m);
        size_t cbase = ((size_t)row*5 + wt)*WW + 4*64 + tid;
        colmax_p[cbase] = m;
        colsum_p[cbase] = l;
    }

    // final row stats: merge across the 16-lane (lane&15) group
#pragma unroll
    for (int r = 0; r < 4; ++r) {
#pragma unroll
        for (int o = 1; o < 16; o <<= 1) {
            float m2 = __shfl_xor(rm[r], o);
            float l2 = __shfl_xor(rl[r], o);
            float mm = fmaxf(rm[r], m2);
            rl[r] = rl[r]*__expf(rm[r] - mm) + l2*__expf(m2 - mm);
            rm[r] = mm;
        }
    }
    if ((lane & 15) == 0) {
        size_t rbase = (size_t)row*WW + wt*64 + wid*16 + (lane>>4)*4;
#pragma unroll
        for (int r = 0; r < 4; ++r) {
            rowmax_f[rbase + r] = rm[r];
            rowinv_f[rbase + r] = 1.f / rl[r];
        }
    }
}

// ---------------------------------------------------------------------------
// Merge 5 col partials per row into final max + 1/sum. grid 1024 x 320 thr.
__global__ __launch_bounds__(320) void k_smerge(
    const float* __restrict__ colmax_p, const float* __restrict__ colsum_p,
    float* __restrict__ colmax_f, float* __restrict__ colinv_f)
{
    const int row = blockIdx.x, tid = threadIdx.x;
    float m = -1e30f, l = 0.f;
#pragma unroll
    for (int t = 0; t < 5; ++t) {
        float pm = colmax_p[((size_t)row*5 + t)*WW + tid];
        float pl = colsum_p[((size_t)row*5 + t)*WW + tid];
        float m2 = fmaxf(m, pm);
        l = l*__expf(m - m2) + pl*__expf(pm - m2);
        m = m2;
    }
    colmax_f[(size_t)row*WW + tid] = m;
    colinv_f[(size_t)row*WW + tid] = 1.f/l;
}

// ---------------------------------------------------------------------------
// FUSED softmax-apply + out-GEMM with S register prefetch (issue-early).
// grid (5 wt, 1024 row), 256 thr.
__global__ __launch_bounds__(256) void k_fused(
    float* __restrict__ S, float* __restrict__ Ml2r, float* __restrict__ Vout,
    const float* __restrict__ xr, float* __restrict__ outf,
    const float* __restrict__ colmax_f, const float* __restrict__ colinv_f,
    const float* __restrict__ rowmax_f, const float* __restrict__ rowinv_f)
{
    __shared__ __align__(16) char A[8192], Bm[8192];   // fp16 tiles, swizzled
    __shared__ float T[64*65];                          // Ml2r transpose tile
    __shared__ float cmx[320], cin[320], rmx[64], rin[64];
    const int wt = blockIdx.x, row = blockIdx.y;
    const int b = row >> 7, h = row & 127;
    const int tid = threadIdx.x, lane = tid & 63, wid = tid >> 6;
    const int wrow = tid >> 2, quad = tid & 3;

    for (int e = tid; e < 320; e += 256) {
        cmx[e] = colmax_f[(size_t)row*WW + e];
        cin[e] = colinv_f[(size_t)row*WW + e];
    }
    if (tid < 64) {
        rmx[tid] = rowmax_f[(size_t)row*WW + wt*64 + tid];
        rin[tid] = rowinv_f[(size_t)row*WW + wt*64 + tid];
    }
    __syncthreads();

    f32x4 acc[4];
#pragma unroll
    for (int n = 0; n < 4; ++n) acc[n] = (f32x4)0.f;
    float vsum = 0.f;
    float* Sbase = &S[((size_t)row*WW + wt*64 + wrow)*WW];
    const float rm = rmx[wrow], ri = rin[wrow];

    // prefetch vt=0's S values
    float4 s_pre[4];
#pragma unroll
    for (int i = 0; i < 4; ++i)
        s_pre[i] = *(float4*)&Sbase[(quad + 4*i)*4];

    for (int vt = 0; vt < 5; ++vt) {
        if (vt) __syncthreads();
        float4 s_cur[4];
#pragma unroll
        for (int i = 0; i < 4; ++i) s_cur[i] = s_pre[i];
        if (vt < 4) {               // issue next tile's loads early
#pragma unroll
            for (int i = 0; i < 4; ++i)
                s_pre[i] = *(float4*)&Sbase[(vt+1)*64 + (quad + 4*i)*4];
        }
#pragma unroll
        for (int i = 0; i < 4; ++i) {
            const int f = quad + 4*i;
            const int v0 = f*4;
            float4 s = s_cur[i];
            float4 pr;
            pr.x = __expf(s.x - rm)*ri;
            pr.y = __expf(s.y - rm)*ri;
            pr.z = __expf(s.z - rm)*ri;
            pr.w = __expf(s.w - rm)*ri;
            *(float4*)&Sbase[vt*64 + v0] = pr;      // Mr2l in place
            const int vg = vt*64 + v0;
            float p0 = __expf(s.x - cmx[vg+0])*cin[vg+0];
            float p1 = __expf(s.y - cmx[vg+1])*cin[vg+1];
            float p2 = __expf(s.z - cmx[vg+2])*cin[vg+2];
            float p3 = __expf(s.w - cmx[vg+3])*cin[vg+3];
            T[(v0+0)*65 + wrow] = p0;
            T[(v0+1)*65 + wrow] = p1;
            T[(v0+2)*65 + wrow] = p2;
            T[(v0+3)*65 + wrow] = p3;
            vsum += p0 + p1 + p2 + p3;
            half4 hp;
            hp[0] = (_Float16)pr.x; hp[1] = (_Float16)pr.y;
            hp[2] = (_Float16)pr.z; hp[3] = (_Float16)pr.w;
            *(half4*)&A[(wrow*8 + ((f>>1) ^ (wrow & 7)))*16 + (f & 1)*8] = hp;
        }
        for (int e = tid; e < 512; e += 256) {
            int i = e >> 3, u = e & 7;
            const float4* xp = (const float4*)
                &xr[(((size_t)b*CC + i)*HH + h)*WW + vt*64 + u*8];
            float4 b0 = xp[0], b1 = xp[1];
            half8 hb;
            hb[0]=(_Float16)b0.x; hb[1]=(_Float16)b0.y; hb[2]=(_Float16)b0.z;
            hb[3]=(_Float16)b0.w; hb[4]=(_Float16)b1.x; hb[5]=(_Float16)b1.y;
            hb[6]=(_Float16)b1.z; hb[7]=(_Float16)b1.w;
            *(half8*)&Bm[(i*8 + (u ^ (i & 7)))*16] = hb;
        }
        __syncthreads();
#pragma unroll
        for (int c = 0; c < 2; ++c) {
            const int u = c*4 + (lane >> 4);
            const int arow = wid*16 + (lane & 15);
            half8 ah = *(const half8*)&A[(arow*8 + (u ^ (arow & 7)))*16];
#pragma unroll
            for (int n = 0; n < 4; ++n) {
                const int brow = n*16 + (lane & 15);
                half8 bh = *(const half8*)&Bm[(brow*8 + (u ^ (brow & 7)))*16];
                acc[n] = __builtin_amdgcn_mfma_f32_16x16x32_f16(ah, bh, acc[n], 0,0,0);
            }
        }
        // Ml2r transposed write, float4
        for (int e = tid; e < 1024; e += 256) {
            int vr = e >> 4, wc4 = (e & 15)*4;
            const float* tp = &T[vr*65 + wc4];
            *(float4*)&Ml2r[((size_t)row*WW + vt*64 + vr)*WW + wt*64 + wc4] =
                make_float4(tp[0], tp[1], tp[2], tp[3]);
        }
    }

    vsum += __shfl_xor(vsum, 1);
    vsum += __shfl_xor(vsum, 2);
    if (quad == 0)
        Vout[(size_t)row*WW + wt*64 + wrow] = (vsum > 0.1f) ? 1.f : 0.f;

#pragma unroll
    for (int n = 0; n < 4; ++n) {
        *(float4*)&outf[(((size_t)b*CC + n*16 + (lane & 15))*HH + h)*WW
                        + wt*64 + wid*16 + (lane>>4)*4] =
            make_float4(acc[n][0], acc[n][1], acc[n][2], acc[n][3]);
    }
}

// ---------------------------------------------------------------------------
// FALLBACK path (ws too small): separate softmax-apply and out-GEMM.
__global__ __launch_bounds__(320) void k_softmax(
    float* __restrict__ S, float* __restrict__ Ml2r, float* __restrict__ Vout,
    const float* __restrict__ colmax_f, const float* __restrict__ colinv_f,
    const float* __restrict__ rowmax_f, const float* __restrict__ rowinv_f)
{
    __shared__ float rowmax[320], rowinv[320], colmax[320], colinv[320];
    __shared__ float T[64*65];
    __shared__ float Vp2[5*64];
    const int row = blockIdx.x;
    const int tid = threadIdx.x;
    float* Srow = &S[(size_t)row * WW * WW];

    rowmax[tid] = rowmax_f[(size_t)row*WW + tid];
    rowinv[tid] = rowinv_f[(size_t)row*WW + tid];
    colmax[tid] = colmax_f[(size_t)row*WW + tid];
    colinv[tid] = colinv_f[(size_t)row*WW + tid];
    __syncthreads();

    const int myw = tid & 63;
    const int myg = tid / 64;
    for (int wt = 0; wt < 5; ++wt) {
        float vpart = 0.f;
        for (int vt = 0; vt < 5; ++vt) {
            for (int e = tid; e < 4096; e += 320) {
                int i = e >> 6, j = e & 63;
                int wgl = wt*64 + i, vgl = vt*64 + j;
                size_t si = (size_t)wgl*WW + vgl;
                float s = Srow[si];
                Srow[si] = __expf(s - rowmax[wgl]) * rowinv[wgl];
                T[j*65 + i] = __expf(s - colmax[vgl]) * colinv[vgl];
            }
            __syncthreads();
            for (int e = tid; e < 4096; e += 320) {
                int vr = e >> 6, wc = e & 63;
                Ml2r[((size_t)row*WW + vt*64 + vr)*WW + wt*64 + wc] = T[vr*65 + wc];
            }
            for (int j = myg; j < 64; j += 5) vpart += T[j*65 + myw];
            __syncthreads();
        }
        Vp2[myg*64 + myw] = vpart;
        __syncthreads();
        if (tid < 64) {
            float sv = 0.f;
#pragma unroll
            for (int g = 0; g < 5; ++g) sv += Vp2[g*64 + tid];
            Vout[(size_t)row*WW + wt*64 + tid] = (sv > 0.1f) ? 1.f : 0.f;
        }
        __syncthreads();
    }
}

__global__ __launch_bounds__(256) void k_outgemm(
    const float* __restrict__ M, const float* __restrict__ xr,
    float* __restrict__ outf)
{
    __shared__ __align__(16) char Am[8192], Bm[8192];
    const int wt = blockIdx.x;
    const int row = blockIdx.y;
    const int b = row >> 7, h = row & 127;
    const int tid = threadIdx.x, lane = tid & 63, wid = tid >> 6;

    f32x4 acc[4];
#pragma unroll
    for (int n = 0; n < 4; ++n) acc[n] = (f32x4)0.f;

    for (int vt = 0; vt < 5; ++vt) {
        if (vt) __syncthreads();
        for (int e = tid; e < 512; e += 256) {
            int i = e >> 3, u = e & 7;
            const float4* mp = (const float4*)
                &M[((size_t)row*WW + wt*64 + i)*WW + vt*64 + u*8];
            float4 a0 = mp[0], a1 = mp[1];
            const float4* xp = (const float4*)
                &xr[(((size_t)b*CC + i)*HH + h)*WW + vt*64 + u*8];
            float4 b0 = xp[0], b1 = xp[1];
            half8 ha, hb;
            ha[0]=(_Float16)a0.x; ha[1]=(_Float16)a0.y; ha[2]=(_Float16)a0.z;
            ha[3]=(_Float16)a0.w; ha[4]=(_Float16)a1.x; ha[5]=(_Float16)a1.y;
            ha[6]=(_Float16)a1.z; ha[7]=(_Float16)a1.w;
            hb[0]=(_Float16)b0.x; hb[1]=(_Float16)b0.y; hb[2]=(_Float16)b0.z;
            hb[3]=(_Float16)b0.w; hb[4]=(_Float16)b1.x; hb[5]=(_Float16)b1.y;
            hb[6]=(_Float16)b1.z; hb[7]=(_Float16)b1.w;
            int off = (i*8 + (u ^ (i & 7)))*16;
            *(half8*)&Am[off] = ha;
            *(half8*)&Bm[off] = hb;
        }
        __syncthreads();
#pragma unroll
        for (int c = 0; c < 2; ++c) {
            const int u = c*4 + (lane >> 4);
            const int arow = wid*16 + (lane & 15);
            half8 ah = *(const half8*)&Am[(arow*8 + (u ^ (arow & 7)))*16];
#pragma unroll
            for (int n = 0; n < 4; ++n) {
                const int brow = n*16 + (lane & 15);
                half8 bh = *(const half8*)&Bm[(brow*8 + (u ^ (brow & 7)))*16];
                acc[n] = __builtin_amdgcn_mfma_f32_16x16x32_f16(ah, bh, acc[n], 0,0,0);
            }
        }
    }

#pragma unroll
    for (int n = 0; n < 4; ++n) {
        *(float4*)&outf[(((size_t)b*CC + n*16 + (lane & 15))*HH + h)*WW
                        + wt*64 + wid*16 + (lane>>4)*4] =
            make_float4(acc[n][0], acc[n][1], acc[n][2], acc[n][3]);
    }
}

// ---------------------------------------------------------------------------
extern "C" void kernel_launch(void* const* d_in, const int* in_sizes, int n_in,
                              void* d_out, int out_size, void* d_ws, size_t ws_size,
                              hipStream_t stream)
{
    const float* x_l = (const float*)d_in[0];
    const float* x_r = (const float*)d_in[1];
    const float* w1  = (const float*)d_in[2];
    const float* w2  = (const float*)d_in[3];
    const float* wl  = (const float*)d_in[4];
    const float* bl  = (const float*)d_in[5];
    const float* wr  = (const float*)d_in[6];
    const float* br  = (const float*)d_in[7];
    float* out = (float*)d_out;

    float* outf = out;
    float* Vp   = out + OFF_V;
    float* Ml2r = out + OFF_ML2R;
    float* Mr2l = out + OFF_MR2L;

    // r (conv1 output) hi/lo for both sides in Mr2l region (10 NCL capacity)
    _Float16* r_lh = (_Float16*)Mr2l;
    _Float16* r_ll = r_lh + 1*(size_t)NCL;
    _Float16* r_rh = r_lh + 2*(size_t)NCL;
    _Float16* r_rl = r_lh + 3*(size_t)NCL;
    // F hi/lo in Ml2r region; conv/1x1 weights at its tail
    _Float16* F0h = (_Float16*)Ml2r;
    _Float16* F0l = F0h + (size_t)NCL;
    _Float16* F1h = F0l + (size_t)NCL;
    _Float16* F1l = F1h + (size_t)NCL;
    float* S  = Mr2l;
    _Float16* WTH = (_Float16*)(Ml2r + (size_t)N_M - WT_FLOATS);
    _Float16* wB1h = WTH;
    _Float16* wB1l = WTH + 36864;
    _Float16* wB2h = WTH + 73728;
    _Float16* wB2l = WTH + 110592;
    _Float16* wl1h = WTH + 147456;
    _Float16* wl1l = WTH + 151552;
    _Float16* wr1h = WTH + 155648;
    _Float16* wr1l = WTH + 159744;
    // col partials in the outf region (consumed before outf is written)
    float* colmax_p = out + 0;          // [1024][5][320]
    float* colsum_p = out + 1700000;

    const size_t FIN_FLOATS = (size_t)1024*320;
    bool fused = ws_size >= 4*FIN_FLOATS*sizeof(float);  // 5.24 MB
    float* colmax_f, *colinv_f, *rowmax_f, *rowinv_f;
    if (fused) {
        float* ws = (float*)d_ws;
        colmax_f = ws + 0*FIN_FLOATS;
        colinv_f = ws + 1*FIN_FLOATS;
        rowmax_f = ws + 2*FIN_FLOATS;
        rowinv_f = ws + 3*FIN_FLOATS;
    } else {
        colmax_f = out + 6800000;
        colinv_f = out + 7200000;
        rowmax_f = out + 7600000;
        rowinv_f = out + 8000000;
    }

    k_wt<<<64, 256, 0, stream>>>(w1, w2, wl, wr,
                                 wB1h, wB1l, wB2h, wB2l,
                                 wl1h, wl1l, wr1h, wr1l);

    dim3 pgrid(WW/32, HH/2, BB*2);
    k_conv_a<<<pgrid, 256, 0, stream>>>(x_l, x_r, wB1h, wB1l,
                                        r_lh, r_ll, r_rh, r_rl);
    k_conv_b<<<pgrid, 256, 0, stream>>>(r_lh, r_ll, r_rh, r_rl,
                                        wB2h, wB2l, x_l, x_r,
                                        wl1h, wl1l, wr1h, wr1l, bl, br,
                                        F0h, F0l, F1h, F1l);

    dim3 sgrid(5, BB*HH);
    k_sgemm<<<sgrid, 256, 0, stream>>>(F0h, F0l, F1h, F1l, S,
                                       colmax_p, colsum_p,
                                       rowmax_f, rowinv_f);

    k_smerge<<<BB*HH, 320, 0, stream>>>(colmax_p, colsum_p,
                                        colmax_f, colinv_f);

    if (fused) {
        dim3 fgrid(5, BB*HH);
        k_fused<<<fgrid, 256, 0, stream>>>(S, Ml2r, Vp, x_r, outf,
                                           colmax_f, colinv_f,
                                           rowmax_f, rowinv_f);
    } else {
        k_softmax<<<BB*HH, 320, 0, stream>>>(S, Ml2r, Vp,
                                             colmax_f, colinv_f,
                                             rowmax_f, rowinv_f);
        dim3 ogrid(5, BB*HH);
        k_outgemm<<<ogrid, 256, 0, stream>>>(Mr2l, x_r, outf);
    }
}

// Round 11
// 1095.023 us; speedup vs baseline: 4.5640x; 1.0198x over previous
//
#include <hip/hip_runtime.h>

#define BB 8
#define CC 64
#define HH 128
#define WW 320

// float offsets inside d_out
#define N_OUTF (BB*CC*HH*WW)           // 20,971,520
#define N_V    (BB*HH*WW)              // 327,680
#define N_M    (BB*HH*WW*WW)           // 104,857,600
#define OFF_V    (N_OUTF)
#define OFF_ML2R (N_OUTF + N_V)        // 21,299,200
#define OFF_MR2L (OFF_ML2R + N_M)      // 126,156,800
#define OUT_TOTAL (OFF_MR2L + N_M)     // 231,014,400
// weight tail at end of Ml2r region: 4x conv (36864 h) + 4x 1x1 (4096 h)
#define WT_FLOATS ((4*36864 + 4*4096)/2)           // 81,920 floats
#define NCL 20971520                   // halfs per channels-last buffer
#define INV512 (1.f/512.f)

typedef _Float16 half8 __attribute__((ext_vector_type(8)));
typedef _Float16 half4 __attribute__((ext_vector_type(4)));
typedef float f32x4 __attribute__((ext_vector_type(4)));

// ---------------------------------------------------------------------------
// Weights prep: rb_w -> fp16 hi/lo [co][tap][ci]; 1x1 -> fp16 hi/lo [co][ci].
__global__ __launch_bounds__(256) void k_wt(
    const float* __restrict__ w1, const float* __restrict__ w2,
    const float* __restrict__ wl, const float* __restrict__ wr,
    _Float16* __restrict__ wB1h, _Float16* __restrict__ wB1l,
    _Float16* __restrict__ wB2h, _Float16* __restrict__ wB2l,
    _Float16* __restrict__ wl1h, _Float16* __restrict__ wl1l,
    _Float16* __restrict__ wr1h, _Float16* __restrict__ wr1l)
{
    int tid = blockIdx.x * 256 + threadIdx.x;
    int stride = gridDim.x * 256;
    for (int e = tid; e < 64*9*64; e += stride) {   // e = co*576 + tap*64 + ci
        int co = e / 576;
        int rem = e - co*576;
        int tap = rem >> 6, ci = rem & 63;
        float v1 = w1[(co*64 + ci)*9 + tap];
        float v2 = w2[(co*64 + ci)*9 + tap];
        _Float16 h1 = (_Float16)v1, h2 = (_Float16)v2;
        wB1h[e] = h1; wB1l[e] = (_Float16)((v1 - (float)h1)*512.f);
        wB2h[e] = h2; wB2l[e] = (_Float16)((v2 - (float)h2)*512.f);
    }
    for (int e = tid; e < 4096; e += stride) {      // e = co*64 + ci
        float vl = wl[e], vr = wr[e];
        _Float16 hl = (_Float16)vl, hr = (_Float16)vr;
        wl1h[e] = hl; wl1l[e] = (_Float16)((vl - (float)hl)*512.f);
        wr1h[e] = hr; wr1l[e] = (_Float16)((vr - (float)hr)*512.f);
    }
}

// ---------------------------------------------------------------------------
// conv_a = prep + conv1 for BOTH sides. grid (10, 64, 16): z>>3=side, z&7=b.
__global__ __launch_bounds__(256) void k_conv_a(
    const float* __restrict__ in_l_, const float* __restrict__ in_r_,
    const _Float16* __restrict__ wBh, const _Float16* __restrict__ wBl,
    _Float16* __restrict__ r_lh, _Float16* __restrict__ r_ll,
    _Float16* __restrict__ r_rh, _Float16* __restrict__ r_rl)
{
    __shared__ __align__(16) char smem[2*4*34*128];    // 34816 B
    char* in_sh = smem;
    char* in_sl = smem + 17408;
    const int tid = threadIdx.x;
    const int x0 = blockIdx.x * 32;
    const int y0 = blockIdx.y * 2;
    const int z  = blockIdx.z;
    const int side = z >> 3, b = z & 7;
    const float* in = side ? in_r_ : in_l_;
    _Float16* out_h = side ? r_rh : r_lh;
    _Float16* out_l = side ? r_rl : r_ll;
    const int lane = tid & 63;
    const int xq = lane & 15, kq = lane >> 4;
    const int n = tid >> 6;                            // wave = co-tile

    half8 bwh[18], bwl[18];
    {
        const _Float16* wbh = &wBh[((size_t)(n*16 + xq)*9)*64 + kq*8];
        const _Float16* wbl = &wBl[((size_t)(n*16 + xq)*9)*64 + kq*8];
#pragma unroll
        for (int t = 0; t < 9; ++t)
#pragma unroll
            for (int c = 0; c < 2; ++c) {
                bwh[t*2 + c] = *(const half8*)&wbh[t*64 + c*32];
                bwl[t*2 + c] = *(const half8*)&wbl[t*64 + c*32];
            }
    }

    for (int e = tid; e < 1088; e += 256) {
        int t = e / 34;
        int xx = e - t*34;
        int ry = t >> 3, u = t & 7;
        int gy = y0 + ry - 1, gx = x0 + xx - 1;
        half8 hh, hl;
#pragma unroll
        for (int j = 0; j < 8; ++j) { hh[j] = (_Float16)0.f; hl[j] = (_Float16)0.f; }
        if ((unsigned)gy < (unsigned)HH && (unsigned)gx < (unsigned)WW) {
            const float* p = &in[((size_t)(b*CC + u*8)*HH + gy)*WW + gx];
#pragma unroll
            for (int j = 0; j < 8; ++j) {
                float v = p[(size_t)j*HH*WW];
                _Float16 h = (_Float16)v;
                hh[j] = h; hl[j] = (_Float16)((v - (float)h)*512.f);
            }
        }
        int off = ((ry*34 + xx)*8 + (u ^ (xx & 7)))*16;
        *(half8*)&in_sh[off] = hh;
        *(half8*)&in_sl[off] = hl;
    }
    __syncthreads();

    f32x4 accm[2][2], accc[2][2];                      // [rr][m]
#pragma unroll
    for (int rr = 0; rr < 2; ++rr)
#pragma unroll
        for (int m = 0; m < 2; ++m) { accm[rr][m] = (f32x4)0.f; accc[rr][m] = (f32x4)0.f; }

#pragma unroll
    for (int rr = 0; rr < 2; ++rr) {
#pragma unroll
        for (int m = 0; m < 2; ++m) {
            const int xb = m*16 + xq;
#pragma unroll
            for (int t = 0; t < 9; ++t) {
                const int ry = t / 3, kx = t - ry*3;
                const int trow = rr + ry;
                const int xxx = xb + kx;
#pragma unroll
                for (int c = 0; c < 2; ++c) {
                    const int u = c*4 + kq;
                    int off = ((trow*34 + xxx)*8 + (u ^ (xxx & 7)))*16;
                    half8 ah = *(const half8*)&in_sh[off];
                    half8 al = *(const half8*)&in_sl[off];
                    accm[rr][m] = __builtin_amdgcn_mfma_f32_16x16x32_f16(
                        ah, bwh[t*2 + c], accm[rr][m], 0, 0, 0);
                    accc[rr][m] = __builtin_amdgcn_mfma_f32_16x16x32_f16(
                        al, bwh[t*2 + c], accc[rr][m], 0, 0, 0);
                    accc[rr][m] = __builtin_amdgcn_mfma_f32_16x16x32_f16(
                        ah, bwl[t*2 + c], accc[rr][m], 0, 0, 0);
                }
            }
        }
    }
    __syncthreads();

    char* out_sh = smem;                // [rr*32+x][co], 8192 B each
    char* out_sl = smem + 8192;
#pragma unroll
    for (int rr = 0; rr < 2; ++rr) {
#pragma unroll
        for (int m = 0; m < 2; ++m) {
#pragma unroll
            for (int r = 0; r < 4; ++r) {
                int x = m*16 + kq*4 + r;          // 0..31
                int co = n*16 + xq;
                float v = accm[rr][m][r] + accc[rr][m][r]*INV512;
                v = (v > 0.f) ? v : 0.1f*v;       // LeakyReLU
                _Float16 vh = (_Float16)v;
                _Float16 vl = (_Float16)((v - (float)vh)*512.f);
                int boff = ((rr*32 + x)*8 + ((co >> 3) ^ (x & 7)))*16 + (co & 7)*2;
                *(_Float16*)&out_sh[boff] = vh;
                *(_Float16*)&out_sl[boff] = vl;
            }
        }
    }
    __syncthreads();

#pragma unroll
    for (int i = 0; i < 2; ++i) {
        int unit = tid + 256*i;               // 0..511
        int rr = unit >> 8, x = (unit >> 3) & 31, u = unit & 7;
        int loff = ((rr*32 + x)*8 + (u ^ (x & 7)))*16;
        size_t g = (((size_t)(b*HH + y0 + rr)*WW) + x0 + x)*64 + u*8;
        *(half8*)&out_h[g] = *(half8*)&out_sh[loff];
        *(half8*)&out_l[g] = *(half8*)&out_sl[loff];
    }
}

// ---------------------------------------------------------------------------
// conv_b = conv2 + residual + 1x1 projection (K=128 GEMM), BOTH sides.
__global__ __launch_bounds__(256) void k_conv_b(
    const _Float16* __restrict__ r_lh, const _Float16* __restrict__ r_ll,
    const _Float16* __restrict__ r_rh, const _Float16* __restrict__ r_rl,
    const _Float16* __restrict__ wBh, const _Float16* __restrict__ wBl,
    const float* __restrict__ res_l, const float* __restrict__ res_r,
    const _Float16* __restrict__ wl1h, const _Float16* __restrict__ wl1l,
    const _Float16* __restrict__ wr1h, const _Float16* __restrict__ wr1l,
    const float* __restrict__ bias_l, const float* __restrict__ bias_r,
    _Float16* __restrict__ F0h, _Float16* __restrict__ F0l,
    _Float16* __restrict__ F1h, _Float16* __restrict__ F1l)
{
    __shared__ __align__(16) char smem[49152];
    char* in_sh = smem;
    char* in_sl = smem + 17408;
    const int tid = threadIdx.x;
    const int x0 = blockIdx.x * 32;
    const int y0 = blockIdx.y * 2;
    const int z  = blockIdx.z;
    const int side = z >> 3, b = z & 7;
    const _Float16* in_h = side ? r_rh : r_lh;
    const _Float16* in_l = side ? r_rl : r_ll;
    const float* res = side ? res_r : res_l;
    const _Float16* w1h = side ? wr1h : wl1h;
    const _Float16* w1l = side ? wr1l : wl1l;
    const float* bias = side ? bias_r : bias_l;
    _Float16* Fh = side ? F1h : F0h;
    _Float16* Fl = side ? F1l : F0l;
    const int lane = tid & 63;
    const int xq = lane & 15, kq = lane >> 4;
    const int n = tid >> 6;

    half8 bwh[18], bwl[18];
    {
        const _Float16* wbh = &wBh[((size_t)(n*16 + xq)*9)*64 + kq*8];
        const _Float16* wbl = &wBl[((size_t)(n*16 + xq)*9)*64 + kq*8];
#pragma unroll
        for (int t = 0; t < 9; ++t)
#pragma unroll
            for (int c = 0; c < 2; ++c) {
                bwh[t*2 + c] = *(const half8*)&wbh[t*64 + c*32];
                bwl[t*2 + c] = *(const half8*)&wbl[t*64 + c*32];
            }
    }

    for (int e = tid; e < 1088; e += 256) {
        int t = e / 34;
        int xx = e - t*34;
        int ry = t >> 3, u = t & 7;
        int gy = y0 + ry - 1, gx = x0 + xx - 1;
        uint4 vh = make_uint4(0u,0u,0u,0u), vl = make_uint4(0u,0u,0u,0u);
        if ((unsigned)gy < (unsigned)HH && (unsigned)gx < (unsigned)WW) {
            size_t g = (((size_t)(b*HH + gy)*WW) + gx)*64 + u*8;
            vh = *(const uint4*)&in_h[g];
            vl = *(const uint4*)&in_l[g];
        }
        int off = ((ry*34 + xx)*8 + (u ^ (xx & 7)))*16;
        *(uint4*)&in_sh[off] = vh;
        *(uint4*)&in_sl[off] = vl;
    }
    __syncthreads();

    f32x4 accm[2][2], accc[2][2];
#pragma unroll
    for (int rr = 0; rr < 2; ++rr)
#pragma unroll
        for (int m = 0; m < 2; ++m) { accm[rr][m] = (f32x4)0.f; accc[rr][m] = (f32x4)0.f; }

#pragma unroll
    for (int rr = 0; rr < 2; ++rr) {
#pragma unroll
        for (int m = 0; m < 2; ++m) {
            const int xb = m*16 + xq;
#pragma unroll
            for (int t = 0; t < 9; ++t) {
                const int ry = t / 3, kx = t - ry*3;
                const int trow = rr + ry;
                const int xxx = xb + kx;
#pragma unroll
                for (int c = 0; c < 2; ++c) {
                    const int u = c*4 + kq;
                    int off = ((trow*34 + xxx)*8 + (u ^ (xxx & 7)))*16;
                    half8 ah = *(const half8*)&in_sh[off];
                    half8 al = *(const half8*)&in_sl[off];
                    accm[rr][m] = __builtin_amdgcn_mfma_f32_16x16x32_f16(
                        ah, bwh[t*2 + c], accm[rr][m], 0, 0, 0);
                    accc[rr][m] = __builtin_amdgcn_mfma_f32_16x16x32_f16(
                        al, bwh[t*2 + c], accc[rr][m], 0, 0, 0);
                    accc[rr][m] = __builtin_amdgcn_mfma_f32_16x16x32_f16(
                        ah, bwl[t*2 + c], accc[rr][m], 0, 0, 0);
                }
            }
        }
    }
    __syncthreads();            // in_s dead

    char* out_sh = smem;
    char* out_sl = smem + 8192;
    char* res_sh = smem + 16384;
    char* res_sl = smem + 24576;
    char* w_sh   = smem + 32768;
    char* w_sl   = smem + 40960;

#pragma unroll
    for (int i = 0; i < 2; ++i) {
        int e = tid + 256*i;                  // 0..511
        int rr = e >> 8, x = (e >> 3) & 31, cu = e & 7;
        const float* p = &res[((size_t)(b*CC + cu*8)*HH + y0 + rr)*WW + x0 + x];
        half8 hh, hl;
#pragma unroll
        for (int j = 0; j < 8; ++j) {
            float v = p[(size_t)j*HH*WW];
            _Float16 h = (_Float16)v;
            hh[j] = h; hl[j] = (_Float16)((v - (float)h)*512.f);
        }
        int off = ((rr*32 + x)*8 + (cu ^ (x & 7)))*16;
        *(half8*)&res_sh[off] = hh;
        *(half8*)&res_sl[off] = hl;
    }
#pragma unroll
    for (int i = 0; i < 2; ++i) {
        int e = tid + 256*i;
        int co = e >> 3, u = e & 7;
        int off = (co*8 + (u ^ (co & 7)))*16;
        *(half8*)&w_sh[off] = *(const half8*)&w1h[co*64 + u*8];
        *(half8*)&w_sl[off] = *(const half8*)&w1l[co*64 + u*8];
    }
#pragma unroll
    for (int rr = 0; rr < 2; ++rr) {
#pragma unroll
        for (int m = 0; m < 2; ++m) {
#pragma unroll
            for (int r = 0; r < 4; ++r) {
                int x = m*16 + kq*4 + r;
                int co = n*16 + xq;
                float v = accm[rr][m][r] + accc[rr][m][r]*INV512;
                _Float16 vh = (_Float16)v;
                _Float16 vl = (_Float16)((v - (float)vh)*512.f);
                int boff = ((rr*32 + x)*8 + ((co >> 3) ^ (x & 7)))*16 + (co & 7)*2;
                *(_Float16*)&out_sh[boff] = vh;
                *(_Float16*)&out_sl[boff] = vl;
            }
        }
    }
    __syncthreads();

    float bv[4];
#pragma unroll
    for (int nn = 0; nn < 4; ++nn) bv[nn] = bias[nn*16 + (lane & 15)];

    f32x4 am[4], ac[4];
#pragma unroll
    for (int nn = 0; nn < 4; ++nn) { am[nn] = (f32x4)0.f; ac[nn] = (f32x4)0.f; }

    const int arow = n*16 + (lane & 15);
#pragma unroll
    for (int c = 0; c < 4; ++c) {
        half8 ah, al;
        int u = (c & 1)*4 + (lane >> 4);
        int off = (arow*8 + (u ^ (arow & 7)))*16;
        if (c < 2) {
            ah = *(const half8*)&out_sh[off];
            al = *(const half8*)&out_sl[off];
        } else {
            ah = *(const half8*)&res_sh[off];
            al = *(const half8*)&res_sl[off];
        }
#pragma unroll
        for (int nn = 0; nn < 4; ++nn) {
            int brow = nn*16 + (lane & 15);
            int woff = (brow*8 + (u ^ (brow & 7)))*16;
            half8 bh  = *(const half8*)&w_sh[woff];
            half8 blw = *(const half8*)&w_sl[woff];
            am[nn] = __builtin_amdgcn_mfma_f32_16x16x32_f16(ah, bh,  am[nn], 0,0,0);
            ac[nn] = __builtin_amdgcn_mfma_f32_16x16x32_f16(al, bh,  ac[nn], 0,0,0);
            ac[nn] = __builtin_amdgcn_mfma_f32_16x16x32_f16(ah, blw, ac[nn], 0,0,0);
        }
    }
    __syncthreads();            // res tiles dead; F aliases them

    char* F_sh = smem + 16384;
    char* F_sl = smem + 24576;
#pragma unroll
    for (int nn = 0; nn < 4; ++nn) {
#pragma unroll
        for (int r = 0; r < 4; ++r) {
            int pos = n*16 + (lane >> 4)*4 + r;      // 0..63
            int co = nn*16 + (lane & 15);
            float v = am[nn][r] + ac[nn][r]*INV512 + bv[nn];
            _Float16 vh = (_Float16)v;
            _Float16 vl = (_Float16)((v - (float)vh)*512.f);
            int boff = (pos*8 + ((co >> 3) ^ (pos & 7)))*16 + (co & 7)*2;
            *(_Float16*)&F_sh[boff] = vh;
            *(_Float16*)&F_sl[boff] = vl;
        }
    }
    __syncthreads();

#pragma unroll
    for (int i = 0; i < 2; ++i) {
        int unit = tid + 256*i;
        int rr = unit >> 8, x = (unit >> 3) & 31, u = unit & 7;
        int loff = ((rr*32 + x)*8 + (u ^ (x & 7)))*16;
        size_t g = (((size_t)(b*HH + y0 + rr)*WW) + x0 + x)*64 + u*8;
        *(half8*)&Fh[g] = *(half8*)&F_sh[loff];
        *(half8*)&Fl[g] = *(half8*)&F_sl[loff];
    }
}

// ---------------------------------------------------------------------------
// Row-strip S-GEMM. WRITE_S=true: also writes S (fallback path). Always
// writes FINAL row stats and col partials per vt.
template<bool WRITE_S>
__global__ __launch_bounds__(256) void k_sgemm(
    const _Float16* __restrict__ F0h, const _Float16* __restrict__ F0l,
    const _Float16* __restrict__ F1h, const _Float16* __restrict__ F1l,
    float* __restrict__ S,
    float* __restrict__ colmax_p, float* __restrict__ colsum_p,
    float* __restrict__ rowmax_f, float* __restrict__ rowinv_f)
{
    __shared__ __align__(16) char smem[32768];   // R0: A then odd-vt B; R1: even-vt B
    __shared__ float cpm[2][4][64], cpl[2][4][64];
    const int wt = blockIdx.x, row = blockIdx.y;
    const int tid = threadIdx.x, lane = tid & 63, wid = tid >> 6;
    char* R0 = smem;
    char* R1 = smem + 16384;

    for (int e = tid; e < 512; e += 256) {
        int i = e >> 3, u = e & 7;
        int off = (i*8 + (u ^ (i & 7)))*16;
        size_t ga = ((size_t)row*WW + wt*64 + i)*64 + u*8;
        *(uint4*)&R0[off]        = *(const uint4*)&F0h[ga];
        *(uint4*)&R0[8192 + off] = *(const uint4*)&F0l[ga];
        size_t gb = ((size_t)row*WW + i)*64 + u*8;
        *(uint4*)&R1[off]        = *(const uint4*)&F1h[gb];
        *(uint4*)&R1[8192 + off] = *(const uint4*)&F1l[gb];
    }
    __syncthreads();

    half8 ah[2], al[2];
    {
        const int arow = wid*16 + (lane & 15);
#pragma unroll
        for (int c = 0; c < 2; ++c) {
            int u = c*4 + (lane >> 4);
            int aoff = (arow*8 + (u ^ (arow & 7)))*16;
            ah[c] = *(const half8*)&R0[aoff];
            al[c] = *(const half8*)&R0[8192 + aoff];
        }
    }

    float rm[4], rl[4];
#pragma unroll
    for (int r = 0; r < 4; ++r) { rm[r] = -1e30f; rl[r] = 0.f; }

    for (int vt = 0; vt < 5; ++vt) {
        char* cur = (vt & 1) ? R0 : R1;
        __syncthreads();
        if (vt < 4) {
            char* nxt = (vt & 1) ? R1 : R0;
            for (int e = tid; e < 512; e += 256) {
                int i = e >> 3, u = e & 7;
                int off = (i*8 + (u ^ (i & 7)))*16;
                size_t gb = ((size_t)row*WW + (vt+1)*64 + i)*64 + u*8;
                *(uint4*)&nxt[off]        = *(const uint4*)&F1h[gb];
                *(uint4*)&nxt[8192 + off] = *(const uint4*)&F1l[gb];
            }
        }
        if (vt > 0 && tid < 64) {
            int pb = (vt-1) & 1;
            float m0 = cpm[pb][0][tid], m1 = cpm[pb][1][tid];
            float m2 = cpm[pb][2][tid], m3 = cpm[pb][3][tid];
            float m = fmaxf(fmaxf(m0, m1), fmaxf(m2, m3));
            float l = cpl[pb][0][tid]*__expf(m0-m) + cpl[pb][1][tid]*__expf(m1-m)
                    + cpl[pb][2][tid]*__expf(m2-m) + cpl[pb][3][tid]*__expf(m3-m);
            size_t cbase = ((size_t)row*5 + wt)*WW + (size_t)(vt-1)*64 + tid;
            colmax_p[cbase] = m;
            colsum_p[cbase] = l;
        }

        f32x4 accm[4], accc[4];
#pragma unroll
        for (int n = 0; n < 4; ++n) { accm[n] = (f32x4)0.f; accc[n] = (f32x4)0.f; }
#pragma unroll
        for (int c = 0; c < 2; ++c) {
            const int u = c*4 + (lane >> 4);
#pragma unroll
            for (int n = 0; n < 4; ++n) {
                const int brow = n*16 + (lane & 15);
                int boff = (brow*8 + (u ^ (brow & 7)))*16;
                half8 bh = *(const half8*)&cur[boff];
                half8 bl = *(const half8*)&cur[8192 + boff];
                accm[n] = __builtin_amdgcn_mfma_f32_16x16x32_f16(ah[c], bh, accm[n], 0,0,0);
                accc[n] = __builtin_amdgcn_mfma_f32_16x16x32_f16(al[c], bh, accc[n], 0,0,0);
                accc[n] = __builtin_amdgcn_mfma_f32_16x16x32_f16(ah[c], bl, accc[n], 0,0,0);
            }
        }

        float sv[4][4];
#pragma unroll
        for (int n = 0; n < 4; ++n)
#pragma unroll
            for (int r = 0; r < 4; ++r)
                sv[n][r] = accm[n][r] + accc[n][r]*INV512;

        if (WRITE_S) {
#pragma unroll
            for (int n = 0; n < 4; ++n) {
                float* sp = &S[((size_t)row*WW + wt*64 + wid*16 + (lane>>4)*4)*WW
                               + vt*64 + n*16 + (lane & 15)];
#pragma unroll
                for (int r = 0; r < 4; ++r) sp[(size_t)r*WW] = sv[n][r];
            }
        }

#pragma unroll
        for (int r = 0; r < 4; ++r) {
            float tmax = fmaxf(fmaxf(sv[0][r], sv[1][r]), fmaxf(sv[2][r], sv[3][r]));
            float newm = fmaxf(rm[r], tmax);
            rl[r] = rl[r]*__expf(rm[r] - newm)
                  + __expf(sv[0][r]-newm) + __expf(sv[1][r]-newm)
                  + __expf(sv[2][r]-newm) + __expf(sv[3][r]-newm);
            rm[r] = newm;
        }

#pragma unroll
        for (int n = 0; n < 4; ++n) {
            float m = fmaxf(fmaxf(sv[n][0], sv[n][1]), fmaxf(sv[n][2], sv[n][3]));
            m = fmaxf(m, __shfl_xor(m, 16));
            m = fmaxf(m, __shfl_xor(m, 32));
            float l = __expf(sv[n][0]-m) + __expf(sv[n][1]-m)
                    + __expf(sv[n][2]-m) + __expf(sv[n][3]-m);
            l += __shfl_xor(l, 16); l += __shfl_xor(l, 32);
            if (lane < 16) { cpm[vt&1][wid][n*16 + lane] = m;
                             cpl[vt&1][wid][n*16 + lane] = l; }
        }
    }
    __syncthreads();
    if (tid < 64) {
        float m0 = cpm[0][0][tid], m1 = cpm[0][1][tid];
        float m2 = cpm[0][2][tid], m3 = cpm[0][3][tid];
        float m = fmaxf(fmaxf(m0, m1), fmaxf(m2, m3));
        float l = cpl[0][0][tid]*__expf(m0-m) + cpl[0][1][tid]*__expf(m1-m)
                + cpl[0][2][tid]*__expf(m2-m) + cpl[0][3][tid]*__expf(m3-m);
        size_t cbase = ((size_t)row*5 + wt)*WW + 4*64 + tid;
        colmax_p[cbase] = m;
        colsum_p[cbase] = l;
    }

#pragma unroll
    for (int r = 0; r < 4; ++r) {
#pragma unroll
        for (int o = 1; o < 16; o <<= 1) {
            float m2 = __shfl_xor(rm[r], o);
            float l2 = __shfl_xor(rl[r], o);
            float mm = fmaxf(rm[r], m2);
            rl[r] = rl[r]*__expf(rm[r] - mm) + l2*__expf(m2 - mm);
            rm[r] = mm;
        }
    }
    if ((lane & 15) == 0) {
        size_t rbase = (size_t)row*WW + wt*64 + wid*16 + (lane>>4)*4;
#pragma unroll
        for (int r = 0; r < 4; ++r) {
            rowmax_f[rbase + r] = rm[r];
            rowinv_f[rbase + r] = 1.f / rl[r];
        }
    }
}

// ---------------------------------------------------------------------------
// Merge 5 col partials per row into final max + 1/sum. grid 1024 x 320 thr.
__global__ __launch_bounds__(320) void k_smerge(
    const float* __restrict__ colmax_p, const float* __restrict__ colsum_p,
    float* __restrict__ colmax_f, float* __restrict__ colinv_f)
{
    const int row = blockIdx.x, tid = threadIdx.x;
    float m = -1e30f, l = 0.f;
#pragma unroll
    for (int t = 0; t < 5; ++t) {
        float pm = colmax_p[((size_t)row*5 + t)*WW + tid];
        float pl = colsum_p[((size_t)row*5 + t)*WW + tid];
        float m2 = fmaxf(m, pm);
        l = l*__expf(m - m2) + pl*__expf(pm - m2);
        m = m2;
    }
    colmax_f[(size_t)row*WW + tid] = m;
    colinv_f[(size_t)row*WW + tid] = 1.f/l;
}

// ---------------------------------------------------------------------------
// FUSED v2: recompute S from F (bit-identical to stats pass), normalize,
// write Mr2l + Ml2r + V + outf. No S materialization. grid (5 wt, 1024 row).
// LDS exactly 64KB: A_s 16K | B_s 16K | T 16K | Am 8K | Bm 8K.
__global__ __launch_bounds__(256) void k_fused2(
    const _Float16* __restrict__ F0h, const _Float16* __restrict__ F0l,
    const _Float16* __restrict__ F1h, const _Float16* __restrict__ F1l,
    float* __restrict__ Ml2r, float* __restrict__ Mr2l,
    float* __restrict__ Vout,
    const float* __restrict__ xr, float* __restrict__ outf,
    const float* __restrict__ colmax_f, const float* __restrict__ colinv_f,
    const float* __restrict__ rowmax_f, const float* __restrict__ rowinv_f)
{
    __shared__ __align__(16) char smem[65536];
    char* A_sh = smem;                 // F0 strip hi
    char* A_sl = smem + 8192;          // F0 strip lo
    char* B_sh = smem + 16384;         // F1 vt hi
    char* B_sl = smem + 24576;         // F1 vt lo
    float* T   = (float*)(smem + 32768);   // [64 v][64 w], XOR swizzled
    char* Am   = smem + 49152;         // P fp16 tile
    char* Bm   = smem + 57344;         // xr fp16 tile
    const int wt = blockIdx.x, row = blockIdx.y;
    const int b = row >> 7, h = row & 127;
    const int tid = threadIdx.x, lane = tid & 63, wid = tid >> 6;

    // prologue: stage A (F0 strip)
    for (int e = tid; e < 512; e += 256) {
        int i = e >> 3, u = e & 7;
        int off = (i*8 + (u ^ (i & 7)))*16;
        size_t ga = ((size_t)row*WW + wt*64 + i)*64 + u*8;
        *(uint4*)&A_sh[off] = *(const uint4*)&F0h[ga];
        *(uint4*)&A_sl[off] = *(const uint4*)&F0l[ga];
    }
    // row stats for this thread's 4 w-rows
    const int w_lo = wid*16 + (lane >> 4)*4;
    float rmv[4], riv[4];
#pragma unroll
    for (int r = 0; r < 4; ++r) {
        rmv[r] = rowmax_f[(size_t)row*WW + wt*64 + w_lo + r];
        riv[r] = rowinv_f[(size_t)row*WW + wt*64 + w_lo + r];
    }
    __syncthreads();

    half8 ah[2], al[2];
    {
        const int arow = wid*16 + (lane & 15);
#pragma unroll
        for (int c = 0; c < 2; ++c) {
            int u = c*4 + (lane >> 4);
            int aoff = (arow*8 + (u ^ (arow & 7)))*16;
            ah[c] = *(const half8*)&A_sh[aoff];
            al[c] = *(const half8*)&A_sl[aoff];
        }
    }

    f32x4 acc[4];
#pragma unroll
    for (int n = 0; n < 4; ++n) acc[n] = (f32x4)0.f;
    float vsum[4] = {0.f, 0.f, 0.f, 0.f};

    for (int vt = 0; vt < 5; ++vt) {
        if (vt) __syncthreads();      // prev MFMA-P / Ml2r-store / MFMA-S done
        // stage B_s (F1 vt) + Bm (xr vt)
        for (int e = tid; e < 512; e += 256) {
            int i = e >> 3, u = e & 7;
            int off = (i*8 + (u ^ (i & 7)))*16;
            size_t gb = ((size_t)row*WW + vt*64 + i)*64 + u*8;
            *(uint4*)&B_sh[off] = *(const uint4*)&F1h[gb];
            *(uint4*)&B_sl[off] = *(const uint4*)&F1l[gb];
            const float4* xp = (const float4*)
                &xr[(((size_t)b*CC + i)*HH + h)*WW + vt*64 + u*8];
            float4 b0 = xp[0], b1 = xp[1];
            half8 hb;
            hb[0]=(_Float16)b0.x; hb[1]=(_Float16)b0.y; hb[2]=(_Float16)b0.z;
            hb[3]=(_Float16)b0.w; hb[4]=(_Float16)b1.x; hb[5]=(_Float16)b1.y;
            hb[6]=(_Float16)b1.z; hb[7]=(_Float16)b1.w;
            *(half8*)&Bm[off] = hb;
        }
        // col stats for this vt (L2-hot, coalesced over lane&15)
        float cmv[4], civ[4];
#pragma unroll
        for (int n = 0; n < 4; ++n) {
            size_t vg = (size_t)row*WW + vt*64 + n*16 + (lane & 15);
            cmv[n] = colmax_f[vg];
            civ[n] = colinv_f[vg];
        }
        __syncthreads();

        // MFMA-S: recompute S tile (identical sequence to stats pass)
        f32x4 sm[4], sc[4];
#pragma unroll
        for (int n = 0; n < 4; ++n) { sm[n] = (f32x4)0.f; sc[n] = (f32x4)0.f; }
#pragma unroll
        for (int c = 0; c < 2; ++c) {
            const int u = c*4 + (lane >> 4);
#pragma unroll
            for (int n = 0; n < 4; ++n) {
                const int brow = n*16 + (lane & 15);
                int boff = (brow*8 + (u ^ (brow & 7)))*16;
                half8 bh = *(const half8*)&B_sh[boff];
                half8 bl = *(const half8*)&B_sl[boff];
                sm[n] = __builtin_amdgcn_mfma_f32_16x16x32_f16(ah[c], bh, sm[n], 0,0,0);
                sc[n] = __builtin_amdgcn_mfma_f32_16x16x32_f16(al[c], bh, sc[n], 0,0,0);
                sc[n] = __builtin_amdgcn_mfma_f32_16x16x32_f16(ah[c], bl, sc[n], 0,0,0);
            }
        }

        // normalize + scatter: Mr2l direct, T (Ml2r), Am (P fp16), vsum
#pragma unroll
        for (int n = 0; n < 4; ++n) {
            const int v = n*16 + (lane & 15);
            float* mp = &Mr2l[((size_t)row*WW + wt*64 + w_lo)*WW + vt*64 + v];
#pragma unroll
            for (int r = 0; r < 4; ++r) {
                float s = sm[n][r] + sc[n][r]*INV512;
                float pr = __expf(s - rmv[r])*riv[r];
                float pc = __expf(s - cmv[n])*civ[n];
                mp[(size_t)r*WW] = pr;
                T[v*64 + ((w_lo + r) ^ ((v & 7) << 2))] = pc;
                vsum[r] += pc;
                int w = w_lo + r;
                *(_Float16*)&Am[(w*8 + ((v >> 3) ^ (w & 7)))*16 + (v & 7)*2]
                    = (_Float16)pr;
            }
        }
        __syncthreads();

        // MFMA-P: out_f strip += P @ xr^T
#pragma unroll
        for (int c = 0; c < 2; ++c) {
            const int u = c*4 + (lane >> 4);
            const int arow = wid*16 + (lane & 15);
            half8 ap = *(const half8*)&Am[(arow*8 + (u ^ (arow & 7)))*16];
#pragma unroll
            for (int n = 0; n < 4; ++n) {
                const int brow = n*16 + (lane & 15);
                half8 bh = *(const half8*)&Bm[(brow*8 + (u ^ (brow & 7)))*16];
                acc[n] = __builtin_amdgcn_mfma_f32_16x16x32_f16(ap, bh, acc[n], 0,0,0);
            }
        }
        // Ml2r store from T (float4, swizzle-compatible: XOR is mult of 4)
        for (int e = tid; e < 1024; e += 256) {
            int vr = e >> 4, wc4 = (e & 15)*4;
            const float* tp = &T[vr*64 + (wc4 ^ ((vr & 7) << 2))];
            *(float4*)&Ml2r[((size_t)row*WW + vt*64 + vr)*WW + wt*64 + wc4] =
                make_float4(tp[0], tp[1], tp[2], tp[3]);
        }
    }

    // V: reduce over the 16-lane (lane&15) group
#pragma unroll
    for (int r = 0; r < 4; ++r) {
#pragma unroll
        for (int o = 1; o < 16; o <<= 1)
            vsum[r] += __shfl_xor(vsum[r], o);
    }
    if ((lane & 15) == 0) {
#pragma unroll
        for (int r = 0; r < 4; ++r)
            Vout[(size_t)row*WW + wt*64 + w_lo + r] = (vsum[r] > 0.1f) ? 1.f : 0.f;
    }

#pragma unroll
    for (int n = 0; n < 4; ++n) {
        *(float4*)&outf[(((size_t)b*CC + n*16 + (lane & 15))*HH + h)*WW
                        + wt*64 + wid*16 + (lane>>4)*4] =
            make_float4(acc[n][0], acc[n][1], acc[n][2], acc[n][3]);
    }
}

// ---------------------------------------------------------------------------
// FALLBACK path (ws too small): fused softmax-apply + out-GEMM reading S.
__global__ __launch_bounds__(256) void k_fused(
    float* __restrict__ S, float* __restrict__ Ml2r, float* __restrict__ Vout,
    const float* __restrict__ xr, float* __restrict__ outf,
    const float* __restrict__ colmax_f, const float* __restrict__ colinv_f,
    const float* __restrict__ rowmax_f, const float* __restrict__ rowinv_f)
{
    __shared__ __align__(16) char A[8192], Bm[8192];
    __shared__ float T[64*65];
    __shared__ float cmx[320], cin[320], rmx[64], rin[64];
    const int wt = blockIdx.x, row = blockIdx.y;
    const int b = row >> 7, h = row & 127;
    const int tid = threadIdx.x, lane = tid & 63, wid = tid >> 6;
    const int wrow = tid >> 2, quad = tid & 3;

    for (int e = tid; e < 320; e += 256) {
        cmx[e] = colmax_f[(size_t)row*WW + e];
        cin[e] = colinv_f[(size_t)row*WW + e];
    }
    if (tid < 64) {
        rmx[tid] = rowmax_f[(size_t)row*WW + wt*64 + tid];
        rin[tid] = rowinv_f[(size_t)row*WW + wt*64 + tid];
    }
    __syncthreads();

    f32x4 acc[4];
#pragma unroll
    for (int n = 0; n < 4; ++n) acc[n] = (f32x4)0.f;
    float vsum = 0.f;
    float* Sbase = &S[((size_t)row*WW + wt*64 + wrow)*WW];
    const float rm = rmx[wrow], ri = rin[wrow];

    float4 s_pre[4];
#pragma unroll
    for (int i = 0; i < 4; ++i)
        s_pre[i] = *(float4*)&Sbase[(quad + 4*i)*4];

    for (int vt = 0; vt < 5; ++vt) {
        if (vt) __syncthreads();
        float4 s_cur[4];
#pragma unroll
        for (int i = 0; i < 4; ++i) s_cur[i] = s_pre[i];
        if (vt < 4) {
#pragma unroll
            for (int i = 0; i < 4; ++i)
                s_pre[i] = *(float4*)&Sbase[(vt+1)*64 + (quad + 4*i)*4];
        }
#pragma unroll
        for (int i = 0; i < 4; ++i) {
            const int f = quad + 4*i;
            const int v0 = f*4;
            float4 s = s_cur[i];
            float4 pr;
            pr.x = __expf(s.x - rm)*ri;
            pr.y = __expf(s.y - rm)*ri;
            pr.z = __expf(s.z - rm)*ri;
            pr.w = __expf(s.w - rm)*ri;
            *(float4*)&Sbase[vt*64 + v0] = pr;
            const int vg = vt*64 + v0;
            float p0 = __expf(s.x - cmx[vg+0])*cin[vg+0];
            float p1 = __expf(s.y - cmx[vg+1])*cin[vg+1];
            float p2 = __expf(s.z - cmx[vg+2])*cin[vg+2];
            float p3 = __expf(s.w - cmx[vg+3])*cin[vg+3];
            T[(v0+0)*65 + wrow] = p0;
            T[(v0+1)*65 + wrow] = p1;
            T[(v0+2)*65 + wrow] = p2;
            T[(v0+3)*65 + wrow] = p3;
            vsum += p0 + p1 + p2 + p3;
            half4 hp;
            hp[0] = (_Float16)pr.x; hp[1] = (_Float16)pr.y;
            hp[2] = (_Float16)pr.z; hp[3] = (_Float16)pr.w;
            *(half4*)&A[(wrow*8 + ((f>>1) ^ (wrow & 7)))*16 + (f & 1)*8] = hp;
        }
        for (int e = tid; e < 512; e += 256) {
            int i = e >> 3, u = e & 7;
            const float4* xp = (const float4*)
                &xr[(((size_t)b*CC + i)*HH + h)*WW + vt*64 + u*8];
            float4 b0 = xp[0], b1 = xp[1];
            half8 hb;
            hb[0]=(_Float16)b0.x; hb[1]=(_Float16)b0.y; hb[2]=(_Float16)b0.z;
            hb[3]=(_Float16)b0.w; hb[4]=(_Float16)b1.x; hb[5]=(_Float16)b1.y;
            hb[6]=(_Float16)b1.z; hb[7]=(_Float16)b1.w;
            *(half8*)&Bm[(i*8 + (u ^ (i & 7)))*16] = hb;
        }
        __syncthreads();
#pragma unroll
        for (int c = 0; c < 2; ++c) {
            const int u = c*4 + (lane >> 4);
            const int arow = wid*16 + (lane & 15);
            half8 ah = *(const half8*)&A[(arow*8 + (u ^ (arow & 7)))*16];
#pragma unroll
            for (int n = 0; n < 4; ++n) {
                const int brow = n*16 + (lane & 15);
                half8 bh = *(const half8*)&Bm[(brow*8 + (u ^ (brow & 7)))*16];
                acc[n] = __builtin_amdgcn_mfma_f32_16x16x32_f16(ah, bh, acc[n], 0,0,0);
            }
        }
        for (int e = tid; e < 1024; e += 256) {
            int vr = e >> 4, wc4 = (e & 15)*4;
            const float* tp = &T[vr*65 + wc4];
            *(float4*)&Ml2r[((size_t)row*WW + vt*64 + vr)*WW + wt*64 + wc4] =
                make_float4(tp[0], tp[1], tp[2], tp[3]);
        }
    }

    vsum += __shfl_xor(vsum, 1);
    vsum += __shfl_xor(vsum, 2);
    if (quad == 0)
        Vout[(size_t)row*WW + wt*64 + wrow] = (vsum > 0.1f) ? 1.f : 0.f;

#pragma unroll
    for (int n = 0; n < 4; ++n) {
        *(float4*)&outf[(((size_t)b*CC + n*16 + (lane & 15))*HH + h)*WW
                        + wt*64 + wid*16 + (lane>>4)*4] =
            make_float4(acc[n][0], acc[n][1], acc[n][2], acc[n][3]);
    }
}

// ---------------------------------------------------------------------------
extern "C" void kernel_launch(void* const* d_in, const int* in_sizes, int n_in,
                              void* d_out, int out_size, void* d_ws, size_t ws_size,
                              hipStream_t stream)
{
    const float* x_l = (const float*)d_in[0];
    const float* x_r = (const float*)d_in[1];
    const float* w1  = (const float*)d_in[2];
    const float* w2  = (const float*)d_in[3];
    const float* wl  = (const float*)d_in[4];
    const float* bl  = (const float*)d_in[5];
    const float* wr  = (const float*)d_in[6];
    const float* br  = (const float*)d_in[7];
    float* out = (float*)d_out;

    float* outf = out;
    float* Vp   = out + OFF_V;
    float* Ml2r = out + OFF_ML2R;
    float* Mr2l = out + OFF_MR2L;

    // r (conv1 output) hi/lo for both sides in Mr2l region (10 NCL capacity)
    _Float16* r_lh = (_Float16*)Mr2l;
    _Float16* r_ll = r_lh + 1*(size_t)NCL;
    _Float16* r_rh = r_lh + 2*(size_t)NCL;
    _Float16* r_rl = r_lh + 3*(size_t)NCL;
    float* S  = Mr2l;
    _Float16* WTH = (_Float16*)(Ml2r + (size_t)N_M - WT_FLOATS);
    _Float16* wB1h = WTH;
    _Float16* wB1l = WTH + 36864;
    _Float16* wB2h = WTH + 73728;
    _Float16* wB2l = WTH + 110592;
    _Float16* wl1h = WTH + 147456;
    _Float16* wl1l = WTH + 151552;
    _Float16* wr1h = WTH + 155648;
    _Float16* wr1l = WTH + 159744;
    // col partials in the outf region (consumed before outf is written)
    float* colmax_p = out + 0;          // [1024][5][320]
    float* colsum_p = out + 1700000;

    const size_t FIN_FLOATS = (size_t)1024*320;          // 327,680
    const size_t NCLF = (size_t)NCL/2;                   // F buffer floats
    // S-less path needs stats (4 arrays) + F (4 buffers) in d_ws
    bool noS = ws_size >= (4*FIN_FLOATS + 4*NCLF)*sizeof(float);   // 173 MB
    bool fusedOK = ws_size >= 4*FIN_FLOATS*sizeof(float);          // 5.24 MB

    float *colmax_f, *colinv_f, *rowmax_f, *rowinv_f;
    _Float16 *F0h, *F0l, *F1h, *F1l;
    if (fusedOK) {
        float* ws = (float*)d_ws;
        colmax_f = ws + 0*FIN_FLOATS;
        colinv_f = ws + 1*FIN_FLOATS;
        rowmax_f = ws + 2*FIN_FLOATS;
        rowinv_f = ws + 3*FIN_FLOATS;
    } else {
        colmax_f = out + 6800000;
        colinv_f = out + 7200000;
        rowmax_f = out + 7600000;
        rowinv_f = out + 8000000;
    }
    if (noS) {
        _Float16* wsF = (_Float16*)((float*)d_ws + 4*FIN_FLOATS);
        F0h = wsF;
        F0l = F0h + (size_t)NCL;
        F1h = F0l + (size_t)NCL;
        F1l = F1h + (size_t)NCL;
    } else {
        F0h = (_Float16*)Ml2r;
        F0l = F0h + (size_t)NCL;
        F1h = F0l + (size_t)NCL;
        F1l = F1h + (size_t)NCL;
    }

    k_wt<<<64, 256, 0, stream>>>(w1, w2, wl, wr,
                                 wB1h, wB1l, wB2h, wB2l,
                                 wl1h, wl1l, wr1h, wr1l);

    dim3 pgrid(WW/32, HH/2, BB*2);
    k_conv_a<<<pgrid, 256, 0, stream>>>(x_l, x_r, wB1h, wB1l,
                                        r_lh, r_ll, r_rh, r_rl);
    k_conv_b<<<pgrid, 256, 0, stream>>>(r_lh, r_ll, r_rh, r_rl,
                                        wB2h, wB2l, x_l, x_r,
                                        wl1h, wl1l, wr1h, wr1l, bl, br,
                                        F0h, F0l, F1h, F1l);

    dim3 sgrid(5, BB*HH);
    if (noS) {
        k_sgemm<false><<<sgrid, 256, 0, stream>>>(F0h, F0l, F1h, F1l, S,
                                                  colmax_p, colsum_p,
                                                  rowmax_f, rowinv_f);
    } else {
        k_sgemm<true><<<sgrid, 256, 0, stream>>>(F0h, F0l, F1h, F1l, S,
                                                 colmax_p, colsum_p,
                                                 rowmax_f, rowinv_f);
    }

    k_smerge<<<BB*HH, 320, 0, stream>>>(colmax_p, colsum_p,
                                        colmax_f, colinv_f);

    dim3 fgrid(5, BB*HH);
    if (noS) {
        k_fused2<<<fgrid, 256, 0, stream>>>(F0h, F0l, F1h, F1l,
                                            Ml2r, Mr2l, Vp, x_r, outf,
                                            colmax_f, colinv_f,
                                            rowmax_f, rowinv_f);
    } else {
        // fallback: S materialized in Mr2l, normalized in place
        k_fused<<<fgrid, 256, 0, stream>>>(S, Ml2r, Vp, x_r, outf,
                                           colmax_f, colinv_f,
                                           rowmax_f, rowinv_f);
    }
}